// Round 5
// baseline (688.284 us; speedup 1.0000x reference)
//
#include <hip/hip_runtime.h>

// Problem constants (from reference): B=128, N=512, H=256, F_JET=8, gin=776.
#define B_   128
#define N_   512
#define H_   256
#define FJ   8
#define ROWS (B_ * N_)          // 65536 flattened vertex rows
#define NEGV (-1e9f)

typedef _Float16 f16;
typedef __attribute__((ext_vector_type(8))) f16   f16x8;   // one MFMA A/B fragment (4 VGPRs)
typedef __attribute__((ext_vector_type(4))) float f32x4;   // one MFMA C/D fragment

static __device__ inline f32x4 MFMA16(f16x8 a, f16x8 b, f32x4 c) {
  return __builtin_amdgcn_mfma_f32_16x16x32_f16(a, b, c, 0, 0, 0);
}

// global -> LDS direct copy, 16B per lane. LDS ptr must be wave-uniform; HW adds lane*16.
static __device__ inline void gld16(const void* g, void* l) {
  __builtin_amdgcn_global_load_lds(
      (const __attribute__((address_space(1))) void*)g,
      (__attribute__((address_space(3))) void*)(uintptr_t)l,
      16, 0, 0);
}

// ---------------------------------------------------------------------------
// Prep: transpose/convert weights to fp16 with the LDS bank-swizzle BAKED IN:
// within each row, 16B-chunk c is stored at slot c^(row&7)  (8-chunk window).
//  WaT[d][k']  = f16(Wa[k][d])            (256x256)
//  WmT[d][k']  = f16(Wm[k][d])            (256x256)
//  WzrT[n][k'] = f16(W{z|r}[row(k)][n'])  (512x512), n<256 -> Wz else Wr
//  WhcT[n][k'] = f16(Wh[row(k)][n])       (256x512)
// ---------------------------------------------------------------------------
__global__ void k_prep(const float* __restrict__ Wa, const float* __restrict__ Wm,
                       const float* __restrict__ Wz, const float* __restrict__ Wr,
                       const float* __restrict__ Wh,
                       f16* __restrict__ WaT, f16* __restrict__ WmT,
                       f16* __restrict__ WzrT, f16* __restrict__ WhcT) {
  int idx = blockIdx.x * 256 + threadIdx.x;
  if (idx < 65536) {
    int d = idx >> 8, k = idx & 255;
    int kk = ((((k >> 3) ^ (d & 7)) << 3) | (k & 7));
    WaT[d * 256 + kk] = (f16)Wa[k * 256 + d];
  } else if (idx < 131072) {
    int t = idx - 65536;
    int d = t >> 8, k = t & 255;
    int kk = ((((k >> 3) ^ (d & 7)) << 3) | (k & 7));
    WmT[d * 256 + kk] = (f16)Wm[k * 256 + d];
  } else if (idx < 131072 + 262144) {
    int t = idx - 131072;
    int n = t >> 9, k = t & 511;
    const float* src = (n < 256) ? Wz : Wr;
    int np  = n & 255;
    int row = (k < 256) ? k : (264 + k);   // 520 + (k - 256)
    int kk = ((((k >> 3) ^ (n & 7)) << 3) | (k & 7));
    WzrT[n * 512 + kk] = (f16)src[row * 256 + np];
  } else {
    int t = idx - (131072 + 262144);       // < 131072
    int n = t >> 9, k = t & 511;
    int row = (k < 256) ? k : (264 + k);
    int kk = ((((k >> 3) ^ (n & 7)) << 3) | (k & 7));
    WhcT[n * 512 + kk] = (f16)Wh[row * 256 + n];
  }
}

// partial sums: hmean4[b][part][d] = sum_{n in part} h[b][n][d], part of 128 rows
__global__ void k_hmean(const float* __restrict__ h, float* __restrict__ hmean4) {
  int b = blockIdx.x, part = blockIdx.y, d = threadIdx.x;
  const float* p = h + ((size_t)b * N_ + part * 128) * H_ + d;
  float s = 0.f;
  #pragma unroll 8
  for (int n = 0; n < 128; ++n) s += p[n * H_];
  hmean4[(b * 4 + part) * H_ + d] = s;
}

// Per-batch GRU constants: c_*[b][d] = bias[d] + h_mean[b]·W*[256:512,d] + jets[b]·W*[512:520,d]
__global__ void k_cvec(const float* __restrict__ hmean4, const float* __restrict__ jets,
                       const float* __restrict__ Wz, const float* __restrict__ Wr,
                       const float* __restrict__ Wh,
                       const float* __restrict__ bz, const float* __restrict__ br,
                       const float* __restrict__ bh,
                       float* __restrict__ cz, float* __restrict__ cr, float* __restrict__ ch) {
  __shared__ float hm[H_];
  __shared__ float jt[FJ];
  int b = blockIdx.x, d = threadIdx.x;
  hm[d] = (hmean4[(b * 4 + 0) * H_ + d] + hmean4[(b * 4 + 1) * H_ + d] +
           hmean4[(b * 4 + 2) * H_ + d] + hmean4[(b * 4 + 3) * H_ + d]) * (1.f / N_);
  if (d < FJ) jt[d] = jets[b * FJ + d];
  __syncthreads();
  float az = bz[d], ar = br[d], ah = bh[d];
  #pragma unroll 4
  for (int k = 0; k < H_; ++k) {
    float m = hm[k];
    az += m * Wz[(256 + k) * 256 + d];
    ar += m * Wr[(256 + k) * 256 + d];
    ah += m * Wh[(256 + k) * 256 + d];
  }
  #pragma unroll
  for (int f = 0; f < FJ; ++f) {
    float j = jt[f];
    az += j * Wz[(512 + f) * 256 + d];
    ar += j * Wr[(512 + f) * 256 + d];
    ah += j * Wh[(512 + f) * 256 + d];
  }
  cz[b * H_ + d] = az;
  cr[b * H_ + d] = ar;
  ch[b * H_ + d] = ah;
}

// ---------------------------------------------------------------------------
// Images of h: h16 = linear f16 copy; Kimg = f16 copy pre-swizzled per row
// (chunk c at slot c^(row&7)) for the attn K staging.
// ---------------------------------------------------------------------------
__global__ void k_kimg(const float* __restrict__ h, f16* __restrict__ Kimg,
                       f16* __restrict__ h16) {
  int t  = blockIdx.x * 256 + threadIdx.x;   // chunk id: 128*512*32 = 2,097,152
  int c  = t & 31;
  int rj = t >> 5;                            // b*512 + j
  const float* p = h + (size_t)rj * 256 + c * 8;
  f32x4 v0 = *(const f32x4*)p;
  f32x4 v1 = *(const f32x4*)(p + 4);
  f16x8 hv;
  #pragma unroll
  for (int e = 0; e < 4; ++e) { hv[e] = (f16)v0[e]; hv[4 + e] = (f16)v1[e]; }
  *(f16x8*)&h16[(size_t)rj * 256 + (size_t)c * 8] = hv;
  *(f16x8*)&Kimg[(size_t)rj * 256 + (size_t)((c ^ (rj & 7)) * 8)] = hv;
}

// ===========================================================================
// Shared GEMM geometry (all 4 matmuls):
//   block 128(m) x 256(n), 4 waves 2x2 (wave tile 64x128, acc[4][8]), BK=64.
//   LDS: ALds 128x64 f16 (16KB), BLds 256x64 f16 (32KB) -> 48KB, 3 blocks/CU.
//   A staged from LINEAR f16 rows (msg/h16/rh), swizzle on per-lane source;
//   B staged from PRE-SWIZZLED weight image (linear copy), or from h16 with
//   source swizzle (hmT). All fragment reads XOR-deswizzle -> conflict-free.
// ===========================================================================

// per-lane constant source offset for A panels (row stride 512B, 8-row groups)
#define A_LANE_OFF(m0) ((size_t)((m0) + wave * 32 + (lane >> 3)) * 512 \
                        + (size_t)(((lane & 7) ^ ((lane >> 3) & 7)) << 4))
// stage A tile rows m0..m0+127, K-cols k0..k0+63 from linear f16 base (k0 within source row)
#define STAGE_A(base, kbyte)                                            \
  {                                                                     \
    const char* s_ = (const char*)(base) + a_off + (size_t)(kbyte);     \
    char* d_ = (char*)ALds + wave * 4096;                               \
    _Pragma("unroll")                                                   \
    for (int i_ = 0; i_ < 4; ++i_) gld16(s_ + i_ * 4096, d_ + i_ * 1024); \
  }
// stage B tile (256 rows x 64k) as a LINEAR copy from a pre-swizzled image
// with row stride RS bytes
#define STAGE_B_IMG(base, RS, k0)                                       \
  {                                                                     \
    const char* s_ = (const char*)(base) + b_off + (size_t)(k0) * 2;    \
    char* d_ = (char*)BLds + wave * 8192;                               \
    _Pragma("unroll")                                                   \
    for (int i_ = 0; i_ < 8; ++i_) gld16(s_ + (size_t)i_ * 8 * (RS), d_ + i_ * 1024); \
  }

#define GEMM_COMPUTE()                                                  \
  _Pragma("unroll")                                                     \
  for (int ks = 0; ks < 2; ++ks) {                                      \
    f16x8 af[4], bf[8];                                                 \
    _Pragma("unroll")                                                   \
    for (int mi = 0; mi < 4; ++mi)                                      \
      af[mi] = *(const f16x8*)((const char*)ALds + (wr + mi * 16 + m16) * 128 \
                               + (((ks * 4 + g) ^ (m16 & 7)) << 4));    \
    _Pragma("unroll")                                                   \
    for (int ni = 0; ni < 8; ++ni)                                      \
      bf[ni] = *(const f16x8*)((const char*)BLds + (wc + ni * 16 + m16) * 128 \
                               + (((ks * 4 + g) ^ (m16 & 7)) << 4));    \
    _Pragma("unroll")                                                   \
    for (int mi = 0; mi < 4; ++mi)                                      \
      _Pragma("unroll")                                                 \
      for (int ni = 0; ni < 8; ++ni)                                    \
        acc[mi][ni] = MFMA16(af[mi], bf[ni], acc[mi][ni]);              \
  }

#define GEMM_PREAMBLE()                                                 \
  const int tid = threadIdx.x, lane = tid & 63, wave = tid >> 6;        \
  const int g = lane >> 4, m16 = lane & 15;                             \
  const int wr = (wave >> 1) * 64, wc = (wave & 1) * 128;               \
  f32x4 acc[4][8] = {};

// ---------------------------------------------------------------------------
// q = f16(h @ Wa + ba).  M=65536, N=256, K=256. Grid (512,1).
// ---------------------------------------------------------------------------
__global__ __launch_bounds__(256) void k_gemm_q(
    const f16* __restrict__ h16, const f16* __restrict__ WaT,
    const float* __restrict__ ba, f16* __restrict__ q) {
  __shared__ __align__(16) f16 ALds[128 * 64];
  __shared__ __align__(16) f16 BLds[256 * 64];
  GEMM_PREAMBLE();
  const int m0 = blockIdx.x * 128;
  const size_t a_off = A_LANE_OFF(m0);
  const size_t b_off = (size_t)(wave * 64 + (lane >> 3)) * 512 + (size_t)((lane & 7) << 4);
  for (int k0 = 0; k0 < 256; k0 += 64) {
    if (k0) __syncthreads();
    STAGE_A(h16, k0 * 2);
    STAGE_B_IMG(WaT, 512, k0);
    asm volatile("s_waitcnt vmcnt(0)" ::: "memory");
    __syncthreads();
    GEMM_COMPUTE();
  }
  #pragma unroll
  for (int mi = 0; mi < 4; ++mi)
    #pragma unroll
    for (int ni = 0; ni < 8; ++ni) {
      int gcol = wc + ni * 16 + m16;
      float bias = ba[gcol];
      #pragma unroll
      for (int r = 0; r < 4; ++r) {
        int grow = m0 + wr + mi * 16 + 4 * g + r;
        q[(size_t)grow * 256 + gcol] = (f16)(acc[mi][ni][r] + bias);
      }
    }
}

// ---------------------------------------------------------------------------
// hmT[b][d][n] = f16( (h[b] @ Wm + bm)^T ), per batch M=256(d), N=512(n), K=256.
// Grid (128 batches, 4): m0=(by>>1)*128, n0=(by&1)*256.
// A = WmT image (baked swizzle); B = h16[b] rows with source swizzle.
// ---------------------------------------------------------------------------
__global__ __launch_bounds__(256) void k_gemm_hmT(
    const f16* __restrict__ h16, const f16* __restrict__ WmT,
    const float* __restrict__ bm, f16* __restrict__ hmT) {
  __shared__ __align__(16) f16 ALds[128 * 64];
  __shared__ __align__(16) f16 BLds[256 * 64];
  GEMM_PREAMBLE();
  const int b = blockIdx.x;
  const int m0 = (blockIdx.y >> 1) * 128, n0 = (blockIdx.y & 1) * 256;
  // A from baked WmT: linear copy
  const size_t a_off = (size_t)(m0 + wave * 32 + (lane >> 3)) * 512 + (size_t)((lane & 7) << 4);
  // B from linear h16[b]: source swizzle
  const size_t b_off = (size_t)(b * 512 + n0 + wave * 64 + (lane >> 3)) * 512
                     + (size_t)(((lane & 7) ^ ((lane >> 3) & 7)) << 4);
  for (int k0 = 0; k0 < 256; k0 += 64) {
    if (k0) __syncthreads();
    { // A: linear from swizzled image
      const char* s_ = (const char*)WmT + a_off + (size_t)k0 * 2;
      char* d_ = (char*)ALds + wave * 4096;
      #pragma unroll
      for (int i_ = 0; i_ < 4; ++i_) gld16(s_ + i_ * 4096, d_ + i_ * 1024);
    }
    { // B: swizzled source from h16
      const char* s_ = (const char*)h16 + b_off + (size_t)k0 * 2;
      char* d_ = (char*)BLds + wave * 8192;
      #pragma unroll
      for (int i_ = 0; i_ < 8; ++i_) gld16(s_ + (size_t)i_ * 4096, d_ + i_ * 1024);
    }
    asm volatile("s_waitcnt vmcnt(0)" ::: "memory");
    __syncthreads();
    GEMM_COMPUTE();
  }
  #pragma unroll
  for (int mi = 0; mi < 4; ++mi)
    #pragma unroll
    for (int r = 0; r < 4; ++r) {
      int d = m0 + wr + mi * 16 + 4 * g + r;
      float bias = bm[d];
      #pragma unroll
      for (int ni = 0; ni < 8; ++ni) {
        int n = n0 + wc + ni * 16 + m16;
        hmT[(size_t)b * H_ * N_ + (size_t)d * N_ + n] = (f16)(acc[mi][ni][r] + bias);
      }
    }
}

// ---------------------------------------------------------------------------
// Flash attention + DTNN message (identical structure to R4's k_attn4).
// ---------------------------------------------------------------------------
__global__ __launch_bounds__(256) void k_attn4(
    const f16* __restrict__ q, const float* __restrict__ mask,
    const f16* __restrict__ hmT, const f16* __restrict__ Kimg,
    f16* __restrict__ msg) {
  __shared__ __align__(16) f16 Kt[64 * 256];    // 32KB
  __shared__ __align__(16) f16 Vt[256 * 64];    // 32KB
  __shared__ __align__(16) f16 Plds[4][16][72];
  __shared__ float mask_lds[N_];
  const int tid = threadIdx.x, lane = tid & 63, wave = tid >> 6;
  const int g = lane >> 4, m16 = lane & 15;
  const int b = blockIdx.x, i0 = blockIdx.y * 64;

  mask_lds[tid]       = mask[b * N_ + tid];
  mask_lds[tid + 256] = mask[b * N_ + tid + 256];

  const f16* qp = q + (size_t)(b * N_ + i0 + wave * 16 + m16) * H_ + 8 * g;
  f16x8 qf[8];
  #pragma unroll
  for (int kb = 0; kb < 8; ++kb) qf[kb] = *(const f16x8*)(qp + kb * 32);

  f32x4 o[16] = {};
  float mrun[4], lrun[4];
  #pragma unroll
  for (int r = 0; r < 4; ++r) { mrun[r] = -3.0e38f; lrun[r] = 0.f; }

  const char* hvbs = (const char*)(hmT + (size_t)b * H_ * N_);
  const char* ksrc = (const char*)(Kimg + (size_t)b * N_ * H_);

  for (int jt = 0; jt < 8; ++jt) {
    const int j0 = jt * 64;
    {
      const char* s = ksrc + jt * 32768 + wave * 8192 + lane * 16;
      char* dst = (char*)Kt + wave * 8192;
      #pragma unroll
      for (int i = 0; i < 8; ++i) gld16(s + i * 1024, dst + i * 1024);
    }
    {
      int drow = wave * 64 + (lane >> 3);
      const char* s = hvbs + (size_t)drow * 1024 + jt * 128
                    + (((lane & 7) ^ ((lane >> 3) & 7)) << 4);
      char* dst = (char*)Vt + wave * 8192;
      #pragma unroll
      for (int i = 0; i < 8; ++i) gld16(s + (size_t)i * 8192, dst + i * 1024);
    }
    asm volatile("s_waitcnt vmcnt(0)" ::: "memory");
    __syncthreads();

    f32x4 s[4] = {};
    __builtin_amdgcn_s_setprio(1);
    #pragma unroll
    for (int kb = 0; kb < 8; ++kb)
      #pragma unroll
      for (int cf = 0; cf < 4; ++cf) {
        const int jr = cf * 16 + m16;
        f16x8 kf = *(const f16x8*)&Kt[jr * 256 + (((kb * 4 + g) ^ (m16 & 7)) << 3)];
        s[cf] = MFMA16(qf[kb], kf, s[cf]);
      }
    __builtin_amdgcn_s_setprio(0);
    #pragma unroll
    for (int cf = 0; cf < 4; ++cf) {
      float cm  = mask_lds[j0 + cf * 16 + m16];
      float add = NEGV * (1.f - cm);
      #pragma unroll
      for (int r = 0; r < 4; ++r) s[cf][r] += add;
    }
    float p_[4][4];
    #pragma unroll
    for (int r = 0; r < 4; ++r) {
      float mx = fmaxf(fmaxf(s[0][r], s[1][r]), fmaxf(s[2][r], s[3][r]));
      #pragma unroll
      for (int off = 1; off < 16; off <<= 1) mx = fmaxf(mx, __shfl_xor(mx, off, 64));
      float mnew  = fmaxf(mrun[r], mx);
      float alpha = __expf(mrun[r] - mnew);
      float ps = 0.f;
      #pragma unroll
      for (int cf = 0; cf < 4; ++cf) {
        float pv = __expf(s[cf][r] - mnew);
        p_[cf][r] = pv; ps += pv;
      }
      #pragma unroll
      for (int off = 1; off < 16; off <<= 1) ps += __shfl_xor(ps, off, 64);
      lrun[r] = lrun[r] * alpha + ps;
      mrun[r] = mnew;
      #pragma unroll
      for (int c2 = 0; c2 < 16; ++c2) o[c2][r] *= alpha;
    }
    #pragma unroll
    for (int cf = 0; cf < 4; ++cf)
      #pragma unroll
      for (int r = 0; r < 4; ++r)
        Plds[wave][4 * g + r][cf * 16 + m16] = (f16)p_[cf][r];
    asm volatile("s_waitcnt lgkmcnt(0)" ::: "memory");
    __builtin_amdgcn_sched_barrier(0);
    f16x8 pa[2];
    #pragma unroll
    for (int ks = 0; ks < 2; ++ks) pa[ks] = *(const f16x8*)&Plds[wave][m16][ks * 32 + 8 * g];
    __builtin_amdgcn_s_setprio(1);
    #pragma unroll
    for (int c2 = 0; c2 < 16; ++c2) {
      const int d = c2 * 16 + m16;
      f16x8 v0 = *(const f16x8*)&Vt[d * 64 + (((g)     ^ (m16 & 7)) << 3)];
      f16x8 v1 = *(const f16x8*)&Vt[d * 64 + (((4 + g) ^ (m16 & 7)) << 3)];
      o[c2] = MFMA16(pa[0], v0, o[c2]);
      o[c2] = MFMA16(pa[1], v1, o[c2]);
    }
    __builtin_amdgcn_s_setprio(0);
    __syncthreads();
  }

  #pragma unroll
  for (int r = 0; r < 4; ++r) {
    int irow = i0 + wave * 16 + 4 * g + r;
    float rm  = mask_lds[irow];
    float inv = rm / lrun[r];
    #pragma unroll
    for (int c2 = 0; c2 < 16; ++c2) {
      float val = tanhf(o[c2][r] * inv);
      msg[(size_t)(b * N_ + irow) * H_ + c2 * 16 + m16] = (f16)val;
    }
  }
}

// ---------------------------------------------------------------------------
// Gate GEMM 1: pre = [msg|h] @ Wzr + c. Grid (512 m, 2): y=0 -> z, y=1 -> r.
//   z = f16(sigmoid(pre_z));  rh = f16(sigmoid(pre_r) * h)
// ---------------------------------------------------------------------------
__global__ __launch_bounds__(256) void k_gemm_zr(
    const f16* __restrict__ msg, const f16* __restrict__ h16,
    const f16* __restrict__ WzrT, const float* __restrict__ cz,
    const float* __restrict__ cr, f16* __restrict__ z, f16* __restrict__ rh) {
  __shared__ __align__(16) f16 ALds[128 * 64];
  __shared__ __align__(16) f16 BLds[256 * 64];
  GEMM_PREAMBLE();
  const int m0 = blockIdx.x * 128;
  const int n0 = blockIdx.y * 256;
  const size_t a_off = A_LANE_OFF(m0);
  const size_t b_off = (size_t)(n0 + wave * 64 + (lane >> 3)) * 1024 + (size_t)((lane & 7) << 4);
  for (int k0 = 0; k0 < 512; k0 += 64) {
    if (k0) __syncthreads();
    if (k0 < 256) STAGE_A(msg, k0 * 2)
    else          STAGE_A(h16, (k0 - 256) * 2)
    STAGE_B_IMG(WzrT, 1024, k0);
    asm volatile("s_waitcnt vmcnt(0)" ::: "memory");
    __syncthreads();
    GEMM_COMPUTE();
  }
  const int is_r = blockIdx.y;
  #pragma unroll
  for (int mi = 0; mi < 4; ++mi)
    #pragma unroll
    for (int ni = 0; ni < 8; ++ni) {
      int gcol = wc + ni * 16 + m16;
      #pragma unroll
      for (int r = 0; r < 4; ++r) {
        int grow = m0 + wr + mi * 16 + 4 * g + r;
        int bb = grow >> 9;
        float a = acc[mi][ni][r];
        size_t oidx = (size_t)grow * 256 + gcol;
        if (!is_r) {
          float v = a + cz[bb * 256 + gcol];
          z[oidx] = (f16)(1.f / (1.f + __expf(-v)));
        } else {
          float v  = a + cr[bb * 256 + gcol];
          float rr = 1.f / (1.f + __expf(-v));
          rh[oidx] = (f16)(rr * (float)h16[oidx]);
        }
      }
    }
}

// ---------------------------------------------------------------------------
// Gate GEMM 2: h_tilde = tanh([msg|rh] @ Whc + c_h); out = (1-z)*h + z*h_tilde
// Grid (512 m, 1).
// ---------------------------------------------------------------------------
__global__ __launch_bounds__(256) void k_gemm_ht(
    const f16* __restrict__ msg, const f16* __restrict__ rh,
    const f16* __restrict__ WhcT, const float* __restrict__ ch,
    const f16* __restrict__ z, const float* __restrict__ h,
    float* __restrict__ out) {
  __shared__ __align__(16) f16 ALds[128 * 64];
  __shared__ __align__(16) f16 BLds[256 * 64];
  GEMM_PREAMBLE();
  const int m0 = blockIdx.x * 128;
  const size_t a_off = A_LANE_OFF(m0);
  const size_t b_off = (size_t)(wave * 64 + (lane >> 3)) * 1024 + (size_t)((lane & 7) << 4);
  for (int k0 = 0; k0 < 512; k0 += 64) {
    if (k0) __syncthreads();
    if (k0 < 256) STAGE_A(msg, k0 * 2)
    else          STAGE_A(rh, (k0 - 256) * 2)
    STAGE_B_IMG(WhcT, 1024, k0);
    asm volatile("s_waitcnt vmcnt(0)" ::: "memory");
    __syncthreads();
    GEMM_COMPUTE();
  }
  #pragma unroll
  for (int mi = 0; mi < 4; ++mi)
    #pragma unroll
    for (int ni = 0; ni < 8; ++ni) {
      int gcol = wc + ni * 16 + m16;
      #pragma unroll
      for (int r = 0; r < 4; ++r) {
        int grow = m0 + wr + mi * 16 + 4 * g + r;
        int bb = grow >> 9;
        size_t oidx = (size_t)grow * 256 + gcol;
        float pre = acc[mi][ni][r] + ch[bb * 256 + gcol];
        float htl = tanhf(pre);
        float zv  = (float)z[oidx];
        float hv  = h[oidx];
        out[oidx] = (1.f - zv) * hv + zv * htl;
      }
    }
}

// ---------------------------------------------------------------------------
extern "C" void kernel_launch(void* const* d_in, const int* in_sizes, int n_in,
                              void* d_out, int out_size, void* d_ws, size_t ws_size,
                              hipStream_t stream) {
  const float* h    = (const float*)d_in[0];
  const float* jets = (const float*)d_in[1];
  const float* mask = (const float*)d_in[2];
  const float* Wa   = (const float*)d_in[3];
  const float* ba   = (const float*)d_in[4];
  const float* Wm   = (const float*)d_in[5];
  const float* bm   = (const float*)d_in[6];
  const float* Wz   = (const float*)d_in[7];
  const float* bz   = (const float*)d_in[8];
  const float* Wr   = (const float*)d_in[9];
  const float* br   = (const float*)d_in[10];
  const float* Wh   = (const float*)d_in[11];
  const float* bh   = (const float*)d_in[12];
  float* out = (float*)d_out;

  char* ws = (char*)d_ws;
  size_t off = 0;
  auto alloc = [&](size_t bytes) -> void* {
    void* p = ws + off;
    off += (bytes + 255) & ~(size_t)255;
    return p;
  };
  // big: q (f16, 32MB) during attention; z (f16) + rh (f16) afterwards.
  char*   big   = (char*) alloc((size_t)ROWS * H_ * 4);
  f16*    hmT   = (f16*)  alloc((size_t)B_ * H_ * N_ * 2);
  f16*    msg   = (f16*)  alloc((size_t)ROWS * H_ * 2);
  f16*    Kimg  = (f16*)  alloc((size_t)ROWS * H_ * 2);
  f16*    h16   = (f16*)  alloc((size_t)ROWS * H_ * 2);
  float*  hmean4= (float*)alloc((size_t)B_ * 4 * H_ * 4);
  float*  cz    = (float*)alloc((size_t)B_ * H_ * 4);
  float*  cr    = (float*)alloc((size_t)B_ * H_ * 4);
  float*  chv   = (float*)alloc((size_t)B_ * H_ * 4);
  f16*    WaT   = (f16*)  alloc(65536 * 2);
  f16*    WmT   = (f16*)  alloc(65536 * 2);
  f16*    WzrT  = (f16*)  alloc(262144 * 2);
  f16*    WhcT  = (f16*)  alloc(131072 * 2);
  f16* q  = (f16*)big;
  f16* z  = (f16*)big;                                     // q dead after attn
  f16* rh = (f16*)(big + (size_t)ROWS * H_ * 2);
  if (off > ws_size) return;  // workspace insufficient

  k_prep    <<<2048, 256, 0, stream>>>(Wa, Wm, Wz, Wr, Wh, WaT, WmT, WzrT, WhcT);
  k_hmean   <<<dim3(B_, 4), H_, 0, stream>>>(h, hmean4);
  k_cvec    <<<B_, H_, 0, stream>>>(hmean4, jets, Wz, Wr, Wh, bz, br, bh, cz, cr, chv);
  k_kimg    <<<8192, 256, 0, stream>>>(h, Kimg, h16);
  k_gemm_q  <<<dim3(512, 1), 256, 0, stream>>>(h16, WaT, ba, q);
  k_gemm_hmT<<<dim3(128, 4), 256, 0, stream>>>(h16, WmT, bm, hmT);
  k_attn4   <<<dim3(128, 8), 256, 0, stream>>>(q, mask, hmT, Kimg, msg);
  k_gemm_zr <<<dim3(512, 2), 256, 0, stream>>>(msg, h16, WzrT, cz, cr, z, rh);
  k_gemm_ht <<<dim3(512, 1), 256, 0, stream>>>(msg, rh, WhcT, chv, z, h, out);
}

// Round 6
// 546.782 us; speedup vs baseline: 1.2588x; 1.2588x over previous
//
#include <hip/hip_runtime.h>

// Problem constants (from reference): B=128, N=512, H=256, F_JET=8, gin=776.
#define B_   128
#define N_   512
#define H_   256
#define FJ   8
#define ROWS (B_ * N_)          // 65536 flattened vertex rows
#define NEGV (-1e9f)

typedef _Float16 f16;
typedef __attribute__((ext_vector_type(8))) f16   f16x8;   // one MFMA A/B fragment (4 VGPRs)
typedef __attribute__((ext_vector_type(4))) float f32x4;   // one MFMA C/D fragment

static __device__ inline f32x4 MFMA16(f16x8 a, f16x8 b, f32x4 c) {
  return __builtin_amdgcn_mfma_f32_16x16x32_f16(a, b, c, 0, 0, 0);
}

// global -> LDS direct copy, 16B per lane. LDS ptr must be wave-uniform; HW adds lane*16.
static __device__ inline void gld16(const void* g, void* l) {
  __builtin_amdgcn_global_load_lds(
      (const __attribute__((address_space(1))) void*)g,
      (__attribute__((address_space(3))) void*)(uintptr_t)l,
      16, 0, 0);
}

// ---------------------------------------------------------------------------
// Prep: transpose/convert weights to fp16 with the LDS bank-swizzle BAKED IN:
// within each row, 16B-chunk c is stored at slot c^(row&7)  (8-chunk window).
// ---------------------------------------------------------------------------
__global__ void k_prep(const float* __restrict__ Wa, const float* __restrict__ Wm,
                       const float* __restrict__ Wz, const float* __restrict__ Wr,
                       const float* __restrict__ Wh,
                       f16* __restrict__ WaT, f16* __restrict__ WmT,
                       f16* __restrict__ WzrT, f16* __restrict__ WhcT) {
  int idx = blockIdx.x * 256 + threadIdx.x;
  if (idx < 65536) {
    int d = idx >> 8, k = idx & 255;
    int kk = ((((k >> 3) ^ (d & 7)) << 3) | (k & 7));
    WaT[d * 256 + kk] = (f16)Wa[k * 256 + d];
  } else if (idx < 131072) {
    int t = idx - 65536;
    int d = t >> 8, k = t & 255;
    int kk = ((((k >> 3) ^ (d & 7)) << 3) | (k & 7));
    WmT[d * 256 + kk] = (f16)Wm[k * 256 + d];
  } else if (idx < 131072 + 262144) {
    int t = idx - 131072;
    int n = t >> 9, k = t & 511;
    const float* src = (n < 256) ? Wz : Wr;
    int np  = n & 255;
    int row = (k < 256) ? k : (264 + k);   // 520 + (k - 256)
    int kk = ((((k >> 3) ^ (n & 7)) << 3) | (k & 7));
    WzrT[n * 512 + kk] = (f16)src[row * 256 + np];
  } else {
    int t = idx - (131072 + 262144);       // < 131072
    int n = t >> 9, k = t & 511;
    int row = (k < 256) ? k : (264 + k);
    int kk = ((((k >> 3) ^ (n & 7)) << 3) | (k & 7));
    WhcT[n * 512 + kk] = (f16)Wh[row * 256 + n];
  }
}

// partial sums: hmean4[b][part][d] = sum_{n in part} h[b][n][d]
__global__ void k_hmean(const float* __restrict__ h, float* __restrict__ hmean4) {
  int b = blockIdx.x, part = blockIdx.y, d = threadIdx.x;
  const float* p = h + ((size_t)b * N_ + part * 128) * H_ + d;
  float s = 0.f;
  #pragma unroll 8
  for (int n = 0; n < 128; ++n) s += p[n * H_];
  hmean4[(b * 4 + part) * H_ + d] = s;
}

// Per-batch GRU constants: c_*[b][d] = bias[d] + h_mean[b]·W*[256:512,d] + jets[b]·W*[512:520,d]
__global__ void k_cvec(const float* __restrict__ hmean4, const float* __restrict__ jets,
                       const float* __restrict__ Wz, const float* __restrict__ Wr,
                       const float* __restrict__ Wh,
                       const float* __restrict__ bz, const float* __restrict__ br,
                       const float* __restrict__ bh,
                       float* __restrict__ cz, float* __restrict__ cr, float* __restrict__ ch) {
  __shared__ float hm[H_];
  __shared__ float jt[FJ];
  int b = blockIdx.x, d = threadIdx.x;
  hm[d] = (hmean4[(b * 4 + 0) * H_ + d] + hmean4[(b * 4 + 1) * H_ + d] +
           hmean4[(b * 4 + 2) * H_ + d] + hmean4[(b * 4 + 3) * H_ + d]) * (1.f / N_);
  if (d < FJ) jt[d] = jets[b * FJ + d];
  __syncthreads();
  float az = bz[d], ar = br[d], ah = bh[d];
  #pragma unroll 4
  for (int k = 0; k < H_; ++k) {
    float m = hm[k];
    az += m * Wz[(256 + k) * 256 + d];
    ar += m * Wr[(256 + k) * 256 + d];
    ah += m * Wh[(256 + k) * 256 + d];
  }
  #pragma unroll
  for (int f = 0; f < FJ; ++f) {
    float j = jt[f];
    az += j * Wz[(512 + f) * 256 + d];
    ar += j * Wr[(512 + f) * 256 + d];
    ah += j * Wh[(512 + f) * 256 + d];
  }
  cz[b * H_ + d] = az;
  cr[b * H_ + d] = ar;
  ch[b * H_ + d] = ah;
}

// h16 = linear f16 copy of h
__global__ void k_h16(const float* __restrict__ h, f16* __restrict__ h16) {
  int t  = blockIdx.x * 256 + threadIdx.x;   // chunk id: 2,097,152
  const float* p = h + (size_t)t * 8;
  f32x4 v0 = *(const f32x4*)p;
  f32x4 v1 = *(const f32x4*)(p + 4);
  f16x8 hv;
  #pragma unroll
  for (int e = 0; e < 4; ++e) { hv[e] = (f16)v0[e]; hv[4 + e] = (f16)v1[e]; }
  *(f16x8*)&h16[(size_t)t * 8] = hv;
}

// ===========================================================================
// Shared GEMM geometry: block 128x128, 4 waves 2x2 (wave tile 64x64, acc[4][4]),
// BK=64, double-buffered LDS (2 x (A 16KB + B 16KB) = 64KB, 2 blocks/CU).
// 2-phase pipeline with COUNTED vmcnt: stage(next) issued before compute(cur);
// s_waitcnt vmcnt(8) retires cur's 8 loads, next's 8 stay in flight.
// Barrier ledger per iteration kt:
//   [stage next -> buf (kt+1)&1]  (8 gld16)
//   vmcnt(8) -> cur's loads landed in LDS (in-order retirement)
//   s_barrier #1 -> ALL waves' cur data visible
//   compute(cur)  (ds_reads complete in-wave via lgkm data deps)
//   s_barrier #2 -> no wave enters kt+1 (which stages buf kt&1 = cur) until
//                   all waves finished reading cur.   => race-free.
// ===========================================================================
#define GEMM_PRE()                                                      \
  const int tid = threadIdx.x, lane = tid & 63, wave = tid >> 6;        \
  const int g = lane >> 4, m16 = lane & 15;                             \
  const int wr = (wave >> 1) * 64, wc = (wave & 1) * 64;                \
  f32x4 acc[4][4] = {};

#define GEMM_COMPUTE(Ab, Bb)                                            \
  _Pragma("unroll")                                                     \
  for (int ks = 0; ks < 2; ++ks) {                                      \
    f16x8 af[4], bf[4];                                                 \
    _Pragma("unroll")                                                   \
    for (int mi = 0; mi < 4; ++mi)                                      \
      af[mi] = *(const f16x8*)((const char*)(Ab) + (wr + mi * 16 + m16) * 128 \
                               + (((ks * 4 + g) ^ (m16 & 7)) << 4));    \
    _Pragma("unroll")                                                   \
    for (int ni = 0; ni < 4; ++ni)                                      \
      bf[ni] = *(const f16x8*)((const char*)(Bb) + (wc + ni * 16 + m16) * 128 \
                               + (((ks * 4 + g) ^ (m16 & 7)) << 4));    \
    _Pragma("unroll")                                                   \
    for (int mi = 0; mi < 4; ++mi)                                      \
      _Pragma("unroll")                                                 \
      for (int ni = 0; ni < 4; ++ni)                                    \
        acc[mi][ni] = MFMA16(af[mi], bf[ni], acc[mi][ni]);              \
  }

// 2-phase K-loop driver; STAGEFN(buf, k0) must issue exactly 8 gld16.
#define GEMM_LOOP(KMAX, STAGEFN)                                        \
  STAGEFN(0, 0);                                                       \
  for (int kt = 0; kt < (KMAX) / 64; ++kt) {                            \
    const int cur = kt & 1;                                             \
    if (kt < (KMAX) / 64 - 1) {                                         \
      STAGEFN(cur ^ 1, (kt + 1) * 64);                                  \
      asm volatile("s_waitcnt vmcnt(8)" ::: "memory");                  \
    } else {                                                            \
      asm volatile("s_waitcnt vmcnt(0)" ::: "memory");                  \
    }                                                                   \
    __builtin_amdgcn_sched_barrier(0);                                  \
    __builtin_amdgcn_s_barrier();                                       \
    __builtin_amdgcn_sched_barrier(0);                                  \
    GEMM_COMPUTE(&AL[cur][0], &BL[cur][0]);                             \
    __builtin_amdgcn_s_barrier();                                       \
    __builtin_amdgcn_sched_barrier(0);                                  \
  }

// per-lane source offsets
//  linear f16 source (row stride 512B) with swizzle baked into the address:
#define SRC_SWZ(row0) ((size_t)(row0 + wave * 32 + (lane >> 3)) * 512 \
                       + (size_t)(((lane & 7) ^ ((lane >> 3) & 7)) << 4))
//  pre-swizzled image, linear copy, row stride RS bytes:
#define SRC_IMG(row0, RS) ((size_t)(row0 + wave * 32 + (lane >> 3)) * (RS) \
                           + (size_t)((lane & 7) << 4))

// ---------------------------------------------------------------------------
// q = f16(h @ Wa + ba). Grid (512 m, 2 n).
// ---------------------------------------------------------------------------
__global__ __launch_bounds__(256) void k_gemm_q(
    const f16* __restrict__ h16, const f16* __restrict__ WaT,
    const float* __restrict__ ba, f16* __restrict__ q) {
  __shared__ __align__(16) f16 AL[2][128 * 64], BL[2][128 * 64];
  GEMM_PRE();
  const int m0 = blockIdx.x * 128, n0 = blockIdx.y * 128;
  const size_t a_off = SRC_SWZ(m0);
  const size_t b_off = SRC_IMG(n0, 512);
  #define STG_Q(buf, k0)                                                \
    {                                                                   \
      const char* sa = (const char*)h16 + a_off + (size_t)(k0) * 2;     \
      const char* sb = (const char*)WaT + b_off + (size_t)(k0) * 2;     \
      char* da = (char*)&AL[buf][0] + wave * 4096;                      \
      char* db = (char*)&BL[buf][0] + wave * 4096;                      \
      _Pragma("unroll")                                                 \
      for (int i_ = 0; i_ < 4; ++i_) {                                  \
        gld16(sa + i_ * 4096, da + i_ * 1024);                          \
        gld16(sb + i_ * 4096, db + i_ * 1024);                          \
      }                                                                 \
    }
  GEMM_LOOP(256, STG_Q);
  #pragma unroll
  for (int mi = 0; mi < 4; ++mi)
    #pragma unroll
    for (int ni = 0; ni < 4; ++ni) {
      int gcol = n0 + wc + ni * 16 + m16;
      float bias = ba[gcol];
      #pragma unroll
      for (int r = 0; r < 4; ++r) {
        int grow = m0 + wr + mi * 16 + 4 * g + r;
        q[(size_t)grow * 256 + gcol] = (f16)(acc[mi][ni][r] + bias);
      }
    }
}

// ---------------------------------------------------------------------------
// hmT[b][d][n] = f16( (h[b] @ Wm + bm)^T ). Grid (128 batches, 8).
// A = WmT image (baked swizzle, linear copy); B = h16[b] rows, source swizzle.
// ---------------------------------------------------------------------------
__global__ __launch_bounds__(256) void k_gemm_hmT(
    const f16* __restrict__ h16, const f16* __restrict__ WmT,
    const float* __restrict__ bm, f16* __restrict__ hmT) {
  __shared__ __align__(16) f16 AL[2][128 * 64], BL[2][128 * 64];
  GEMM_PRE();
  const int b = blockIdx.x;
  const int m0 = (blockIdx.y >> 2) * 128, n0 = (blockIdx.y & 3) * 128;
  const size_t a_off = SRC_IMG(m0, 512);
  const size_t b_off = SRC_SWZ(b * 512 + n0);
  #define STG_HM(buf, k0)                                               \
    {                                                                   \
      const char* sa = (const char*)WmT + a_off + (size_t)(k0) * 2;     \
      const char* sb = (const char*)h16 + b_off + (size_t)(k0) * 2;     \
      char* da = (char*)&AL[buf][0] + wave * 4096;                      \
      char* db = (char*)&BL[buf][0] + wave * 4096;                      \
      _Pragma("unroll")                                                 \
      for (int i_ = 0; i_ < 4; ++i_) {                                  \
        gld16(sa + i_ * 4096, da + i_ * 1024);                          \
        gld16(sb + i_ * 4096, db + i_ * 1024);                          \
      }                                                                 \
    }
  GEMM_LOOP(256, STG_HM);
  #pragma unroll
  for (int mi = 0; mi < 4; ++mi)
    #pragma unroll
    for (int r = 0; r < 4; ++r) {
      int d = m0 + wr + mi * 16 + 4 * g + r;
      float bias = bm[d];
      #pragma unroll
      for (int ni = 0; ni < 4; ++ni) {
        int n = n0 + wc + ni * 16 + m16;
        hmT[(size_t)b * H_ * N_ + (size_t)d * N_ + n] = (f16)(acc[mi][ni][r] + bias);
      }
    }
}

// ---------------------------------------------------------------------------
// Flash attention + DTNN message (R4 structure; K now staged from linear h16
// with swizzle computed on the per-lane global source address).
// ---------------------------------------------------------------------------
__global__ __launch_bounds__(256) void k_attn4(
    const f16* __restrict__ q, const float* __restrict__ mask,
    const f16* __restrict__ hmT, const f16* __restrict__ h16,
    f16* __restrict__ msg) {
  __shared__ __align__(16) f16 Kt[64 * 256];    // 32KB
  __shared__ __align__(16) f16 Vt[256 * 64];    // 32KB
  __shared__ __align__(16) f16 Plds[4][16][72];
  __shared__ float mask_lds[N_];
  const int tid = threadIdx.x, lane = tid & 63, wave = tid >> 6;
  const int g = lane >> 4, m16 = lane & 15;
  const int b = blockIdx.x, i0 = blockIdx.y * 64;

  mask_lds[tid]       = mask[b * N_ + tid];
  mask_lds[tid + 256] = mask[b * N_ + tid + 256];

  const f16* qp = q + (size_t)(b * N_ + i0 + wave * 16 + m16) * H_ + 8 * g;
  f16x8 qf[8];
  #pragma unroll
  for (int kb = 0; kb < 8; ++kb) qf[kb] = *(const f16x8*)(qp + kb * 32);

  f32x4 o[16] = {};
  float mrun[4], lrun[4];
  #pragma unroll
  for (int r = 0; r < 4; ++r) { mrun[r] = -3.0e38f; lrun[r] = 0.f; }

  const char* hvbs = (const char*)(hmT + (size_t)b * H_ * N_);
  const char* h16b = (const char*)(h16 + (size_t)b * N_ * H_);

  for (int jt = 0; jt < 8; ++jt) {
    const int j0 = jt * 64;
    { // stage K (64 j-rows x 256 k) from linear h16; LDS row j slot s holds
      // source chunk s^(j&7).  LDS pos = wave*8192 + i*1024 + lane*16.
      const int rl = lane >> 5, s5 = lane & 31;
      char* dst = (char*)Kt + wave * 8192;
      #pragma unroll
      for (int i = 0; i < 8; ++i) {
        int row = wave * 16 + i * 2 + rl;
        const char* src = h16b + (size_t)(j0 + row) * 512
                        + (size_t)((s5 ^ (row & 7)) << 4);
        gld16(src, dst + i * 1024);
      }
    }
    { // stage V (256 d-rows x 64 j) from linear hmT, source swizzle
      int drow = wave * 64 + (lane >> 3);
      const char* s = hvbs + (size_t)drow * 1024 + jt * 128
                    + (((lane & 7) ^ ((lane >> 3) & 7)) << 4);
      char* dst = (char*)Vt + wave * 8192;
      #pragma unroll
      for (int i = 0; i < 8; ++i) gld16(s + (size_t)i * 8192, dst + i * 1024);
    }
    asm volatile("s_waitcnt vmcnt(0)" ::: "memory");
    __syncthreads();

    f32x4 s[4] = {};
    __builtin_amdgcn_s_setprio(1);
    #pragma unroll
    for (int kb = 0; kb < 8; ++kb)
      #pragma unroll
      for (int cf = 0; cf < 4; ++cf) {
        const int jr = cf * 16 + m16;
        f16x8 kf = *(const f16x8*)&Kt[jr * 256 + (((kb * 4 + g) ^ (m16 & 7)) << 3)];
        s[cf] = MFMA16(qf[kb], kf, s[cf]);
      }
    __builtin_amdgcn_s_setprio(0);
    #pragma unroll
    for (int cf = 0; cf < 4; ++cf) {
      float cm  = mask_lds[j0 + cf * 16 + m16];
      float add = NEGV * (1.f - cm);
      #pragma unroll
      for (int r = 0; r < 4; ++r) s[cf][r] += add;
    }
    float p_[4][4];
    #pragma unroll
    for (int r = 0; r < 4; ++r) {
      float mx = fmaxf(fmaxf(s[0][r], s[1][r]), fmaxf(s[2][r], s[3][r]));
      #pragma unroll
      for (int off = 1; off < 16; off <<= 1) mx = fmaxf(mx, __shfl_xor(mx, off, 64));
      float mnew  = fmaxf(mrun[r], mx);
      float alpha = __expf(mrun[r] - mnew);
      float ps = 0.f;
      #pragma unroll
      for (int cf = 0; cf < 4; ++cf) {
        float pv = __expf(s[cf][r] - mnew);
        p_[cf][r] = pv; ps += pv;
      }
      #pragma unroll
      for (int off = 1; off < 16; off <<= 1) ps += __shfl_xor(ps, off, 64);
      lrun[r] = lrun[r] * alpha + ps;
      mrun[r] = mnew;
      #pragma unroll
      for (int c2 = 0; c2 < 16; ++c2) o[c2][r] *= alpha;
    }
    #pragma unroll
    for (int cf = 0; cf < 4; ++cf)
      #pragma unroll
      for (int r = 0; r < 4; ++r)
        Plds[wave][4 * g + r][cf * 16 + m16] = (f16)p_[cf][r];
    asm volatile("s_waitcnt lgkmcnt(0)" ::: "memory");
    __builtin_amdgcn_sched_barrier(0);
    f16x8 pa[2];
    #pragma unroll
    for (int ks = 0; ks < 2; ++ks) pa[ks] = *(const f16x8*)&Plds[wave][m16][ks * 32 + 8 * g];
    __builtin_amdgcn_s_setprio(1);
    #pragma unroll
    for (int c2 = 0; c2 < 16; ++c2) {
      const int d = c2 * 16 + m16;
      f16x8 v0 = *(const f16x8*)&Vt[d * 64 + (((g)     ^ (m16 & 7)) << 3)];
      f16x8 v1 = *(const f16x8*)&Vt[d * 64 + (((4 + g) ^ (m16 & 7)) << 3)];
      o[c2] = MFMA16(pa[0], v0, o[c2]);
      o[c2] = MFMA16(pa[1], v1, o[c2]);
    }
    __builtin_amdgcn_s_setprio(0);
    __syncthreads();
  }

  #pragma unroll
  for (int r = 0; r < 4; ++r) {
    int irow = i0 + wave * 16 + 4 * g + r;
    float rm  = mask_lds[irow];
    float inv = rm / lrun[r];
    #pragma unroll
    for (int c2 = 0; c2 < 16; ++c2) {
      float val = tanhf(o[c2][r] * inv);
      msg[(size_t)(b * N_ + irow) * H_ + c2 * 16 + m16] = (f16)val;
    }
  }
}

// ---------------------------------------------------------------------------
// Gate GEMM 1: pre = [msg|h] @ Wzr + c. Grid (512 m, 4 n): y<2 -> z, y>=2 -> r.
// ---------------------------------------------------------------------------
__global__ __launch_bounds__(256) void k_gemm_zr(
    const f16* __restrict__ msg, const f16* __restrict__ h16,
    const f16* __restrict__ WzrT, const float* __restrict__ cz,
    const float* __restrict__ cr, f16* __restrict__ z, f16* __restrict__ rh) {
  __shared__ __align__(16) f16 AL[2][128 * 64], BL[2][128 * 64];
  GEMM_PRE();
  const int m0 = blockIdx.x * 128;
  const int n0 = blockIdx.y * 128;
  const size_t a_off = SRC_SWZ(m0);
  const size_t b_off = SRC_IMG(n0, 1024);
  #define STG_ZR(buf, k0)                                               \
    {                                                                   \
      const char* ab = (const char*)((k0) < 256 ? msg : h16);           \
      const char* sa = ab + a_off + (size_t)(((k0) & 255)) * 2;         \
      const char* sb = (const char*)WzrT + b_off + (size_t)(k0) * 2;    \
      char* da = (char*)&AL[buf][0] + wave * 4096;                      \
      char* db = (char*)&BL[buf][0] + wave * 4096;                      \
      _Pragma("unroll")                                                 \
      for (int i_ = 0; i_ < 4; ++i_) {                                  \
        gld16(sa + i_ * 4096, da + i_ * 1024);                          \
        gld16(sb + i_ * 8192, db + i_ * 1024);                          \
      }                                                                 \
    }
  GEMM_LOOP(512, STG_ZR);
  const int is_r = blockIdx.y >> 1;
  #pragma unroll
  for (int mi = 0; mi < 4; ++mi)
    #pragma unroll
    for (int ni = 0; ni < 4; ++ni) {
      int ncol = (blockIdx.y & 1) * 128 + wc + ni * 16 + m16;   // col in 256-wide block
      #pragma unroll
      for (int r = 0; r < 4; ++r) {
        int grow = m0 + wr + mi * 16 + 4 * g + r;
        int bb = grow >> 9;
        float a = acc[mi][ni][r];
        size_t oidx = (size_t)grow * 256 + ncol;
        if (!is_r) {
          float v = a + cz[bb * 256 + ncol];
          z[oidx] = (f16)(1.f / (1.f + __expf(-v)));
        } else {
          float v  = a + cr[bb * 256 + ncol];
          float rr = 1.f / (1.f + __expf(-v));
          rh[oidx] = (f16)(rr * (float)h16[oidx]);
        }
      }
    }
}

// ---------------------------------------------------------------------------
// Gate GEMM 2: h_tilde = tanh([msg|rh] @ Whc + c_h); out = (1-z)*h + z*h_tilde
// Grid (512 m, 2 n).
// ---------------------------------------------------------------------------
__global__ __launch_bounds__(256) void k_gemm_ht(
    const f16* __restrict__ msg, const f16* __restrict__ rh,
    const f16* __restrict__ WhcT, const float* __restrict__ ch,
    const f16* __restrict__ z, const f16* __restrict__ h16,
    float* __restrict__ out) {
  __shared__ __align__(16) f16 AL[2][128 * 64], BL[2][128 * 64];
  GEMM_PRE();
  const int m0 = blockIdx.x * 128;
  const int n0 = blockIdx.y * 128;
  const size_t a_off = SRC_SWZ(m0);
  const size_t b_off = SRC_IMG(n0, 1024);
  #define STG_HT(buf, k0)                                               \
    {                                                                   \
      const char* ab = (const char*)((k0) < 256 ? msg : rh);            \
      const char* sa = ab + a_off + (size_t)(((k0) & 255)) * 2;         \
      const char* sb = (const char*)WhcT + b_off + (size_t)(k0) * 2;    \
      char* da = (char*)&AL[buf][0] + wave * 4096;                      \
      char* db = (char*)&BL[buf][0] + wave * 4096;                      \
      _Pragma("unroll")                                                 \
      for (int i_ = 0; i_ < 4; ++i_) {                                  \
        gld16(sa + i_ * 4096, da + i_ * 1024);                          \
        gld16(sb + i_ * 8192, db + i_ * 1024);                          \
      }                                                                 \
    }
  GEMM_LOOP(512, STG_HT);
  #pragma unroll
  for (int mi = 0; mi < 4; ++mi)
    #pragma unroll
    for (int ni = 0; ni < 4; ++ni) {
      int gcol = n0 + wc + ni * 16 + m16;
      #pragma unroll
      for (int r = 0; r < 4; ++r) {
        int grow = m0 + wr + mi * 16 + 4 * g + r;
        int bb = grow >> 9;
        size_t oidx = (size_t)grow * 256 + gcol;
        float pre = acc[mi][ni][r] + ch[bb * 256 + gcol];
        float htl = tanhf(pre);
        float zv  = (float)z[oidx];
        float hv  = (float)h16[oidx];
        out[oidx] = (1.f - zv) * hv + zv * htl;
      }
    }
}

// ---------------------------------------------------------------------------
extern "C" void kernel_launch(void* const* d_in, const int* in_sizes, int n_in,
                              void* d_out, int out_size, void* d_ws, size_t ws_size,
                              hipStream_t stream) {
  const float* h    = (const float*)d_in[0];
  const float* jets = (const float*)d_in[1];
  const float* mask = (const float*)d_in[2];
  const float* Wa   = (const float*)d_in[3];
  const float* ba   = (const float*)d_in[4];
  const float* Wm   = (const float*)d_in[5];
  const float* bm   = (const float*)d_in[6];
  const float* Wz   = (const float*)d_in[7];
  const float* bz   = (const float*)d_in[8];
  const float* Wr   = (const float*)d_in[9];
  const float* br   = (const float*)d_in[10];
  const float* Wh   = (const float*)d_in[11];
  const float* bh   = (const float*)d_in[12];
  float* out = (float*)d_out;

  char* ws = (char*)d_ws;
  size_t off = 0;
  auto alloc = [&](size_t bytes) -> void* {
    void* p = ws + off;
    off += (bytes + 255) & ~(size_t)255;
    return p;
  };
  // big: q (f16, 32MB) during attention; z (f16) + rh (f16) afterwards.
  char*   big   = (char*) alloc((size_t)ROWS * H_ * 4);
  f16*    hmT   = (f16*)  alloc((size_t)B_ * H_ * N_ * 2);
  f16*    msg   = (f16*)  alloc((size_t)ROWS * H_ * 2);
  f16*    h16   = (f16*)  alloc((size_t)ROWS * H_ * 2);
  float*  hmean4= (float*)alloc((size_t)B_ * 4 * H_ * 4);
  float*  cz    = (float*)alloc((size_t)B_ * H_ * 4);
  float*  cr    = (float*)alloc((size_t)B_ * H_ * 4);
  float*  chv   = (float*)alloc((size_t)B_ * H_ * 4);
  f16*    WaT   = (f16*)  alloc(65536 * 2);
  f16*    WmT   = (f16*)  alloc(65536 * 2);
  f16*    WzrT  = (f16*)  alloc(262144 * 2);
  f16*    WhcT  = (f16*)  alloc(131072 * 2);
  f16* q  = (f16*)big;
  f16* z  = (f16*)big;                                     // q dead after attn
  f16* rh = (f16*)(big + (size_t)ROWS * H_ * 2);
  if (off > ws_size) return;  // workspace insufficient

  k_prep    <<<2048, 256, 0, stream>>>(Wa, Wm, Wz, Wr, Wh, WaT, WmT, WzrT, WhcT);
  k_hmean   <<<dim3(B_, 4), H_, 0, stream>>>(h, hmean4);
  k_cvec    <<<B_, H_, 0, stream>>>(hmean4, jets, Wz, Wr, Wh, bz, br, bh, cz, cr, chv);
  k_h16     <<<8192, 256, 0, stream>>>(h, h16);
  k_gemm_q  <<<dim3(512, 2), 256, 0, stream>>>(h16, WaT, ba, q);
  k_gemm_hmT<<<dim3(128, 8), 256, 0, stream>>>(h16, WmT, bm, hmT);
  k_attn4   <<<dim3(128, 8), 256, 0, stream>>>(q, mask, hmT, h16, msg);
  k_gemm_zr <<<dim3(512, 4), 256, 0, stream>>>(msg, h16, WzrT, cz, cr, z, rh);
  k_gemm_ht <<<dim3(512, 2), 256, 0, stream>>>(msg, rh, WhcT, chv, z, h16, out);
}

// Round 7
// 539.590 us; speedup vs baseline: 1.2756x; 1.0133x over previous
//
#include <hip/hip_runtime.h>

// Problem constants (from reference): B=128, N=512, H=256, F_JET=8, gin=776.
#define B_   128
#define N_   512
#define H_   256
#define FJ   8
#define ROWS (B_ * N_)          // 65536 flattened vertex rows
#define NEGV (-1e9f)

typedef _Float16 f16;
typedef __attribute__((ext_vector_type(8))) f16   f16x8;   // one MFMA A/B fragment (4 VGPRs)
typedef __attribute__((ext_vector_type(4))) float f32x4;   // one MFMA C/D fragment

static __device__ inline f32x4 MFMA16(f16x8 a, f16x8 b, f32x4 c) {
  return __builtin_amdgcn_mfma_f32_16x16x32_f16(a, b, c, 0, 0, 0);
}

// global -> LDS direct copy, 16B per lane. LDS ptr must be wave-uniform; HW adds lane*16.
static __device__ inline void gld16(const void* g, void* l) {
  __builtin_amdgcn_global_load_lds(
      (const __attribute__((address_space(1))) void*)g,
      (__attribute__((address_space(3))) void*)(uintptr_t)l,
      16, 0, 0);
}

// ---------------------------------------------------------------------------
// Prep: transpose/convert weights to fp16 with the LDS bank-swizzle BAKED IN:
// within each row, 16B-chunk c is stored at slot c^(row&7)  (8-chunk window).
// ---------------------------------------------------------------------------
__global__ void k_prep(const float* __restrict__ Wa, const float* __restrict__ Wm,
                       const float* __restrict__ Wz, const float* __restrict__ Wr,
                       const float* __restrict__ Wh,
                       f16* __restrict__ WaT, f16* __restrict__ WmT,
                       f16* __restrict__ WzrT, f16* __restrict__ WhcT) {
  int idx = blockIdx.x * 256 + threadIdx.x;
  if (idx < 65536) {
    int d = idx >> 8, k = idx & 255;
    int kk = ((((k >> 3) ^ (d & 7)) << 3) | (k & 7));
    WaT[d * 256 + kk] = (f16)Wa[k * 256 + d];
  } else if (idx < 131072) {
    int t = idx - 65536;
    int d = t >> 8, k = t & 255;
    int kk = ((((k >> 3) ^ (d & 7)) << 3) | (k & 7));
    WmT[d * 256 + kk] = (f16)Wm[k * 256 + d];
  } else if (idx < 131072 + 262144) {
    int t = idx - 131072;
    int n = t >> 9, k = t & 511;
    const float* src = (n < 256) ? Wz : Wr;
    int np  = n & 255;
    int row = (k < 256) ? k : (264 + k);   // 520 + (k - 256)
    int kk = ((((k >> 3) ^ (n & 7)) << 3) | (k & 7));
    WzrT[n * 512 + kk] = (f16)src[row * 256 + np];
  } else {
    int t = idx - (131072 + 262144);       // < 131072
    int n = t >> 9, k = t & 511;
    int row = (k < 256) ? k : (264 + k);
    int kk = ((((k >> 3) ^ (n & 7)) << 3) | (k & 7));
    WhcT[n * 512 + kk] = (f16)Wh[row * 256 + n];
  }
}

// partial sums: hmean4[b][part][d] = sum_{n in part} h[b][n][d]
__global__ void k_hmean(const float* __restrict__ h, float* __restrict__ hmean4) {
  int b = blockIdx.x, part = blockIdx.y, d = threadIdx.x;
  const float* p = h + ((size_t)b * N_ + part * 128) * H_ + d;
  float s = 0.f;
  #pragma unroll 8
  for (int n = 0; n < 128; ++n) s += p[n * H_];
  hmean4[(b * 4 + part) * H_ + d] = s;
}

// Per-batch GRU constants: c_*[b][d] = bias[d] + h_mean[b]·W*[256:512,d] + jets[b]·W*[512:520,d]
__global__ void k_cvec(const float* __restrict__ hmean4, const float* __restrict__ jets,
                       const float* __restrict__ Wz, const float* __restrict__ Wr,
                       const float* __restrict__ Wh,
                       const float* __restrict__ bz, const float* __restrict__ br,
                       const float* __restrict__ bh,
                       float* __restrict__ cz, float* __restrict__ cr, float* __restrict__ ch) {
  __shared__ float hm[H_];
  __shared__ float jt[FJ];
  int b = blockIdx.x, d = threadIdx.x;
  hm[d] = (hmean4[(b * 4 + 0) * H_ + d] + hmean4[(b * 4 + 1) * H_ + d] +
           hmean4[(b * 4 + 2) * H_ + d] + hmean4[(b * 4 + 3) * H_ + d]) * (1.f / N_);
  if (d < FJ) jt[d] = jets[b * FJ + d];
  __syncthreads();
  float az = bz[d], ar = br[d], ah = bh[d];
  #pragma unroll 4
  for (int k = 0; k < H_; ++k) {
    float m = hm[k];
    az += m * Wz[(256 + k) * 256 + d];
    ar += m * Wr[(256 + k) * 256 + d];
    ah += m * Wh[(256 + k) * 256 + d];
  }
  #pragma unroll
  for (int f = 0; f < FJ; ++f) {
    float j = jt[f];
    az += j * Wz[(512 + f) * 256 + d];
    ar += j * Wr[(512 + f) * 256 + d];
    ah += j * Wh[(512 + f) * 256 + d];
  }
  cz[b * H_ + d] = az;
  cr[b * H_ + d] = ar;
  ch[b * H_ + d] = ah;
}

// h16 = linear f16 copy of h
__global__ void k_h16(const float* __restrict__ h, f16* __restrict__ h16) {
  int t  = blockIdx.x * 256 + threadIdx.x;   // chunk id: 2,097,152
  const float* p = h + (size_t)t * 8;
  f32x4 v0 = *(const f32x4*)p;
  f32x4 v1 = *(const f32x4*)(p + 4);
  f16x8 hv;
  #pragma unroll
  for (int e = 0; e < 4; ++e) { hv[e] = (f16)v0[e]; hv[4 + e] = (f16)v1[e]; }
  *(f16x8*)&h16[(size_t)t * 8] = hv;
}

// ===========================================================================
// Shared GEMM geometry: block 128x128, 4 waves 2x2 (wave tile 64x64, acc[4][4]),
// BK=64, double-buffered LDS, 2-phase counted-vmcnt pipeline (see R6 ledger).
// ===========================================================================
#define GEMM_PRE()                                                      \
  const int tid = threadIdx.x, lane = tid & 63, wave = tid >> 6;        \
  const int g = lane >> 4, m16 = lane & 15;                             \
  const int wr = (wave >> 1) * 64, wc = (wave & 1) * 64;                \
  f32x4 acc[4][4] = {};

#define GEMM_COMPUTE(Ab, Bb)                                            \
  _Pragma("unroll")                                                     \
  for (int ks = 0; ks < 2; ++ks) {                                      \
    f16x8 af[4], bf[4];                                                 \
    _Pragma("unroll")                                                   \
    for (int mi = 0; mi < 4; ++mi)                                      \
      af[mi] = *(const f16x8*)((const char*)(Ab) + (wr + mi * 16 + m16) * 128 \
                               + (((ks * 4 + g) ^ (m16 & 7)) << 4));    \
    _Pragma("unroll")                                                   \
    for (int ni = 0; ni < 4; ++ni)                                      \
      bf[ni] = *(const f16x8*)((const char*)(Bb) + (wc + ni * 16 + m16) * 128 \
                               + (((ks * 4 + g) ^ (m16 & 7)) << 4));    \
    _Pragma("unroll")                                                   \
    for (int mi = 0; mi < 4; ++mi)                                      \
      _Pragma("unroll")                                                 \
      for (int ni = 0; ni < 4; ++ni)                                    \
        acc[mi][ni] = MFMA16(af[mi], bf[ni], acc[mi][ni]);              \
  }

// 2-phase K-loop driver; STAGEFN(buf, k0) must issue exactly 8 gld16.
#define GEMM_LOOP(KMAX, STAGEFN)                                        \
  STAGEFN(0, 0);                                                       \
  for (int kt = 0; kt < (KMAX) / 64; ++kt) {                            \
    const int cur = kt & 1;                                             \
    if (kt < (KMAX) / 64 - 1) {                                         \
      STAGEFN(cur ^ 1, (kt + 1) * 64);                                  \
      asm volatile("s_waitcnt vmcnt(8)" ::: "memory");                  \
    } else {                                                            \
      asm volatile("s_waitcnt vmcnt(0)" ::: "memory");                  \
    }                                                                   \
    __builtin_amdgcn_sched_barrier(0);                                  \
    __builtin_amdgcn_s_barrier();                                       \
    __builtin_amdgcn_sched_barrier(0);                                  \
    GEMM_COMPUTE(&AL[cur][0], &BL[cur][0]);                             \
    __builtin_amdgcn_s_barrier();                                       \
    __builtin_amdgcn_sched_barrier(0);                                  \
  }

// per-lane source offsets
#define SRC_SWZ(row0) ((size_t)(row0 + wave * 32 + (lane >> 3)) * 512 \
                       + (size_t)(((lane & 7) ^ ((lane >> 3) & 7)) << 4))
#define SRC_IMG(row0, RS) ((size_t)(row0 + wave * 32 + (lane >> 3)) * (RS) \
                           + (size_t)((lane & 7) << 4))

// ---------------------------------------------------------------------------
// q = f16(h @ Wa + ba). Grid (512 m, 2 n).
// ---------------------------------------------------------------------------
__global__ __launch_bounds__(256) void k_gemm_q(
    const f16* __restrict__ h16, const f16* __restrict__ WaT,
    const float* __restrict__ ba, f16* __restrict__ q) {
  __shared__ __align__(16) f16 AL[2][128 * 64], BL[2][128 * 64];
  GEMM_PRE();
  const int m0 = blockIdx.x * 128, n0 = blockIdx.y * 128;
  const size_t a_off = SRC_SWZ(m0);
  const size_t b_off = SRC_IMG(n0, 512);
  #define STG_Q(buf, k0)                                                \
    {                                                                   \
      const char* sa = (const char*)h16 + a_off + (size_t)(k0) * 2;     \
      const char* sb = (const char*)WaT + b_off + (size_t)(k0) * 2;     \
      char* da = (char*)&AL[buf][0] + wave * 4096;                      \
      char* db = (char*)&BL[buf][0] + wave * 4096;                      \
      _Pragma("unroll")                                                 \
      for (int i_ = 0; i_ < 4; ++i_) {                                  \
        gld16(sa + i_ * 4096, da + i_ * 1024);                          \
        gld16(sb + i_ * 4096, db + i_ * 1024);                          \
      }                                                                 \
    }
  GEMM_LOOP(256, STG_Q);
  #pragma unroll
  for (int mi = 0; mi < 4; ++mi)
    #pragma unroll
    for (int ni = 0; ni < 4; ++ni) {
      int gcol = n0 + wc + ni * 16 + m16;
      float bias = ba[gcol];
      #pragma unroll
      for (int r = 0; r < 4; ++r) {
        int grow = m0 + wr + mi * 16 + 4 * g + r;
        q[(size_t)grow * 256 + gcol] = (f16)(acc[mi][ni][r] + bias);
      }
    }
}

// ---------------------------------------------------------------------------
// hmT[b][d][n] = f16( (h[b] @ Wm + bm)^T ). Grid (128 batches, 8).
// ---------------------------------------------------------------------------
__global__ __launch_bounds__(256) void k_gemm_hmT(
    const f16* __restrict__ h16, const f16* __restrict__ WmT,
    const float* __restrict__ bm, f16* __restrict__ hmT) {
  __shared__ __align__(16) f16 AL[2][128 * 64], BL[2][128 * 64];
  GEMM_PRE();
  const int b = blockIdx.x;
  const int m0 = (blockIdx.y >> 2) * 128, n0 = (blockIdx.y & 3) * 128;
  const size_t a_off = SRC_IMG(m0, 512);
  const size_t b_off = SRC_SWZ(b * 512 + n0);
  #define STG_HM(buf, k0)                                               \
    {                                                                   \
      const char* sa = (const char*)WmT + a_off + (size_t)(k0) * 2;     \
      const char* sb = (const char*)h16 + b_off + (size_t)(k0) * 2;     \
      char* da = (char*)&AL[buf][0] + wave * 4096;                      \
      char* db = (char*)&BL[buf][0] + wave * 4096;                      \
      _Pragma("unroll")                                                 \
      for (int i_ = 0; i_ < 4; ++i_) {                                  \
        gld16(sa + i_ * 4096, da + i_ * 1024);                          \
        gld16(sb + i_ * 4096, db + i_ * 1024);                          \
      }                                                                 \
    }
  GEMM_LOOP(256, STG_HM);
  #pragma unroll
  for (int mi = 0; mi < 4; ++mi)
    #pragma unroll
    for (int r = 0; r < 4; ++r) {
      int d = m0 + wr + mi * 16 + 4 * g + r;
      float bias = bm[d];
      #pragma unroll
      for (int ni = 0; ni < 4; ++ni) {
        int n = n0 + wc + ni * 16 + m16;
        hmT[(size_t)b * H_ * N_ + (size_t)d * N_ + n] = (f16)(acc[mi][ni][r] + bias);
      }
    }
}

// ---------------------------------------------------------------------------
// Flash attention + DTNN message, v5: software-pipelined staging.
// Per-iteration ledger (2 raw barriers):
//   [top]  vmcnt(0): K(jt) landed (only K outstanding here)
//          s_barrier #1: K visible to all; Vt free (all waves' prev PV done)
//          issue stage V(jt)      -> latency hidden under QK+softmax
//          QK from Kt; mask; online softmax
//   [mid]  vmcnt(0): V(jt) landed
//          s_barrier #2: V visible; Kt free (all waves' QK done)
//          if jt<7: issue stage K(jt+1) -> latency hidden under P-rt + PV
//          P roundtrip (lgkmcnt 0); PV from Vt
//   loop -> next top barrier guarantees PV reads of Vt done before V(jt+1).
// ---------------------------------------------------------------------------
__global__ __launch_bounds__(256) void k_attn5(
    const f16* __restrict__ q, const float* __restrict__ mask,
    const f16* __restrict__ hmT, const f16* __restrict__ h16,
    f16* __restrict__ msg) {
  __shared__ __align__(16) f16 Kt[64 * 256];    // 32KB
  __shared__ __align__(16) f16 Vt[256 * 64];    // 32KB
  __shared__ __align__(16) f16 Plds[4][16][72];
  __shared__ float mask_lds[N_];
  const int tid = threadIdx.x, lane = tid & 63, wave = tid >> 6;
  const int g = lane >> 4, m16 = lane & 15;
  const int b = blockIdx.x, i0 = blockIdx.y * 64;

  mask_lds[tid]       = mask[b * N_ + tid];
  mask_lds[tid + 256] = mask[b * N_ + tid + 256];

  const f16* qp = q + (size_t)(b * N_ + i0 + wave * 16 + m16) * H_ + 8 * g;
  f16x8 qf[8];
  #pragma unroll
  for (int kb = 0; kb < 8; ++kb) qf[kb] = *(const f16x8*)(qp + kb * 32);

  f32x4 o[16] = {};
  float mrun[4], lrun[4];
  #pragma unroll
  for (int r = 0; r < 4; ++r) { mrun[r] = -3.0e38f; lrun[r] = 0.f; }

  const char* hvbs = (const char*)(hmT + (size_t)b * H_ * N_);
  const char* h16b = (const char*)(h16 + (size_t)b * N_ * H_);

  // K stage: LDS row j, slot s holds source chunk s^(j&7)
  auto stageK = [&](int jt) {
    const int rl = lane >> 5, s5 = lane & 31;
    char* dst = (char*)Kt + wave * 8192;
    #pragma unroll
    for (int i = 0; i < 8; ++i) {
      int row = wave * 16 + i * 2 + rl;
      const char* src = h16b + (size_t)(jt * 64 + row) * 512
                      + (size_t)((s5 ^ (row & 7)) << 4);
      gld16(src, dst + i * 1024);
    }
  };
  // V stage: LDS row d (stride 128B), slot s holds source chunk s^(d&7)
  auto stageV = [&](int jt) {
    int drow = wave * 64 + (lane >> 3);
    const char* s = hvbs + (size_t)drow * 1024 + jt * 128
                  + (((lane & 7) ^ ((lane >> 3) & 7)) << 4);
    char* dst = (char*)Vt + wave * 8192;
    #pragma unroll
    for (int i = 0; i < 8; ++i) gld16(s + (size_t)i * 8192, dst + i * 1024);
  };

  // first __syncthreads so mask_lds is visible before softmax reads it
  stageK(0);
  __builtin_amdgcn_sched_barrier(0);

  for (int jt = 0; jt < 8; ++jt) {
    const int j0 = jt * 64;
    asm volatile("s_waitcnt vmcnt(0)" ::: "memory");   // K(jt) landed
    __builtin_amdgcn_sched_barrier(0);
    __builtin_amdgcn_s_barrier();                      // #1: K visible, Vt free
    __builtin_amdgcn_sched_barrier(0);
    stageV(jt);                                        // hide under QK+softmax
    __builtin_amdgcn_sched_barrier(0);

    // ---- S = q·K^T
    f32x4 s[4] = {};
    __builtin_amdgcn_s_setprio(1);
    #pragma unroll
    for (int kb = 0; kb < 8; ++kb)
      #pragma unroll
      for (int cf = 0; cf < 4; ++cf) {
        const int jr = cf * 16 + m16;
        f16x8 kf = *(const f16x8*)&Kt[jr * 256 + (((kb * 4 + g) ^ (m16 & 7)) << 3)];
        s[cf] = MFMA16(qf[kb], kf, s[cf]);
      }
    __builtin_amdgcn_s_setprio(0);
    // ---- column mask
    #pragma unroll
    for (int cf = 0; cf < 4; ++cf) {
      float cm  = mask_lds[j0 + cf * 16 + m16];
      float add = NEGV * (1.f - cm);
      #pragma unroll
      for (int r = 0; r < 4; ++r) s[cf][r] += add;
    }
    // ---- online softmax (rows live in 16-lane groups)
    float p_[4][4];
    #pragma unroll
    for (int r = 0; r < 4; ++r) {
      float mx = fmaxf(fmaxf(s[0][r], s[1][r]), fmaxf(s[2][r], s[3][r]));
      #pragma unroll
      for (int off = 1; off < 16; off <<= 1) mx = fmaxf(mx, __shfl_xor(mx, off, 64));
      float mnew  = fmaxf(mrun[r], mx);
      float alpha = __expf(mrun[r] - mnew);
      float ps = 0.f;
      #pragma unroll
      for (int cf = 0; cf < 4; ++cf) {
        float pv = __expf(s[cf][r] - mnew);
        p_[cf][r] = pv; ps += pv;
      }
      #pragma unroll
      for (int off = 1; off < 16; off <<= 1) ps += __shfl_xor(ps, off, 64);
      lrun[r] = lrun[r] * alpha + ps;
      mrun[r] = mnew;
      #pragma unroll
      for (int c2 = 0; c2 < 16; ++c2) o[c2][r] *= alpha;
    }

    asm volatile("s_waitcnt vmcnt(0)" ::: "memory");   // V(jt) landed
    __builtin_amdgcn_sched_barrier(0);
    __builtin_amdgcn_s_barrier();                      // #2: V visible, Kt free
    __builtin_amdgcn_sched_barrier(0);
    if (jt < 7) stageK(jt + 1);                        // hide under P-rt + PV
    __builtin_amdgcn_sched_barrier(0);

    // ---- P -> LDS (C-layout) -> A-fragment layout (wave-local round trip)
    #pragma unroll
    for (int cf = 0; cf < 4; ++cf)
      #pragma unroll
      for (int r = 0; r < 4; ++r)
        Plds[wave][4 * g + r][cf * 16 + m16] = (f16)p_[cf][r];
    asm volatile("s_waitcnt lgkmcnt(0)" ::: "memory");
    __builtin_amdgcn_sched_barrier(0);
    f16x8 pa[2];
    #pragma unroll
    for (int ks = 0; ks < 2; ++ks) pa[ks] = *(const f16x8*)&Plds[wave][m16][ks * 32 + 8 * g];
    // ---- PV from Vt
    __builtin_amdgcn_s_setprio(1);
    #pragma unroll
    for (int c2 = 0; c2 < 16; ++c2) {
      const int d = c2 * 16 + m16;
      f16x8 v0 = *(const f16x8*)&Vt[d * 64 + (((g)     ^ (m16 & 7)) << 3)];
      f16x8 v1 = *(const f16x8*)&Vt[d * 64 + (((4 + g) ^ (m16 & 7)) << 3)];
      o[c2] = MFMA16(pa[0], v0, o[c2]);
      o[c2] = MFMA16(pa[1], v1, o[c2]);
    }
    __builtin_amdgcn_s_setprio(0);
  }

  // epilogue: msg = tanh(row_mask * O / l)
  #pragma unroll
  for (int r = 0; r < 4; ++r) {
    int irow = i0 + wave * 16 + 4 * g + r;
    float rm  = mask_lds[irow];
    float inv = rm / lrun[r];
    #pragma unroll
    for (int c2 = 0; c2 < 16; ++c2) {
      float val = tanhf(o[c2][r] * inv);
      msg[(size_t)(b * N_ + irow) * H_ + c2 * 16 + m16] = (f16)val;
    }
  }
}

// ---------------------------------------------------------------------------
// Gate GEMM 1: pre = [msg|h] @ Wzr + c. Grid (512 m, 4 n): y<2 -> z, y>=2 -> r.
// ---------------------------------------------------------------------------
__global__ __launch_bounds__(256) void k_gemm_zr(
    const f16* __restrict__ msg, const f16* __restrict__ h16,
    const f16* __restrict__ WzrT, const float* __restrict__ cz,
    const float* __restrict__ cr, f16* __restrict__ z, f16* __restrict__ rh) {
  __shared__ __align__(16) f16 AL[2][128 * 64], BL[2][128 * 64];
  GEMM_PRE();
  const int m0 = blockIdx.x * 128;
  const int n0 = blockIdx.y * 128;
  const size_t a_off = SRC_SWZ(m0);
  const size_t b_off = SRC_IMG(n0, 1024);
  #define STG_ZR(buf, k0)                                               \
    {                                                                   \
      const char* ab = (const char*)((k0) < 256 ? msg : h16);           \
      const char* sa = ab + a_off + (size_t)(((k0) & 255)) * 2;         \
      const char* sb = (const char*)WzrT + b_off + (size_t)(k0) * 2;    \
      char* da = (char*)&AL[buf][0] + wave * 4096;                      \
      char* db = (char*)&BL[buf][0] + wave * 4096;                      \
      _Pragma("unroll")                                                 \
      for (int i_ = 0; i_ < 4; ++i_) {                                  \
        gld16(sa + i_ * 4096, da + i_ * 1024);                          \
        gld16(sb + i_ * 8192, db + i_ * 1024);                          \
      }                                                                 \
    }
  GEMM_LOOP(512, STG_ZR);
  const int is_r = blockIdx.y >> 1;
  #pragma unroll
  for (int mi = 0; mi < 4; ++mi)
    #pragma unroll
    for (int ni = 0; ni < 4; ++ni) {
      int ncol = (blockIdx.y & 1) * 128 + wc + ni * 16 + m16;   // col in 256-wide block
      #pragma unroll
      for (int r = 0; r < 4; ++r) {
        int grow = m0 + wr + mi * 16 + 4 * g + r;
        int bb = grow >> 9;
        float a = acc[mi][ni][r];
        size_t oidx = (size_t)grow * 256 + ncol;
        if (!is_r) {
          float v = a + cz[bb * 256 + ncol];
          z[oidx] = (f16)(1.f / (1.f + __expf(-v)));
        } else {
          float v  = a + cr[bb * 256 + ncol];
          float rr = 1.f / (1.f + __expf(-v));
          rh[oidx] = (f16)(rr * (float)h16[oidx]);
        }
      }
    }
}

// ---------------------------------------------------------------------------
// Gate GEMM 2: h_tilde = tanh([msg|rh] @ Whc + c_h); out = (1-z)*h + z*h_tilde
// Grid (512 m, 2 n).
// ---------------------------------------------------------------------------
__global__ __launch_bounds__(256) void k_gemm_ht(
    const f16* __restrict__ msg, const f16* __restrict__ rh,
    const f16* __restrict__ WhcT, const float* __restrict__ ch,
    const f16* __restrict__ z, const f16* __restrict__ h16,
    float* __restrict__ out) {
  __shared__ __align__(16) f16 AL[2][128 * 64], BL[2][128 * 64];
  GEMM_PRE();
  const int m0 = blockIdx.x * 128;
  const int n0 = blockIdx.y * 128;
  const size_t a_off = SRC_SWZ(m0);
  const size_t b_off = SRC_IMG(n0, 1024);
  #define STG_HT(buf, k0)                                               \
    {                                                                   \
      const char* ab = (const char*)((k0) < 256 ? msg : rh);            \
      const char* sa = ab + a_off + (size_t)(((k0) & 255)) * 2;         \
      const char* sb = (const char*)WhcT + b_off + (size_t)(k0) * 2;    \
      char* da = (char*)&AL[buf][0] + wave * 4096;                      \
      char* db = (char*)&BL[buf][0] + wave * 4096;                      \
      _Pragma("unroll")                                                 \
      for (int i_ = 0; i_ < 4; ++i_) {                                  \
        gld16(sa + i_ * 4096, da + i_ * 1024);                          \
        gld16(sb + i_ * 8192, db + i_ * 1024);                          \
      }                                                                 \
    }
  GEMM_LOOP(512, STG_HT);
  #pragma unroll
  for (int mi = 0; mi < 4; ++mi)
    #pragma unroll
    for (int ni = 0; ni < 4; ++ni) {
      int gcol = n0 + wc + ni * 16 + m16;
      #pragma unroll
      for (int r = 0; r < 4; ++r) {
        int grow = m0 + wr + mi * 16 + 4 * g + r;
        int bb = grow >> 9;
        size_t oidx = (size_t)grow * 256 + gcol;
        float pre = acc[mi][ni][r] + ch[bb * 256 + gcol];
        float htl = tanhf(pre);
        float zv  = (float)z[oidx];
        float hv  = (float)h16[oidx];
        out[oidx] = (1.f - zv) * hv + zv * htl;
      }
    }
}

// ---------------------------------------------------------------------------
extern "C" void kernel_launch(void* const* d_in, const int* in_sizes, int n_in,
                              void* d_out, int out_size, void* d_ws, size_t ws_size,
                              hipStream_t stream) {
  const float* h    = (const float*)d_in[0];
  const float* jets = (const float*)d_in[1];
  const float* mask = (const float*)d_in[2];
  const float* Wa   = (const float*)d_in[3];
  const float* ba   = (const float*)d_in[4];
  const float* Wm   = (const float*)d_in[5];
  const float* bm   = (const float*)d_in[6];
  const float* Wz   = (const float*)d_in[7];
  const float* bz   = (const float*)d_in[8];
  const float* Wr   = (const float*)d_in[9];
  const float* br   = (const float*)d_in[10];
  const float* Wh   = (const float*)d_in[11];
  const float* bh   = (const float*)d_in[12];
  float* out = (float*)d_out;

  char* ws = (char*)d_ws;
  size_t off = 0;
  auto alloc = [&](size_t bytes) -> void* {
    void* p = ws + off;
    off += (bytes + 255) & ~(size_t)255;
    return p;
  };
  // big: q (f16, 32MB) during attention; z (f16) + rh (f16) afterwards.
  char*   big   = (char*) alloc((size_t)ROWS * H_ * 4);
  f16*    hmT   = (f16*)  alloc((size_t)B_ * H_ * N_ * 2);
  f16*    msg   = (f16*)  alloc((size_t)ROWS * H_ * 2);
  f16*    h16   = (f16*)  alloc((size_t)ROWS * H_ * 2);
  float*  hmean4= (float*)alloc((size_t)B_ * 4 * H_ * 4);
  float*  cz    = (float*)alloc((size_t)B_ * H_ * 4);
  float*  cr    = (float*)alloc((size_t)B_ * H_ * 4);
  float*  chv   = (float*)alloc((size_t)B_ * H_ * 4);
  f16*    WaT   = (f16*)  alloc(65536 * 2);
  f16*    WmT   = (f16*)  alloc(65536 * 2);
  f16*    WzrT  = (f16*)  alloc(262144 * 2);
  f16*    WhcT  = (f16*)  alloc(131072 * 2);
  f16* q  = (f16*)big;
  f16* z  = (f16*)big;                                     // q dead after attn
  f16* rh = (f16*)(big + (size_t)ROWS * H_ * 2);
  if (off > ws_size) return;  // workspace insufficient

  k_prep    <<<2048, 256, 0, stream>>>(Wa, Wm, Wz, Wr, Wh, WaT, WmT, WzrT, WhcT);
  k_hmean   <<<dim3(B_, 4), H_, 0, stream>>>(h, hmean4);
  k_cvec    <<<B_, H_, 0, stream>>>(hmean4, jets, Wz, Wr, Wh, bz, br, bh, cz, cr, chv);
  k_h16     <<<8192, 256, 0, stream>>>(h, h16);
  k_gemm_q  <<<dim3(512, 2), 256, 0, stream>>>(h16, WaT, ba, q);
  k_gemm_hmT<<<dim3(128, 8), 256, 0, stream>>>(h16, WmT, bm, hmT);
  k_attn5   <<<dim3(128, 8), 256, 0, stream>>>(q, mask, hmT, h16, msg);
  k_gemm_zr <<<dim3(512, 4), 256, 0, stream>>>(msg, h16, WzrT, cz, cr, z, rh);
  k_gemm_ht <<<dim3(512, 2), 256, 0, stream>>>(msg, rh, WhcT, chv, z, h16, out);
}

// Round 9
// 437.604 us; speedup vs baseline: 1.5728x; 1.2331x over previous
//
#include <hip/hip_runtime.h>

// Problem constants (from reference): B=128, N=512, H=256, F_JET=8, gin=776.
#define B_   128
#define N_   512
#define H_   256
#define FJ   8
#define ROWS (B_ * N_)          // 65536 flattened vertex rows
#define NEGV (-1e9f)

typedef _Float16 f16;
typedef __attribute__((ext_vector_type(8)))  f16   f16x8;    // MFMA A/B fragment (4 VGPRs)
typedef __attribute__((ext_vector_type(4)))  float f32x4;    // 16x16 C/D fragment
typedef __attribute__((ext_vector_type(16))) float f32x16;   // 32x32 C/D fragment

static __device__ inline f32x4 MFMA16(f16x8 a, f16x8 b, f32x4 c) {
  return __builtin_amdgcn_mfma_f32_16x16x32_f16(a, b, c, 0, 0, 0);
}
static __device__ inline f32x16 MFMA32(f16x8 a, f16x8 b, f32x16 c) {
  return __builtin_amdgcn_mfma_f32_32x32x16_f16(a, b, c, 0, 0, 0);
}

// global -> LDS direct copy, 16B per lane. LDS ptr must be wave-uniform; HW adds lane*16.
static __device__ inline void gld16(const void* g, void* l) {
  __builtin_amdgcn_global_load_lds(
      (const __attribute__((address_space(1))) void*)g,
      (__attribute__((address_space(3))) void*)(uintptr_t)l,
      16, 0, 0);
}

// pack two f32 -> 2 f16 in one u32 (v_cvt_pkrtz_f16_f32)
static __device__ inline uint32_t pkrtz(float a, float b) {
  auto v = __builtin_amdgcn_cvt_pkrtz(a, b);
  return __builtin_bit_cast(uint32_t, v);
}
static __device__ inline float tanhfast(float x) {
  float e = __expf(2.f * x);
  return 1.f - 2.f / (e + 1.f);
}

// ---------------------------------------------------------------------------
// Prep: transpose/convert weights to fp16 with the LDS bank-swizzle BAKED IN:
// within each row, 16B-chunk c is stored at slot c^(row&7)  (8-chunk window).
// ---------------------------------------------------------------------------
__global__ void k_prep(const float* __restrict__ Wa, const float* __restrict__ Wm,
                       const float* __restrict__ Wz, const float* __restrict__ Wr,
                       const float* __restrict__ Wh,
                       f16* __restrict__ WaT, f16* __restrict__ WmT,
                       f16* __restrict__ WzrT, f16* __restrict__ WhcT) {
  int idx = blockIdx.x * 256 + threadIdx.x;
  if (idx < 65536) {
    int d = idx >> 8, k = idx & 255;
    int kk = ((((k >> 3) ^ (d & 7)) << 3) | (k & 7));
    WaT[d * 256 + kk] = (f16)Wa[k * 256 + d];
  } else if (idx < 131072) {
    int t = idx - 65536;
    int d = t >> 8, k = t & 255;
    int kk = ((((k >> 3) ^ (d & 7)) << 3) | (k & 7));
    WmT[d * 256 + kk] = (f16)Wm[k * 256 + d];
  } else if (idx < 131072 + 262144) {
    int t = idx - 131072;
    int n = t >> 9, k = t & 511;
    const float* src = (n < 256) ? Wz : Wr;
    int np  = n & 255;
    int row = (k < 256) ? k : (264 + k);   // 520 + (k - 256)
    int kk = ((((k >> 3) ^ (n & 7)) << 3) | (k & 7));
    WzrT[n * 512 + kk] = (f16)src[row * 256 + np];
  } else {
    int t = idx - (131072 + 262144);       // < 131072
    int n = t >> 9, k = t & 511;
    int row = (k < 256) ? k : (264 + k);
    int kk = ((((k >> 3) ^ (n & 7)) << 3) | (k & 7));
    WhcT[n * 512 + kk] = (f16)Wh[row * 256 + n];
  }
}

// partial sums: hmean4[b][part][d] = sum_{n in part} h[b][n][d]
__global__ void k_hmean(const float* __restrict__ h, float* __restrict__ hmean4) {
  int b = blockIdx.x, part = blockIdx.y, d = threadIdx.x;
  const float* p = h + ((size_t)b * N_ + part * 128) * H_ + d;
  float s = 0.f;
  #pragma unroll 8
  for (int n = 0; n < 128; ++n) s += p[n * H_];
  hmean4[(b * 4 + part) * H_ + d] = s;
}

// Per-batch GRU constants: c_*[b][d] = bias[d] + h_mean[b]·W*[256:512,d] + jets[b]·W*[512:520,d]
__global__ void k_cvec(const float* __restrict__ hmean4, const float* __restrict__ jets,
                       const float* __restrict__ Wz, const float* __restrict__ Wr,
                       const float* __restrict__ Wh,
                       const float* __restrict__ bz, const float* __restrict__ br,
                       const float* __restrict__ bh,
                       float* __restrict__ cz, float* __restrict__ cr, float* __restrict__ ch) {
  __shared__ float hm[H_];
  __shared__ float jt[FJ];
  int b = blockIdx.x, d = threadIdx.x;
  hm[d] = (hmean4[(b * 4 + 0) * H_ + d] + hmean4[(b * 4 + 1) * H_ + d] +
           hmean4[(b * 4 + 2) * H_ + d] + hmean4[(b * 4 + 3) * H_ + d]) * (1.f / N_);
  if (d < FJ) jt[d] = jets[b * FJ + d];
  __syncthreads();
  float az = bz[d], ar = br[d], ah = bh[d];
  #pragma unroll 4
  for (int k = 0; k < H_; ++k) {
    float m = hm[k];
    az += m * Wz[(256 + k) * 256 + d];
    ar += m * Wr[(256 + k) * 256 + d];
    ah += m * Wh[(256 + k) * 256 + d];
  }
  #pragma unroll
  for (int f = 0; f < FJ; ++f) {
    float j = jt[f];
    az += j * Wz[(512 + f) * 256 + d];
    ar += j * Wr[(512 + f) * 256 + d];
    ah += j * Wh[(512 + f) * 256 + d];
  }
  cz[b * H_ + d] = az;
  cr[b * H_ + d] = ar;
  ch[b * H_ + d] = ah;
}

// h16 = linear f16 copy of h
__global__ void k_h16(const float* __restrict__ h, f16* __restrict__ h16) {
  int t  = blockIdx.x * 256 + threadIdx.x;   // chunk id: 2,097,152
  const float* p = h + (size_t)t * 8;
  f32x4 v0 = *(const f32x4*)p;
  f32x4 v1 = *(const f32x4*)(p + 4);
  f16x8 hv;
  #pragma unroll
  for (int e = 0; e < 4; ++e) { hv[e] = (f16)v0[e]; hv[4 + e] = (f16)v1[e]; }
  *(f16x8*)&h16[(size_t)t * 8] = hv;
}

// ===========================================================================
// Shared GEMM geometry (unchanged from R6/R7): 128x128 tile, 2-phase counted
// vmcnt pipeline, double-buffered LDS. See R6 barrier ledger.
// ===========================================================================
#define GEMM_PRE()                                                      \
  const int tid = threadIdx.x, lane = tid & 63, wave = tid >> 6;        \
  const int g = lane >> 4, m16 = lane & 15;                             \
  const int wr = (wave >> 1) * 64, wc = (wave & 1) * 64;                \
  f32x4 acc[4][4] = {};

#define GEMM_COMPUTE(Ab, Bb)                                            \
  _Pragma("unroll")                                                     \
  for (int ks = 0; ks < 2; ++ks) {                                      \
    f16x8 af[4], bf[4];                                                 \
    _Pragma("unroll")                                                   \
    for (int mi = 0; mi < 4; ++mi)                                      \
      af[mi] = *(const f16x8*)((const char*)(Ab) + (wr + mi * 16 + m16) * 128 \
                               + (((ks * 4 + g) ^ (m16 & 7)) << 4));    \
    _Pragma("unroll")                                                   \
    for (int ni = 0; ni < 4; ++ni)                                      \
      bf[ni] = *(const f16x8*)((const char*)(Bb) + (wc + ni * 16 + m16) * 128 \
                               + (((ks * 4 + g) ^ (m16 & 7)) << 4));    \
    _Pragma("unroll")                                                   \
    for (int mi = 0; mi < 4; ++mi)                                      \
      _Pragma("unroll")                                                 \
      for (int ni = 0; ni < 4; ++ni)                                    \
        acc[mi][ni] = MFMA16(af[mi], bf[ni], acc[mi][ni]);              \
  }

#define GEMM_LOOP(KMAX, STAGEFN)                                        \
  STAGEFN(0, 0);                                                       \
  for (int kt = 0; kt < (KMAX) / 64; ++kt) {                            \
    const int cur = kt & 1;                                             \
    if (kt < (KMAX) / 64 - 1) {                                         \
      STAGEFN(cur ^ 1, (kt + 1) * 64);                                  \
      asm volatile("s_waitcnt vmcnt(8)" ::: "memory");                  \
    } else {                                                            \
      asm volatile("s_waitcnt vmcnt(0)" ::: "memory");                  \
    }                                                                   \
    __builtin_amdgcn_sched_barrier(0);                                  \
    __builtin_amdgcn_s_barrier();                                       \
    __builtin_amdgcn_sched_barrier(0);                                  \
    GEMM_COMPUTE(&AL[cur][0], &BL[cur][0]);                             \
    __builtin_amdgcn_s_barrier();                                       \
    __builtin_amdgcn_sched_barrier(0);                                  \
  }

#define SRC_SWZ(row0) ((size_t)(row0 + wave * 32 + (lane >> 3)) * 512 \
                       + (size_t)(((lane & 7) ^ ((lane >> 3) & 7)) << 4))
#define SRC_IMG(row0, RS) ((size_t)(row0 + wave * 32 + (lane >> 3)) * (RS) \
                           + (size_t)((lane & 7) << 4))

// ---------------------------------------------------------------------------
// q = f16(h @ Wa + ba). Grid (512 m, 2 n).
// ---------------------------------------------------------------------------
__global__ __launch_bounds__(256) void k_gemm_q(
    const f16* __restrict__ h16, const f16* __restrict__ WaT,
    const float* __restrict__ ba, f16* __restrict__ q) {
  __shared__ __align__(16) f16 AL[2][128 * 64], BL[2][128 * 64];
  GEMM_PRE();
  const int m0 = blockIdx.x * 128, n0 = blockIdx.y * 128;
  const size_t a_off = SRC_SWZ(m0);
  const size_t b_off = SRC_IMG(n0, 512);
  #define STG_Q(buf, k0)                                                \
    {                                                                   \
      const char* sa = (const char*)h16 + a_off + (size_t)(k0) * 2;     \
      const char* sb = (const char*)WaT + b_off + (size_t)(k0) * 2;     \
      char* da = (char*)&AL[buf][0] + wave * 4096;                      \
      char* db = (char*)&BL[buf][0] + wave * 4096;                      \
      _Pragma("unroll")                                                 \
      for (int i_ = 0; i_ < 4; ++i_) {                                  \
        gld16(sa + i_ * 4096, da + i_ * 1024);                          \
        gld16(sb + i_ * 4096, db + i_ * 1024);                          \
      }                                                                 \
    }
  GEMM_LOOP(256, STG_Q);
  #pragma unroll
  for (int mi = 0; mi < 4; ++mi)
    #pragma unroll
    for (int ni = 0; ni < 4; ++ni) {
      int gcol = n0 + wc + ni * 16 + m16;
      float bias = ba[gcol];
      #pragma unroll
      for (int r = 0; r < 4; ++r) {
        int grow = m0 + wr + mi * 16 + 4 * g + r;
        q[(size_t)grow * 256 + gcol] = (f16)(acc[mi][ni][r] + bias);
      }
    }
}

// ---------------------------------------------------------------------------
// hmT[b][d][n] = f16( (h[b] @ Wm + bm)^T ). Grid (128 batches, 8).
// ---------------------------------------------------------------------------
__global__ __launch_bounds__(256) void k_gemm_hmT(
    const f16* __restrict__ h16, const f16* __restrict__ WmT,
    const float* __restrict__ bm, f16* __restrict__ hmT) {
  __shared__ __align__(16) f16 AL[2][128 * 64], BL[2][128 * 64];
  GEMM_PRE();
  const int b = blockIdx.x;
  const int m0 = (blockIdx.y >> 2) * 128, n0 = (blockIdx.y & 3) * 128;
  const size_t a_off = SRC_IMG(m0, 512);
  const size_t b_off = SRC_SWZ(b * 512 + n0);
  #define STG_HM(buf, k0)                                               \
    {                                                                   \
      const char* sa = (const char*)WmT + a_off + (size_t)(k0) * 2;     \
      const char* sb = (const char*)h16 + b_off + (size_t)(k0) * 2;     \
      char* da = (char*)&AL[buf][0] + wave * 4096;                      \
      char* db = (char*)&BL[buf][0] + wave * 4096;                      \
      _Pragma("unroll")                                                 \
      for (int i_ = 0; i_ < 4; ++i_) {                                  \
        gld16(sa + i_ * 4096, da + i_ * 1024);                          \
        gld16(sb + i_ * 4096, db + i_ * 1024);                          \
      }                                                                 \
    }
  GEMM_LOOP(256, STG_HM);
  #pragma unroll
  for (int mi = 0; mi < 4; ++mi)
    #pragma unroll
    for (int r = 0; r < 4; ++r) {
      int d = m0 + wr + mi * 16 + 4 * g + r;
      float bias = bm[d];
      #pragma unroll
      for (int ni = 0; ni < 4; ++ni) {
        int n = n0 + wc + ni * 16 + m16;
        hmT[(size_t)b * H_ * N_ + (size_t)d * N_ + n] = (f16)(acc[mi][ni][r] + bias);
      }
    }
}

// ---------------------------------------------------------------------------
// Flash attention + DTNN message, v7: swapped-QK 32x32 MFMA, in-register
// softmax. Identical to R8's v6 EXCEPT all cross-half exchanges use
// __shfl_xor(.,32,64) (defined semantics) instead of raw v_permlane32_swap.
//
// Lane (i=l31, hi) after S^T = MFMA32(K,Q): holds S^T[j][i] for
// j = (r&3)+8*(r>>2)+4*hi (r=0..15).  B-frag for PV k-slot kk needs
// P[j=kk*16+8*hi+e][i] at elem e:
//   hi=0 words: (j0,j1),(j2,j3),(j4,j5),(j6,j7)  = own pk01, own pk23,
//                partner pk01, partner pk23
//   hi=1 words: (j8..j15)                        = partner pk45, partner
//                pk67, own pk45, own pk67
// ---------------------------------------------------------------------------
__global__ __launch_bounds__(256, 2) void k_attn7(
    const f16* __restrict__ q, const float* __restrict__ mask,
    const f16* __restrict__ hmT, const f16* __restrict__ h16,
    f16* __restrict__ msg) {
  __shared__ __align__(16) f16 Kt[2][32 * 256];   // 2 x 16KB
  __shared__ __align__(16) f16 Vt[2][256 * 32];   // 2 x 16KB
  __shared__ float mask_lds[N_];
  const int tid = threadIdx.x, lane = tid & 63, wave = tid >> 6;
  const int l31 = lane & 31, hi = lane >> 5;
  const int b = blockIdx.x, i0 = blockIdx.y * 128 + wave * 32;

  mask_lds[tid]       = mask[b * N_ + tid];
  mask_lds[tid + 256] = mask[b * N_ + tid + 256];

  // Q fragments: lane holds q-row (i0 + l31), k = s5*16 + hi*8 + e
  const f16* qrow = q + (size_t)(b * N_ + i0 + l31) * H_ + hi * 8;
  f16x8 qb[16];
  #pragma unroll
  for (int s5 = 0; s5 < 16; ++s5) qb[s5] = *(const f16x8*)(qrow + s5 * 16);

  f32x16 ot[8] = {};          // O^T: 8 d-tiles x 16 f32
  float mrun = -3.0e38f, lrun = 0.f;

  const char* hvbs = (const char*)(hmT + (size_t)b * H_ * N_);
  const char* h16b = (const char*)(h16 + (size_t)b * N_ * H_);

  // K stage: 4 gld16/wave; LDS row r (tile-local), slot s holds src chunk s^(r&7)
  auto stageK = [&](int buf, int jt) {
    const int rl = lane >> 5, s5 = lane & 31;
    char* dst = (char*)&Kt[buf][0] + wave * 4096;
    #pragma unroll
    for (int i = 0; i < 4; ++i) {
      int row = wave * 8 + i * 2 + rl;
      const char* src = h16b + (size_t)(jt * 32 + row) * 512
                      + (size_t)((s5 ^ (row & 7)) << 4);
      gld16(src, dst + i * 1024);
    }
  };
  // V stage: 4 gld16/wave; LDS row d (64B), slot s holds src chunk s^((d>>1)&3)
  auto stageV = [&](int buf, int jt) {
    const int swz = ((lane & 3) ^ ((lane >> 3) & 3)) << 4;
    char* dst = (char*)&Vt[buf][0] + wave * 4096;
    #pragma unroll
    for (int i = 0; i < 4; ++i) {
      int d = wave * 64 + i * 16 + (lane >> 2);
      gld16(hvbs + (size_t)d * 1024 + jt * 64 + swz, dst + i * 1024);
    }
  };

  __syncthreads();            // mask_lds visible before first use
  stageK(0, 0); stageV(0, 0); // 8 gld16
  __builtin_amdgcn_sched_barrier(0);

  const int x7 = lane & 7, x3 = (l31 >> 1) & 3;

  for (int jt = 0; jt < 16; ++jt) {
    const int cur = jt & 1, j0 = jt * 32;
    if (jt < 15) {
      stageK(cur ^ 1, jt + 1); stageV(cur ^ 1, jt + 1);
      asm volatile("s_waitcnt vmcnt(8)" ::: "memory");
    } else {
      asm volatile("s_waitcnt vmcnt(0)" ::: "memory");
    }
    __builtin_amdgcn_sched_barrier(0);
    __builtin_amdgcn_s_barrier();      // cur K/V visible; prev-buf reads done
    __builtin_amdgcn_sched_barrier(0);

    // ---- S^T = K · Q^T  (16 slabs of K=16)
    const char* kb = (const char*)&Kt[cur][0] + l31 * 512;
    f32x16 st = {};
    __builtin_amdgcn_s_setprio(1);
    #pragma unroll
    for (int s5 = 0; s5 < 16; ++s5) {
      f16x8 kf = *(const f16x8*)(kb + (((s5 * 2 + hi) ^ x7) << 4));
      st = MFMA32(kf, qb[s5], st);
    }
    __builtin_amdgcn_s_setprio(0);

    // ---- in-register online softmax (lane pair (l31, l31+32) owns q-row l31)
    float pm = st[0];
    #pragma unroll
    for (int r = 1; r < 16; ++r) pm = fmaxf(pm, st[r]);
    pm = fmaxf(pm, __shfl_xor(pm, 32, 64));
    if (!__all(pm <= mrun + 8.f)) {      // defer-max (T13)
      float mn = fmaxf(mrun, pm);
      float al = __expf(mrun - mn);
      lrun *= al;
      #pragma unroll
      for (int dt = 0; dt < 8; ++dt)
        #pragma unroll
        for (int e = 0; e < 16; ++e) ot[dt][e] *= al;
      mrun = mn;
    }
    float p[16], ts = 0.f;
    #pragma unroll
    for (int r = 0; r < 16; ++r) {
      float mk = mask_lds[j0 + (r & 3) + 8 * (r >> 2) + 4 * hi];
      p[r] = __expf(st[r] - mrun) * mk;
      ts += p[r];
    }
    ts += __shfl_xor(ts, 32, 64);
    lrun += ts;

    // ---- pack P -> f16 B-frags via shfl_xor(32) redistribution
    f16x8 pf[2];
    #pragma unroll
    for (int kk = 0; kk < 2; ++kk) {
      uint32_t pk01 = pkrtz(p[kk * 8 + 0], p[kk * 8 + 1]);
      uint32_t pk23 = pkrtz(p[kk * 8 + 2], p[kk * 8 + 3]);
      uint32_t pk45 = pkrtz(p[kk * 8 + 4], p[kk * 8 + 5]);
      uint32_t pk67 = pkrtz(p[kk * 8 + 6], p[kk * 8 + 7]);
      uint32_t s01 = __shfl_xor(pk01, 32, 64);
      uint32_t s23 = __shfl_xor(pk23, 32, 64);
      uint32_t s45 = __shfl_xor(pk45, 32, 64);
      uint32_t s67 = __shfl_xor(pk67, 32, 64);
      union { uint32_t u[4]; f16x8 v; } w;
      w.u[0] = hi ? s45 : pk01;
      w.u[1] = hi ? s67 : pk23;
      w.u[2] = hi ? pk45 : s01;
      w.u[3] = hi ? pk67 : s23;
      pf[kk] = w.v;
    }

    // ---- O^T += V^T · P^T
    const char* vb = (const char*)&Vt[cur][0] + l31 * 64;
    __builtin_amdgcn_s_setprio(1);
    #pragma unroll
    for (int kk = 0; kk < 2; ++kk)
      #pragma unroll
      for (int dt = 0; dt < 8; ++dt) {
        f16x8 vf = *(const f16x8*)(vb + dt * 2048 + (((kk * 2 + hi) ^ x3) << 4));
        ot[dt] = MFMA32(vf, pf[kk], ot[dt]);
      }
    __builtin_amdgcn_s_setprio(0);

    __builtin_amdgcn_s_barrier();      // all reads of cur done before overwrite
    __builtin_amdgcn_sched_barrier(0);
  }

  // ---- epilogue: msg[i][d] = tanh(rm * O^T[d][i] / l), packed 8B stores
  float rm  = mask_lds[i0 + l31];
  float inv = rm / lrun;
  f16* msgp = msg + (size_t)(b * N_ + i0 + l31) * H_;
  #pragma unroll
  for (int dt = 0; dt < 8; ++dt)
    #pragma unroll
    for (int rg = 0; rg < 4; ++rg) {
      float t0 = tanhfast(ot[dt][rg * 4 + 0] * inv);
      float t1 = tanhfast(ot[dt][rg * 4 + 1] * inv);
      float t2 = tanhfast(ot[dt][rg * 4 + 2] * inv);
      float t3 = tanhfast(ot[dt][rg * 4 + 3] * inv);
      union { uint32_t u[2]; uint64_t q; } w;
      w.u[0] = pkrtz(t0, t1); w.u[1] = pkrtz(t2, t3);
      *(uint64_t*)(msgp + dt * 32 + rg * 8 + 4 * hi) = w.q;
    }
}

// ---------------------------------------------------------------------------
// Gate GEMM 1: pre = [msg|h] @ Wzr + c. Grid (512 m, 4 n): y<2 -> z, y>=2 -> r.
// ---------------------------------------------------------------------------
__global__ __launch_bounds__(256) void k_gemm_zr(
    const f16* __restrict__ msg, const f16* __restrict__ h16,
    const f16* __restrict__ WzrT, const float* __restrict__ cz,
    const float* __restrict__ cr, f16* __restrict__ z, f16* __restrict__ rh) {
  __shared__ __align__(16) f16 AL[2][128 * 64], BL[2][128 * 64];
  GEMM_PRE();
  const int m0 = blockIdx.x * 128;
  const int n0 = blockIdx.y * 128;
  const size_t a_off = SRC_SWZ(m0);
  const size_t b_off = SRC_IMG(n0, 1024);
  #define STG_ZR(buf, k0)                                               \
    {                                                                   \
      const char* ab = (const char*)((k0) < 256 ? msg : h16);           \
      const char* sa = ab + a_off + (size_t)(((k0) & 255)) * 2;         \
      const char* sb = (const char*)WzrT + b_off + (size_t)(k0) * 2;    \
      char* da = (char*)&AL[buf][0] + wave * 4096;                      \
      char* db = (char*)&BL[buf][0] + wave * 4096;                      \
      _Pragma("unroll")                                                 \
      for (int i_ = 0; i_ < 4; ++i_) {                                  \
        gld16(sa + i_ * 4096, da + i_ * 1024);                          \
        gld16(sb + i_ * 8192, db + i_ * 1024);                          \
      }                                                                 \
    }
  GEMM_LOOP(512, STG_ZR);
  const int is_r = blockIdx.y >> 1;
  #pragma unroll
  for (int mi = 0; mi < 4; ++mi)
    #pragma unroll
    for (int ni = 0; ni < 4; ++ni) {
      int ncol = (blockIdx.y & 1) * 128 + wc + ni * 16 + m16;
      #pragma unroll
      for (int r = 0; r < 4; ++r) {
        int grow = m0 + wr + mi * 16 + 4 * g + r;
        int bb = grow >> 9;
        float a = acc[mi][ni][r];
        size_t oidx = (size_t)grow * 256 + ncol;
        if (!is_r) {
          float v = a + cz[bb * 256 + ncol];
          z[oidx] = (f16)(1.f / (1.f + __expf(-v)));
        } else {
          float v  = a + cr[bb * 256 + ncol];
          float rr = 1.f / (1.f + __expf(-v));
          rh[oidx] = (f16)(rr * (float)h16[oidx]);
        }
      }
    }
}

// ---------------------------------------------------------------------------
// Gate GEMM 2: h_tilde = tanh([msg|rh] @ Whc + c_h); out = (1-z)*h + z*h_tilde
// Grid (512 m, 2 n).
// ---------------------------------------------------------------------------
__global__ __launch_bounds__(256) void k_gemm_ht(
    const f16* __restrict__ msg, const f16* __restrict__ rh,
    const f16* __restrict__ WhcT, const float* __restrict__ ch,
    const f16* __restrict__ z, const f16* __restrict__ h16,
    float* __restrict__ out) {
  __shared__ __align__(16) f16 AL[2][128 * 64], BL[2][128 * 64];
  GEMM_PRE();
  const int m0 = blockIdx.x * 128;
  const int n0 = blockIdx.y * 128;
  const size_t a_off = SRC_SWZ(m0);
  const size_t b_off = SRC_IMG(n0, 1024);
  #define STG_HT(buf, k0)                                               \
    {                                                                   \
      const char* ab = (const char*)((k0) < 256 ? msg : rh);            \
      const char* sa = ab + a_off + (size_t)(((k0) & 255)) * 2;         \
      const char* sb = (const char*)WhcT + b_off + (size_t)(k0) * 2;    \
      char* da = (char*)&AL[buf][0] + wave * 4096;                      \
      char* db = (char*)&BL[buf][0] + wave * 4096;                      \
      _Pragma("unroll")                                                 \
      for (int i_ = 0; i_ < 4; ++i_) {                                  \
        gld16(sa + i_ * 4096, da + i_ * 1024);                          \
        gld16(sb + i_ * 8192, db + i_ * 1024);                          \
      }                                                                 \
    }
  GEMM_LOOP(512, STG_HT);
  #pragma unroll
  for (int mi = 0; mi < 4; ++mi)
    #pragma unroll
    for (int ni = 0; ni < 4; ++ni) {
      int gcol = n0 + wc + ni * 16 + m16;
      #pragma unroll
      for (int r = 0; r < 4; ++r) {
        int grow = m0 + wr + mi * 16 + 4 * g + r;
        int bb = grow >> 9;
        size_t oidx = (size_t)grow * 256 + gcol;
        float pre = acc[mi][ni][r] + ch[bb * 256 + gcol];
        float htl = tanhf(pre);
        float zv  = (float)z[oidx];
        float hv  = (float)h16[oidx];
        out[oidx] = (1.f - zv) * hv + zv * htl;
      }
    }
}

// ---------------------------------------------------------------------------
extern "C" void kernel_launch(void* const* d_in, const int* in_sizes, int n_in,
                              void* d_out, int out_size, void* d_ws, size_t ws_size,
                              hipStream_t stream) {
  const float* h    = (const float*)d_in[0];
  const float* jets = (const float*)d_in[1];
  const float* mask = (const float*)d_in[2];
  const float* Wa   = (const float*)d_in[3];
  const float* ba   = (const float*)d_in[4];
  const float* Wm   = (const float*)d_in[5];
  const float* bm   = (const float*)d_in[6];
  const float* Wz   = (const float*)d_in[7];
  const float* bz   = (const float*)d_in[8];
  const float* Wr   = (const float*)d_in[9];
  const float* br   = (const float*)d_in[10];
  const float* Wh   = (const float*)d_in[11];
  const float* bh   = (const float*)d_in[12];
  float* out = (float*)d_out;

  char* ws = (char*)d_ws;
  size_t off = 0;
  auto alloc = [&](size_t bytes) -> void* {
    void* p = ws + off;
    off += (bytes + 255) & ~(size_t)255;
    return p;
  };
  // big: q (f16, 32MB) during attention; z (f16) + rh (f16) afterwards.
  char*   big   = (char*) alloc((size_t)ROWS * H_ * 4);
  f16*    hmT   = (f16*)  alloc((size_t)B_ * H_ * N_ * 2);
  f16*    msg   = (f16*)  alloc((size_t)ROWS * H_ * 2);
  f16*    h16   = (f16*)  alloc((size_t)ROWS * H_ * 2);
  float*  hmean4= (float*)alloc((size_t)B_ * 4 * H_ * 4);
  float*  cz    = (float*)alloc((size_t)B_ * H_ * 4);
  float*  cr    = (float*)alloc((size_t)B_ * H_ * 4);
  float*  chv   = (float*)alloc((size_t)B_ * H_ * 4);
  f16*    WaT   = (f16*)  alloc(65536 * 2);
  f16*    WmT   = (f16*)  alloc(65536 * 2);
  f16*    WzrT  = (f16*)  alloc(262144 * 2);
  f16*    WhcT  = (f16*)  alloc(131072 * 2);
  f16* q  = (f16*)big;
  f16* z  = (f16*)big;                                     // q dead after attn
  f16* rh = (f16*)(big + (size_t)ROWS * H_ * 2);
  if (off > ws_size) return;  // workspace insufficient

  k_prep    <<<2048, 256, 0, stream>>>(Wa, Wm, Wz, Wr, Wh, WaT, WmT, WzrT, WhcT);
  k_hmean   <<<dim3(B_, 4), H_, 0, stream>>>(h, hmean4);
  k_cvec    <<<B_, H_, 0, stream>>>(hmean4, jets, Wz, Wr, Wh, bz, br, bh, cz, cr, chv);
  k_h16     <<<8192, 256, 0, stream>>>(h, h16);
  k_gemm_q  <<<dim3(512, 2), 256, 0, stream>>>(h16, WaT, ba, q);
  k_gemm_hmT<<<dim3(128, 8), 256, 0, stream>>>(h16, WmT, bm, hmT);
  k_attn7   <<<dim3(128, 4), 256, 0, stream>>>(q, mask, hmT, h16, msg);
  k_gemm_zr <<<dim3(512, 4), 256, 0, stream>>>(msg, h16, WzrT, cz, cr, z, rh);
  k_gemm_ht <<<dim3(512, 2), 256, 0, stream>>>(msg, rh, WhcT, chv, z, h16, out);
}

// Round 11
// 436.481 us; speedup vs baseline: 1.5769x; 1.0026x over previous
//
#include <hip/hip_runtime.h>

// Problem constants (from reference): B=128, N=512, H=256, F_JET=8, gin=776.
#define B_   128
#define N_   512
#define H_   256
#define FJ   8
#define ROWS (B_ * N_)          // 65536 flattened vertex rows
#define NEGV (-1e9f)

typedef _Float16 f16;
typedef __attribute__((ext_vector_type(8)))  f16   f16x8;    // MFMA A/B fragment (4 VGPRs)
typedef __attribute__((ext_vector_type(4)))  float f32x4;    // 16x16 C/D fragment
typedef __attribute__((ext_vector_type(16))) float f32x16;   // 32x32 C/D fragment

static __device__ inline f32x4 MFMA16(f16x8 a, f16x8 b, f32x4 c) {
  return __builtin_amdgcn_mfma_f32_16x16x32_f16(a, b, c, 0, 0, 0);
}
static __device__ inline f32x16 MFMA32(f16x8 a, f16x8 b, f32x16 c) {
  return __builtin_amdgcn_mfma_f32_32x32x16_f16(a, b, c, 0, 0, 0);
}

// global -> LDS direct copy, 16B per lane. LDS ptr must be wave-uniform; HW adds lane*16.
static __device__ inline void gld16(const void* g, void* l) {
  __builtin_amdgcn_global_load_lds(
      (const __attribute__((address_space(1))) void*)g,
      (__attribute__((address_space(3))) void*)(uintptr_t)l,
      16, 0, 0);
}

// pack two f32 -> 2 f16 in one u32 (v_cvt_pkrtz_f16_f32)
static __device__ inline uint32_t pkrtz(float a, float b) {
  auto v = __builtin_amdgcn_cvt_pkrtz(a, b);
  return __builtin_bit_cast(uint32_t, v);
}
static __device__ inline float tanhfast(float x) {
  float e = __expf(2.f * x);
  return 1.f - 2.f / (e + 1.f);
}

// ---------------------------------------------------------------------------
// Prep: transpose/convert weights to fp16 with the LDS bank-swizzle BAKED IN:
// within each row, 16B-chunk c is stored at slot c^(row&7)  (8-chunk window).
// ---------------------------------------------------------------------------
__global__ void k_prep(const float* __restrict__ Wa, const float* __restrict__ Wm,
                       const float* __restrict__ Wz, const float* __restrict__ Wr,
                       const float* __restrict__ Wh,
                       f16* __restrict__ WaT, f16* __restrict__ WmT,
                       f16* __restrict__ WzrT, f16* __restrict__ WhcT) {
  int idx = blockIdx.x * 256 + threadIdx.x;
  if (idx < 65536) {
    int d = idx >> 8, k = idx & 255;
    int kk = ((((k >> 3) ^ (d & 7)) << 3) | (k & 7));
    WaT[d * 256 + kk] = (f16)Wa[k * 256 + d];
  } else if (idx < 131072) {
    int t = idx - 65536;
    int d = t >> 8, k = t & 255;
    int kk = ((((k >> 3) ^ (d & 7)) << 3) | (k & 7));
    WmT[d * 256 + kk] = (f16)Wm[k * 256 + d];
  } else if (idx < 131072 + 262144) {
    int t = idx - 131072;
    int n = t >> 9, k = t & 511;
    const float* src = (n < 256) ? Wz : Wr;
    int np  = n & 255;
    int row = (k < 256) ? k : (264 + k);   // 520 + (k - 256)
    int kk = ((((k >> 3) ^ (n & 7)) << 3) | (k & 7));
    WzrT[n * 512 + kk] = (f16)src[row * 256 + np];
  } else {
    int t = idx - (131072 + 262144);       // < 131072
    int n = t >> 9, k = t & 511;
    int row = (k < 256) ? k : (264 + k);
    int kk = ((((k >> 3) ^ (n & 7)) << 3) | (k & 7));
    WhcT[n * 512 + kk] = (f16)Wh[row * 256 + n];
  }
}

// partial sums: hmean4[b][part][d] = sum_{n in part} h[b][n][d]
__global__ void k_hmean(const float* __restrict__ h, float* __restrict__ hmean4) {
  int b = blockIdx.x, part = blockIdx.y, d = threadIdx.x;
  const float* p = h + ((size_t)b * N_ + part * 128) * H_ + d;
  float s = 0.f;
  #pragma unroll 8
  for (int n = 0; n < 128; ++n) s += p[n * H_];
  hmean4[(b * 4 + part) * H_ + d] = s;
}

// Per-batch GRU constants: c_*[b][d] = bias[d] + h_mean[b]·W*[256:512,d] + jets[b]·W*[512:520,d]
__global__ void k_cvec(const float* __restrict__ hmean4, const float* __restrict__ jets,
                       const float* __restrict__ Wz, const float* __restrict__ Wr,
                       const float* __restrict__ Wh,
                       const float* __restrict__ bz, const float* __restrict__ br,
                       const float* __restrict__ bh,
                       float* __restrict__ cz, float* __restrict__ cr, float* __restrict__ ch) {
  __shared__ float hm[H_];
  __shared__ float jt[FJ];
  int b = blockIdx.x, d = threadIdx.x;
  hm[d] = (hmean4[(b * 4 + 0) * H_ + d] + hmean4[(b * 4 + 1) * H_ + d] +
           hmean4[(b * 4 + 2) * H_ + d] + hmean4[(b * 4 + 3) * H_ + d]) * (1.f / N_);
  if (d < FJ) jt[d] = jets[b * FJ + d];
  __syncthreads();
  float az = bz[d], ar = br[d], ah = bh[d];
  #pragma unroll 4
  for (int k = 0; k < H_; ++k) {
    float m = hm[k];
    az += m * Wz[(256 + k) * 256 + d];
    ar += m * Wr[(256 + k) * 256 + d];
    ah += m * Wh[(256 + k) * 256 + d];
  }
  #pragma unroll
  for (int f = 0; f < FJ; ++f) {
    float j = jt[f];
    az += j * Wz[(512 + f) * 256 + d];
    ar += j * Wr[(512 + f) * 256 + d];
    ah += j * Wh[(512 + f) * 256 + d];
  }
  cz[b * H_ + d] = az;
  cr[b * H_ + d] = ar;
  ch[b * H_ + d] = ah;
}

// h16 = linear f16 copy of h
__global__ void k_h16(const float* __restrict__ h, f16* __restrict__ h16) {
  int t  = blockIdx.x * 256 + threadIdx.x;   // chunk id: 2,097,152
  const float* p = h + (size_t)t * 8;
  f32x4 v0 = *(const f32x4*)p;
  f32x4 v1 = *(const f32x4*)(p + 4);
  f16x8 hv;
  #pragma unroll
  for (int e = 0; e < 4; ++e) { hv[e] = (f16)v0[e]; hv[4 + e] = (f16)v1[e]; }
  *(f16x8*)&h16[(size_t)t * 8] = hv;
}

// ===========================================================================
// Shared GEMM geometry: 128x128 tile, 4 waves 2x2 (wave 64x64, acc[4][4]),
// BK=64.  ASYMMETRIC deep pipeline:
//   X operand (HBM stream)   : 3 LDS buffers, staged 2 iterations ahead
//   Y operand (L2-hot weights): 2 LDS buffers, staged 1 iteration ahead
// Per-iteration ledger (2 raw barriers):
//   issue Y(kt+1) THEN X(kt+2)  [order matters: vmcnt retirement is in-order!]
//   -> per-wave outstanding queue: X(kt),Y(kt),X(kt+1),Y(kt+1),X(kt+2) = 20
//   vmcnt(12): retires the 8 oldest = X(kt)+Y(kt) exactly.   [R10 BUG: issuing
//   X(kt+2) before Y(kt+1) made the queue X(kt),X(kt+1),Y(kt),... so vmcnt(12)
//   retired X(kt)+X(kt+1) and compute read Y(kt) before it landed.]
//   tail rem==1: issue Y(kt+1) only; queue X,Y,X(+1),Y(+1)=16 -> vmcnt(8)
//   tail rem==0: vmcnt(0)
//   s_barrier #1 -> cur data visible to all waves
//   compute(cur = X buf kt%3, Y buf kt&1)
//   s_barrier #2 -> no wave overwrites cur buffers until all waves done.
//   Buffer-reuse: X buf (kt+2)%3 == (kt-1)%3 read at iter kt-1, done before
//   barrier #2 of kt-1 < issue at kt. Y buf (kt+1)&1 read at iter kt-1. OK.
// ===========================================================================
#define GEMM_PRE()                                                      \
  const int tid = threadIdx.x, lane = tid & 63, wave = tid >> 6;        \
  const int g = lane >> 4, m16 = lane & 15;                             \
  const int wr = (wave >> 1) * 64, wc = (wave & 1) * 64;                \
  f32x4 acc[4][4] = {};

#define GEMM_COMPUTE(Ab, Bb)                                            \
  _Pragma("unroll")                                                     \
  for (int ks = 0; ks < 2; ++ks) {                                      \
    f16x8 af[4], bf[4];                                                 \
    _Pragma("unroll")                                                   \
    for (int mi = 0; mi < 4; ++mi)                                      \
      af[mi] = *(const f16x8*)((const char*)(Ab) + (wr + mi * 16 + m16) * 128 \
                               + (((ks * 4 + g) ^ (m16 & 7)) << 4));    \
    _Pragma("unroll")                                                   \
    for (int ni = 0; ni < 4; ++ni)                                      \
      bf[ni] = *(const f16x8*)((const char*)(Bb) + (wc + ni * 16 + m16) * 128 \
                               + (((ks * 4 + g) ^ (m16 & 7)) << 4));    \
    _Pragma("unroll")                                                   \
    for (int mi = 0; mi < 4; ++mi)                                      \
      _Pragma("unroll")                                                 \
      for (int ni = 0; ni < 4; ++ni)                                    \
        acc[mi][ni] = MFMA16(af[mi], bf[ni], acc[mi][ni]);              \
  }

// STGX/STGY each issue exactly 4 gld16 into buffer (buf) for K-cols k0..k0+63.
#define GEMM_LOOP3(KMAX, STGX, STGY, COMPUTE_CALL)                      \
  STGX(0, 0); STGY(0, 0); STGX(1, 64);                                  \
  for (int kt = 0; kt < (KMAX) / 64; ++kt) {                            \
    const int cx = kt % 3, cy = kt & 1;                                 \
    const int rem = (KMAX) / 64 - 1 - kt;                               \
    if (rem >= 2) {                                                     \
      STGY((kt + 1) & 1, (kt + 1) * 64);   /* Y BEFORE X (in-order vmcnt) */ \
      STGX((kt + 2) % 3, (kt + 2) * 64);                                \
      asm volatile("s_waitcnt vmcnt(12)" ::: "memory");                 \
    } else if (rem == 1) {                                              \
      STGY((kt + 1) & 1, (kt + 1) * 64);                                \
      asm volatile("s_waitcnt vmcnt(8)" ::: "memory");                  \
    } else {                                                            \
      asm volatile("s_waitcnt vmcnt(0)" ::: "memory");                  \
    }                                                                   \
    __builtin_amdgcn_sched_barrier(0);                                  \
    __builtin_amdgcn_s_barrier();                                       \
    __builtin_amdgcn_sched_barrier(0);                                  \
    COMPUTE_CALL;                                                       \
    __builtin_amdgcn_s_barrier();                                       \
    __builtin_amdgcn_sched_barrier(0);                                  \
  }

// per-lane source offsets
#define SRC_SWZ(row0) ((size_t)(row0 + wave * 32 + (lane >> 3)) * 512 \
                       + (size_t)(((lane & 7) ^ ((lane >> 3) & 7)) << 4))
#define SRC_IMG(row0, RS) ((size_t)(row0 + wave * 32 + (lane >> 3)) * (RS) \
                           + (size_t)((lane & 7) << 4))

// ---------------------------------------------------------------------------
// q = f16(h @ Wa + ba). Grid (2 n, 512 m) — n fastest (A L3/L2 reuse).
// X = A (h16 stream, 3-buf), Y = B (WaT image, 2-buf).
// ---------------------------------------------------------------------------
__global__ __launch_bounds__(256) void k_gemm_q(
    const f16* __restrict__ h16, const f16* __restrict__ WaT,
    const float* __restrict__ ba, f16* __restrict__ q) {
  __shared__ __align__(16) f16 AL[3][128 * 64], BL[2][128 * 64];
  GEMM_PRE();
  const int m0 = blockIdx.y * 128, n0 = blockIdx.x * 128;
  const size_t a_off = SRC_SWZ(m0);
  const size_t b_off = SRC_IMG(n0, 512);
  #define STGX_Q(buf, k0)                                               \
    {                                                                   \
      const char* sa = (const char*)h16 + a_off + (size_t)(k0) * 2;     \
      char* da = (char*)&AL[buf][0] + wave * 4096;                      \
      _Pragma("unroll")                                                 \
      for (int i_ = 0; i_ < 4; ++i_) gld16(sa + i_ * 4096, da + i_ * 1024); \
    }
  #define STGY_Q(buf, k0)                                               \
    {                                                                   \
      const char* sb = (const char*)WaT + b_off + (size_t)(k0) * 2;     \
      char* db = (char*)&BL[buf][0] + wave * 4096;                      \
      _Pragma("unroll")                                                 \
      for (int i_ = 0; i_ < 4; ++i_) gld16(sb + i_ * 4096, db + i_ * 1024); \
    }
  GEMM_LOOP3(256, STGX_Q, STGY_Q, GEMM_COMPUTE(&AL[cx][0], &BL[cy][0]));
  #pragma unroll
  for (int mi = 0; mi < 4; ++mi)
    #pragma unroll
    for (int ni = 0; ni < 4; ++ni) {
      int gcol = n0 + wc + ni * 16 + m16;
      float bias = ba[gcol];
      #pragma unroll
      for (int r = 0; r < 4; ++r) {
        int grow = m0 + wr + mi * 16 + 4 * g + r;
        q[(size_t)grow * 256 + gcol] = (f16)(acc[mi][ni][r] + bias);
      }
    }
}

// ---------------------------------------------------------------------------
// hmT[b][d][n] = f16( (h[b] @ Wm + bm)^T ). Grid (8 tiles, 128 b).
// X = B (h16 stream, 3-buf), Y = A (WmT image, 2-buf).
// ---------------------------------------------------------------------------
__global__ __launch_bounds__(256) void k_gemm_hmT(
    const f16* __restrict__ h16, const f16* __restrict__ WmT,
    const float* __restrict__ bm, f16* __restrict__ hmT) {
  __shared__ __align__(16) f16 AL[2][128 * 64], BL[3][128 * 64];
  GEMM_PRE();
  const int b = blockIdx.y;
  const int m0 = (blockIdx.x >> 2) * 128, n0 = (blockIdx.x & 3) * 128;
  const size_t a_off = SRC_IMG(m0, 512);
  const size_t b_off = SRC_SWZ(b * 512 + n0);
  #define STGX_HM(buf, k0)                                              \
    {                                                                   \
      const char* sb = (const char*)h16 + b_off + (size_t)(k0) * 2;     \
      char* db = (char*)&BL[buf][0] + wave * 4096;                      \
      _Pragma("unroll")                                                 \
      for (int i_ = 0; i_ < 4; ++i_) gld16(sb + i_ * 4096, db + i_ * 1024); \
    }
  #define STGY_HM(buf, k0)                                              \
    {                                                                   \
      const char* sa = (const char*)WmT + a_off + (size_t)(k0) * 2;     \
      char* da = (char*)&AL[buf][0] + wave * 4096;                      \
      _Pragma("unroll")                                                 \
      for (int i_ = 0; i_ < 4; ++i_) gld16(sa + i_ * 4096, da + i_ * 1024); \
    }
  GEMM_LOOP3(256, STGX_HM, STGY_HM, GEMM_COMPUTE(&AL[cy][0], &BL[cx][0]));
  #pragma unroll
  for (int mi = 0; mi < 4; ++mi)
    #pragma unroll
    for (int r = 0; r < 4; ++r) {
      int d = m0 + wr + mi * 16 + 4 * g + r;
      float bias = bm[d];
      #pragma unroll
      for (int ni = 0; ni < 4; ++ni) {
        int n = n0 + wc + ni * 16 + m16;
        hmT[(size_t)b * H_ * N_ + (size_t)d * N_ + n] = (f16)(acc[mi][ni][r] + bias);
      }
    }
}

// ---------------------------------------------------------------------------
// Flash attention + DTNN message, v7 (UNCHANGED from R9 — passing).
// ---------------------------------------------------------------------------
__global__ __launch_bounds__(256, 2) void k_attn7(
    const f16* __restrict__ q, const float* __restrict__ mask,
    const f16* __restrict__ hmT, const f16* __restrict__ h16,
    f16* __restrict__ msg) {
  __shared__ __align__(16) f16 Kt[2][32 * 256];   // 2 x 16KB
  __shared__ __align__(16) f16 Vt[2][256 * 32];   // 2 x 16KB
  __shared__ float mask_lds[N_];
  const int tid = threadIdx.x, lane = tid & 63, wave = tid >> 6;
  const int l31 = lane & 31, hi = lane >> 5;
  const int b = blockIdx.x, i0 = blockIdx.y * 128 + wave * 32;

  mask_lds[tid]       = mask[b * N_ + tid];
  mask_lds[tid + 256] = mask[b * N_ + tid + 256];

  const f16* qrow = q + (size_t)(b * N_ + i0 + l31) * H_ + hi * 8;
  f16x8 qb[16];
  #pragma unroll
  for (int s5 = 0; s5 < 16; ++s5) qb[s5] = *(const f16x8*)(qrow + s5 * 16);

  f32x16 ot[8] = {};          // O^T: 8 d-tiles x 16 f32
  float mrun = -3.0e38f, lrun = 0.f;

  const char* hvbs = (const char*)(hmT + (size_t)b * H_ * N_);
  const char* h16b = (const char*)(h16 + (size_t)b * N_ * H_);

  auto stageK = [&](int buf, int jt) {
    const int rl = lane >> 5, s5 = lane & 31;
    char* dst = (char*)&Kt[buf][0] + wave * 4096;
    #pragma unroll
    for (int i = 0; i < 4; ++i) {
      int row = wave * 8 + i * 2 + rl;
      const char* src = h16b + (size_t)(jt * 32 + row) * 512
                      + (size_t)((s5 ^ (row & 7)) << 4);
      gld16(src, dst + i * 1024);
    }
  };
  auto stageV = [&](int buf, int jt) {
    const int swz = ((lane & 3) ^ ((lane >> 3) & 3)) << 4;
    char* dst = (char*)&Vt[buf][0] + wave * 4096;
    #pragma unroll
    for (int i = 0; i < 4; ++i) {
      int d = wave * 64 + i * 16 + (lane >> 2);
      gld16(hvbs + (size_t)d * 1024 + jt * 64 + swz, dst + i * 1024);
    }
  };

  __syncthreads();            // mask_lds visible before first use
  stageK(0, 0); stageV(0, 0); // 8 gld16
  __builtin_amdgcn_sched_barrier(0);

  const int x7 = lane & 7, x3 = (l31 >> 1) & 3;

  for (int jt = 0; jt < 16; ++jt) {
    const int cur = jt & 1, j0 = jt * 32;
    if (jt < 15) {
      stageK(cur ^ 1, jt + 1); stageV(cur ^ 1, jt + 1);
      asm volatile("s_waitcnt vmcnt(8)" ::: "memory");
    } else {
      asm volatile("s_waitcnt vmcnt(0)" ::: "memory");
    }
    __builtin_amdgcn_sched_barrier(0);
    __builtin_amdgcn_s_barrier();      // cur K/V visible; prev-buf reads done
    __builtin_amdgcn_sched_barrier(0);

    // ---- S^T = K · Q^T  (16 slabs of K=16)
    const char* kb = (const char*)&Kt[cur][0] + l31 * 512;
    f32x16 st = {};
    __builtin_amdgcn_s_setprio(1);
    #pragma unroll
    for (int s5 = 0; s5 < 16; ++s5) {
      f16x8 kf = *(const f16x8*)(kb + (((s5 * 2 + hi) ^ x7) << 4));
      st = MFMA32(kf, qb[s5], st);
    }
    __builtin_amdgcn_s_setprio(0);

    // ---- in-register online softmax
    float pm = st[0];
    #pragma unroll
    for (int r = 1; r < 16; ++r) pm = fmaxf(pm, st[r]);
    pm = fmaxf(pm, __shfl_xor(pm, 32, 64));
    if (!__all(pm <= mrun + 8.f)) {      // defer-max (T13)
      float mn = fmaxf(mrun, pm);
      float al = __expf(mrun - mn);
      lrun *= al;
      #pragma unroll
      for (int dt = 0; dt < 8; ++dt)
        #pragma unroll
        for (int e = 0; e < 16; ++e) ot[dt][e] *= al;
      mrun = mn;
    }
    float p[16], ts = 0.f;
    #pragma unroll
    for (int r = 0; r < 16; ++r) {
      float mk = mask_lds[j0 + (r & 3) + 8 * (r >> 2) + 4 * hi];
      p[r] = __expf(st[r] - mrun) * mk;
      ts += p[r];
    }
    ts += __shfl_xor(ts, 32, 64);
    lrun += ts;

    // ---- pack P -> f16 B-frags via shfl_xor(32) redistribution
    f16x8 pf[2];
    #pragma unroll
    for (int kk = 0; kk < 2; ++kk) {
      uint32_t pk01 = pkrtz(p[kk * 8 + 0], p[kk * 8 + 1]);
      uint32_t pk23 = pkrtz(p[kk * 8 + 2], p[kk * 8 + 3]);
      uint32_t pk45 = pkrtz(p[kk * 8 + 4], p[kk * 8 + 5]);
      uint32_t pk67 = pkrtz(p[kk * 8 + 6], p[kk * 8 + 7]);
      uint32_t s01 = __shfl_xor(pk01, 32, 64);
      uint32_t s23 = __shfl_xor(pk23, 32, 64);
      uint32_t s45 = __shfl_xor(pk45, 32, 64);
      uint32_t s67 = __shfl_xor(pk67, 32, 64);
      union { uint32_t u[4]; f16x8 v; } w;
      w.u[0] = hi ? s45 : pk01;
      w.u[1] = hi ? s67 : pk23;
      w.u[2] = hi ? pk45 : s01;
      w.u[3] = hi ? pk67 : s23;
      pf[kk] = w.v;
    }

    // ---- O^T += V^T · P^T
    const char* vb = (const char*)&Vt[cur][0] + l31 * 64;
    __builtin_amdgcn_s_setprio(1);
    #pragma unroll
    for (int kk = 0; kk < 2; ++kk)
      #pragma unroll
      for (int dt = 0; dt < 8; ++dt) {
        f16x8 vf = *(const f16x8*)(vb + dt * 2048 + (((kk * 2 + hi) ^ x3) << 4));
        ot[dt] = MFMA32(vf, pf[kk], ot[dt]);
      }
    __builtin_amdgcn_s_setprio(0);

    __builtin_amdgcn_s_barrier();      // all reads of cur done before overwrite
    __builtin_amdgcn_sched_barrier(0);
  }

  // ---- epilogue: msg[i][d] = tanh(rm * O^T[d][i] / l), packed 8B stores
  float rm  = mask_lds[i0 + l31];
  float inv = rm / lrun;
  f16* msgp = msg + (size_t)(b * N_ + i0 + l31) * H_;
  #pragma unroll
  for (int dt = 0; dt < 8; ++dt)
    #pragma unroll
    for (int rg = 0; rg < 4; ++rg) {
      float t0 = tanhfast(ot[dt][rg * 4 + 0] * inv);
      float t1 = tanhfast(ot[dt][rg * 4 + 1] * inv);
      float t2 = tanhfast(ot[dt][rg * 4 + 2] * inv);
      float t3 = tanhfast(ot[dt][rg * 4 + 3] * inv);
      union { uint32_t u[2]; uint64_t q; } w;
      w.u[0] = pkrtz(t0, t1); w.u[1] = pkrtz(t2, t3);
      *(uint64_t*)(msgp + dt * 32 + rg * 8 + 4 * hi) = w.q;
    }
}

// ---------------------------------------------------------------------------
// Gate GEMM 1: pre = [msg|h] @ Wzr + c. Grid (4 n, 512 m) — n fastest.
// X = A (msg/h16 stream, 3-buf), Y = B (WzrT image, 2-buf).
// ---------------------------------------------------------------------------
__global__ __launch_bounds__(256) void k_gemm_zr(
    const f16* __restrict__ msg, const f16* __restrict__ h16,
    const f16* __restrict__ WzrT, const float* __restrict__ cz,
    const float* __restrict__ cr, f16* __restrict__ z, f16* __restrict__ rh) {
  __shared__ __align__(16) f16 AL[3][128 * 64], BL[2][128 * 64];
  GEMM_PRE();
  const int m0 = blockIdx.y * 128;
  const int n0 = blockIdx.x * 128;
  const size_t a_off = SRC_SWZ(m0);
  const size_t b_off = SRC_IMG(n0, 1024);
  #define STGX_ZR(buf, k0)                                              \
    {                                                                   \
      const char* ab = (const char*)((k0) < 256 ? msg : h16);           \
      const char* sa = ab + a_off + (size_t)(((k0) & 255)) * 2;         \
      char* da = (char*)&AL[buf][0] + wave * 4096;                      \
      _Pragma("unroll")                                                 \
      for (int i_ = 0; i_ < 4; ++i_) gld16(sa + i_ * 4096, da + i_ * 1024); \
    }
  #define STGY_ZR(buf, k0)                                              \
    {                                                                   \
      const char* sb = (const char*)WzrT + b_off + (size_t)(k0) * 2;    \
      char* db = (char*)&BL[buf][0] + wave * 4096;                      \
      _Pragma("unroll")                                                 \
      for (int i_ = 0; i_ < 4; ++i_) gld16(sb + i_ * 8192, db + i_ * 1024); \
    }
  GEMM_LOOP3(512, STGX_ZR, STGY_ZR, GEMM_COMPUTE(&AL[cx][0], &BL[cy][0]));
  const int is_r = blockIdx.x >> 1;
  #pragma unroll
  for (int mi = 0; mi < 4; ++mi)
    #pragma unroll
    for (int ni = 0; ni < 4; ++ni) {
      int ncol = (blockIdx.x & 1) * 128 + wc + ni * 16 + m16;
      #pragma unroll
      for (int r = 0; r < 4; ++r) {
        int grow = m0 + wr + mi * 16 + 4 * g + r;
        int bb = grow >> 9;
        float a = acc[mi][ni][r];
        size_t oidx = (size_t)grow * 256 + ncol;
        if (!is_r) {
          float v = a + cz[bb * 256 + ncol];
          z[oidx] = (f16)(1.f / (1.f + __expf(-v)));
        } else {
          float v  = a + cr[bb * 256 + ncol];
          float rr = 1.f / (1.f + __expf(-v));
          rh[oidx] = (f16)(rr * (float)h16[oidx]);
        }
      }
    }
}

// ---------------------------------------------------------------------------
// Gate GEMM 2: h_tilde = tanh([msg|rh] @ Whc + c_h); out = (1-z)*h + z*h_tilde
// Grid (2 n, 512 m) — n fastest. X = A (msg/rh), Y = B (WhcT).
// ---------------------------------------------------------------------------
__global__ __launch_bounds__(256) void k_gemm_ht(
    const f16* __restrict__ msg, const f16* __restrict__ rh,
    const f16* __restrict__ WhcT, const float* __restrict__ ch,
    const f16* __restrict__ z, const f16* __restrict__ h16,
    float* __restrict__ out) {
  __shared__ __align__(16) f16 AL[3][128 * 64], BL[2][128 * 64];
  GEMM_PRE();
  const int m0 = blockIdx.y * 128;
  const int n0 = blockIdx.x * 128;
  const size_t a_off = SRC_SWZ(m0);
  const size_t b_off = SRC_IMG(n0, 1024);
  #define STGX_HT(buf, k0)                                              \
    {                                                                   \
      const char* ab = (const char*)((k0) < 256 ? msg : rh);            \
      const char* sa = ab + a_off + (size_t)(((k0) & 255)) * 2;         \
      char* da = (char*)&AL[buf][0] + wave * 4096;                      \
      _Pragma("unroll")                                                 \
      for (int i_ = 0; i_ < 4; ++i_) gld16(sa + i_ * 4096, da + i_ * 1024); \
    }
  #define STGY_HT(buf, k0)                                              \
    {                                                                   \
      const char* sb = (const char*)WhcT + b_off + (size_t)(k0) * 2;    \
      char* db = (char*)&BL[buf][0] + wave * 4096;                      \
      _Pragma("unroll")                                                 \
      for (int i_ = 0; i_ < 4; ++i_) gld16(sb + i_ * 8192, db + i_ * 1024); \
    }
  GEMM_LOOP3(512, STGX_HT, STGY_HT, GEMM_COMPUTE(&AL[cx][0], &BL[cy][0]));
  #pragma unroll
  for (int mi = 0; mi < 4; ++mi)
    #pragma unroll
    for (int ni = 0; ni < 4; ++ni) {
      int gcol = n0 + wc + ni * 16 + m16;
      #pragma unroll
      for (int r = 0; r < 4; ++r) {
        int grow = m0 + wr + mi * 16 + 4 * g + r;
        int bb = grow >> 9;
        size_t oidx = (size_t)grow * 256 + gcol;
        float pre = acc[mi][ni][r] + ch[bb * 256 + gcol];
        float htl = tanhf(pre);
        float zv  = (float)z[oidx];
        float hv  = (float)h16[oidx];
        out[oidx] = (1.f - zv) * hv + zv * htl;
      }
    }
}

// ---------------------------------------------------------------------------
extern "C" void kernel_launch(void* const* d_in, const int* in_sizes, int n_in,
                              void* d_out, int out_size, void* d_ws, size_t ws_size,
                              hipStream_t stream) {
  const float* h    = (const float*)d_in[0];
  const float* jets = (const float*)d_in[1];
  const float* mask = (const float*)d_in[2];
  const float* Wa   = (const float*)d_in[3];
  const float* ba   = (const float*)d_in[4];
  const float* Wm   = (const float*)d_in[5];
  const float* bm   = (const float*)d_in[6];
  const float* Wz   = (const float*)d_in[7];
  const float* bz   = (const float*)d_in[8];
  const float* Wr   = (const float*)d_in[9];
  const float* br   = (const float*)d_in[10];
  const float* Wh   = (const float*)d_in[11];
  const float* bh   = (const float*)d_in[12];
  float* out = (float*)d_out;

  char* ws = (char*)d_ws;
  size_t off = 0;
  auto alloc = [&](size_t bytes) -> void* {
    void* p = ws + off;
    off += (bytes + 255) & ~(size_t)255;
    return p;
  };
  // big: q (f16, 32MB) during attention; z (f16) + rh (f16) afterwards.
  char*   big   = (char*) alloc((size_t)ROWS * H_ * 4);
  f16*    hmT   = (f16*)  alloc((size_t)B_ * H_ * N_ * 2);
  f16*    msg   = (f16*)  alloc((size_t)ROWS * H_ * 2);
  f16*    h16   = (f16*)  alloc((size_t)ROWS * H_ * 2);
  float*  hmean4= (float*)alloc((size_t)B_ * 4 * H_ * 4);
  float*  cz    = (float*)alloc((size_t)B_ * H_ * 4);
  float*  cr    = (float*)alloc((size_t)B_ * H_ * 4);
  float*  chv   = (float*)alloc((size_t)B_ * H_ * 4);
  f16*    WaT   = (f16*)  alloc(65536 * 2);
  f16*    WmT   = (f16*)  alloc(65536 * 2);
  f16*    WzrT  = (f16*)  alloc(262144 * 2);
  f16*    WhcT  = (f16*)  alloc(131072 * 2);
  f16* q  = (f16*)big;
  f16* z  = (f16*)big;                                     // q dead after attn
  f16* rh = (f16*)(big + (size_t)ROWS * H_ * 2);
  if (off > ws_size) return;  // workspace insufficient

  k_prep    <<<2048, 256, 0, stream>>>(Wa, Wm, Wz, Wr, Wh, WaT, WmT, WzrT, WhcT);
  k_hmean   <<<dim3(B_, 4), H_, 0, stream>>>(h, hmean4);
  k_cvec    <<<B_, H_, 0, stream>>>(hmean4, jets, Wz, Wr, Wh, bz, br, bh, cz, cr, chv);
  k_h16     <<<8192, 256, 0, stream>>>(h, h16);
  k_gemm_q  <<<dim3(2, 512), 256, 0, stream>>>(h16, WaT, ba, q);
  k_gemm_hmT<<<dim3(8, 128), 256, 0, stream>>>(h16, WmT, bm, hmT);
  k_attn7   <<<dim3(128, 4), 256, 0, stream>>>(q, mask, hmT, h16, msg);
  k_gemm_zr <<<dim3(4, 512), 256, 0, stream>>>(msg, h16, WzrT, cz, cr, z, rh);
  k_gemm_ht <<<dim3(2, 512), 256, 0, stream>>>(msg, rh, WhcT, chv, z, h16, out);
}

// Round 12
// 432.904 us; speedup vs baseline: 1.5899x; 1.0083x over previous
//
#include <hip/hip_runtime.h>

// Problem constants (from reference): B=128, N=512, H=256, F_JET=8, gin=776.
#define B_   128
#define N_   512
#define H_   256
#define FJ   8
#define ROWS (B_ * N_)          // 65536 flattened vertex rows
#define NEGV (-1e9f)

typedef _Float16 f16;
typedef __attribute__((ext_vector_type(8)))  f16   f16x8;    // MFMA A/B fragment (4 VGPRs)
typedef __attribute__((ext_vector_type(4)))  float f32x4;    // 16x16 C/D fragment
typedef __attribute__((ext_vector_type(16))) float f32x16;   // 32x32 C/D fragment

static __device__ inline f32x4 MFMA16(f16x8 a, f16x8 b, f32x4 c) {
  return __builtin_amdgcn_mfma_f32_16x16x32_f16(a, b, c, 0, 0, 0);
}
static __device__ inline f32x16 MFMA32(f16x8 a, f16x8 b, f32x16 c) {
  return __builtin_amdgcn_mfma_f32_32x32x16_f16(a, b, c, 0, 0, 0);
}

// global -> LDS direct copy, 16B per lane. LDS ptr must be wave-uniform; HW adds lane*16.
static __device__ inline void gld16(const void* g, void* l) {
  __builtin_amdgcn_global_load_lds(
      (const __attribute__((address_space(1))) void*)g,
      (__attribute__((address_space(3))) void*)(uintptr_t)l,
      16, 0, 0);
}

// pack two f32 -> 2 f16 in one u32 (v_cvt_pkrtz_f16_f32)
static __device__ inline uint32_t pkrtz(float a, float b) {
  auto v = __builtin_amdgcn_cvt_pkrtz(a, b);
  return __builtin_bit_cast(uint32_t, v);
}
static __device__ inline float tanhfast(float x) {
  float e = __expf(2.f * x);
  return 1.f - 2.f / (e + 1.f);
}

// XCD-aware bijective block remap (T1): launch slot s -> original block o.
// Forward map (o -> slot) is s = (o&7)*C + (o>>3), C = nwg/8 (power of 2).
// Slot round-robins XCDs (xcd = s%8 = (o>>3)&7), so the 8 consecutive
// original blocks [8t..8t+7] (which share operand panels) land on ONE XCD,
// 32 slots apart in its dispatch sequence -> co-resident -> L2 reuse.
#define XCD_O(LG_C) ((int)(((blockIdx.x & ((1u << (LG_C)) - 1)) << 3) | (blockIdx.x >> (LG_C))))

// ---------------------------------------------------------------------------
// Prep: transpose/convert weights to fp16 with the LDS bank-swizzle BAKED IN:
// within each row, 16B-chunk c is stored at slot c^(row&7)  (8-chunk window).
// ---------------------------------------------------------------------------
__global__ void k_prep(const float* __restrict__ Wa, const float* __restrict__ Wm,
                       const float* __restrict__ Wz, const float* __restrict__ Wr,
                       const float* __restrict__ Wh,
                       f16* __restrict__ WaT, f16* __restrict__ WmT,
                       f16* __restrict__ WzrT, f16* __restrict__ WhcT) {
  int idx = blockIdx.x * 256 + threadIdx.x;
  if (idx < 65536) {
    int d = idx >> 8, k = idx & 255;
    int kk = ((((k >> 3) ^ (d & 7)) << 3) | (k & 7));
    WaT[d * 256 + kk] = (f16)Wa[k * 256 + d];
  } else if (idx < 131072) {
    int t = idx - 65536;
    int d = t >> 8, k = t & 255;
    int kk = ((((k >> 3) ^ (d & 7)) << 3) | (k & 7));
    WmT[d * 256 + kk] = (f16)Wm[k * 256 + d];
  } else if (idx < 131072 + 262144) {
    int t = idx - 131072;
    int n = t >> 9, k = t & 511;
    const float* src = (n < 256) ? Wz : Wr;
    int np  = n & 255;
    int row = (k < 256) ? k : (264 + k);   // 520 + (k - 256)
    int kk = ((((k >> 3) ^ (n & 7)) << 3) | (k & 7));
    WzrT[n * 512 + kk] = (f16)src[row * 256 + np];
  } else {
    int t = idx - (131072 + 262144);       // < 131072
    int n = t >> 9, k = t & 511;
    int row = (k < 256) ? k : (264 + k);
    int kk = ((((k >> 3) ^ (n & 7)) << 3) | (k & 7));
    WhcT[n * 512 + kk] = (f16)Wh[row * 256 + n];
  }
}

// partial sums: hmean4[b][part][d] = sum_{n in part} h[b][n][d]
__global__ void k_hmean(const float* __restrict__ h, float* __restrict__ hmean4) {
  int b = blockIdx.x, part = blockIdx.y, d = threadIdx.x;
  const float* p = h + ((size_t)b * N_ + part * 128) * H_ + d;
  float s = 0.f;
  #pragma unroll 8
  for (int n = 0; n < 128; ++n) s += p[n * H_];
  hmean4[(b * 4 + part) * H_ + d] = s;
}

// Per-batch GRU constants: c_*[b][d] = bias[d] + h_mean[b]·W*[256:512,d] + jets[b]·W*[512:520,d]
__global__ void k_cvec(const float* __restrict__ hmean4, const float* __restrict__ jets,
                       const float* __restrict__ Wz, const float* __restrict__ Wr,
                       const float* __restrict__ Wh,
                       const float* __restrict__ bz, const float* __restrict__ br,
                       const float* __restrict__ bh,
                       float* __restrict__ cz, float* __restrict__ cr, float* __restrict__ ch) {
  __shared__ float hm[H_];
  __shared__ float jt[FJ];
  int b = blockIdx.x, d = threadIdx.x;
  hm[d] = (hmean4[(b * 4 + 0) * H_ + d] + hmean4[(b * 4 + 1) * H_ + d] +
           hmean4[(b * 4 + 2) * H_ + d] + hmean4[(b * 4 + 3) * H_ + d]) * (1.f / N_);
  if (d < FJ) jt[d] = jets[b * FJ + d];
  __syncthreads();
  float az = bz[d], ar = br[d], ah = bh[d];
  #pragma unroll 4
  for (int k = 0; k < H_; ++k) {
    float m = hm[k];
    az += m * Wz[(256 + k) * 256 + d];
    ar += m * Wr[(256 + k) * 256 + d];
    ah += m * Wh[(256 + k) * 256 + d];
  }
  #pragma unroll
  for (int f = 0; f < FJ; ++f) {
    float j = jt[f];
    az += j * Wz[(512 + f) * 256 + d];
    ar += j * Wr[(512 + f) * 256 + d];
    ah += j * Wh[(512 + f) * 256 + d];
  }
  cz[b * H_ + d] = az;
  cr[b * H_ + d] = ar;
  ch[b * H_ + d] = ah;
}

// h16 = linear f16 copy of h
__global__ void k_h16(const float* __restrict__ h, f16* __restrict__ h16) {
  int t  = blockIdx.x * 256 + threadIdx.x;   // chunk id: 2,097,152
  const float* p = h + (size_t)t * 8;
  f32x4 v0 = *(const f32x4*)p;
  f32x4 v1 = *(const f32x4*)(p + 4);
  f16x8 hv;
  #pragma unroll
  for (int e = 0; e < 4; ++e) { hv[e] = (f16)v0[e]; hv[4 + e] = (f16)v1[e]; }
  *(f16x8*)&h16[(size_t)t * 8] = hv;
}

// ===========================================================================
// Shared GEMM geometry: 128x128 tile, 4 waves 2x2 (wave 64x64, acc[4][4]),
// BK=64.  ASYMMETRIC deep pipeline (X: 3 buf, 2-ahead; Y: 2 buf, 1-ahead).
// Ledger (verified R11): issue Y(kt+1) THEN X(kt+2); queue =
// X(kt),Y(kt),X(kt+1),Y(kt+1),X(kt+2) = 20 -> vmcnt(12) retires X(kt)+Y(kt).
// Tails: rem==1 -> Y only, vmcnt(8); rem==0 -> vmcnt(0). Two barriers/iter.
// ===========================================================================
#define GEMM_PRE()                                                      \
  const int tid = threadIdx.x, lane = tid & 63, wave = tid >> 6;        \
  const int g = lane >> 4, m16 = lane & 15;                             \
  const int wr = (wave >> 1) * 64, wc = (wave & 1) * 64;                \
  f32x4 acc[4][4] = {};

#define GEMM_COMPUTE(Ab, Bb)                                            \
  _Pragma("unroll")                                                     \
  for (int ks = 0; ks < 2; ++ks) {                                      \
    f16x8 af[4], bf[4];                                                 \
    _Pragma("unroll")                                                   \
    for (int mi = 0; mi < 4; ++mi)                                      \
      af[mi] = *(const f16x8*)((const char*)(Ab) + (wr + mi * 16 + m16) * 128 \
                               + (((ks * 4 + g) ^ (m16 & 7)) << 4));    \
    _Pragma("unroll")                                                   \
    for (int ni = 0; ni < 4; ++ni)                                      \
      bf[ni] = *(const f16x8*)((const char*)(Bb) + (wc + ni * 16 + m16) * 128 \
                               + (((ks * 4 + g) ^ (m16 & 7)) << 4));    \
    _Pragma("unroll")                                                   \
    for (int mi = 0; mi < 4; ++mi)                                      \
      _Pragma("unroll")                                                 \
      for (int ni = 0; ni < 4; ++ni)                                    \
        acc[mi][ni] = MFMA16(af[mi], bf[ni], acc[mi][ni]);              \
  }

// STGX/STGY each issue exactly 4 gld16 into buffer (buf) for K-cols k0..k0+63.
#define GEMM_LOOP3(KMAX, STGX, STGY, COMPUTE_CALL)                      \
  STGX(0, 0); STGY(0, 0); STGX(1, 64);                                  \
  for (int kt = 0; kt < (KMAX) / 64; ++kt) {                            \
    const int cx = kt % 3, cy = kt & 1;                                 \
    const int rem = (KMAX) / 64 - 1 - kt;                               \
    if (rem >= 2) {                                                     \
      STGY((kt + 1) & 1, (kt + 1) * 64);   /* Y BEFORE X (in-order vmcnt) */ \
      STGX((kt + 2) % 3, (kt + 2) * 64);                                \
      asm volatile("s_waitcnt vmcnt(12)" ::: "memory");                 \
    } else if (rem == 1) {                                              \
      STGY((kt + 1) & 1, (kt + 1) * 64);                                \
      asm volatile("s_waitcnt vmcnt(8)" ::: "memory");                  \
    } else {                                                            \
      asm volatile("s_waitcnt vmcnt(0)" ::: "memory");                  \
    }                                                                   \
    __builtin_amdgcn_sched_barrier(0);                                  \
    __builtin_amdgcn_s_barrier();                                       \
    __builtin_amdgcn_sched_barrier(0);                                  \
    COMPUTE_CALL;                                                       \
    __builtin_amdgcn_s_barrier();                                       \
    __builtin_amdgcn_sched_barrier(0);                                  \
  }

// per-lane source offsets
#define SRC_SWZ(row0) ((size_t)(row0 + wave * 32 + (lane >> 3)) * 512 \
                       + (size_t)(((lane & 7) ^ ((lane >> 3) & 7)) << 4))
#define SRC_IMG(row0, RS) ((size_t)(row0 + wave * 32 + (lane >> 3)) * (RS) \
                           + (size_t)((lane & 7) << 4))

// ---------------------------------------------------------------------------
// q = f16(h @ Wa + ba). 1024 blocks, XCD-swizzled; orig o: n = o&1, m = o>>1.
// X = A (h16 stream, 3-buf), Y = B (WaT image, 2-buf).
// ---------------------------------------------------------------------------
__global__ __launch_bounds__(256) void k_gemm_q(
    const f16* __restrict__ h16, const f16* __restrict__ WaT,
    const float* __restrict__ ba, f16* __restrict__ q) {
  __shared__ __align__(16) f16 AL[3][128 * 64], BL[2][128 * 64];
  GEMM_PRE();
  const int o = XCD_O(7);                       // C = 128
  const int m0 = (o >> 1) * 128, n0 = (o & 1) * 128;
  const size_t a_off = SRC_SWZ(m0);
  const size_t b_off = SRC_IMG(n0, 512);
  #define STGX_Q(buf, k0)                                               \
    {                                                                   \
      const char* sa = (const char*)h16 + a_off + (size_t)(k0) * 2;     \
      char* da = (char*)&AL[buf][0] + wave * 4096;                      \
      _Pragma("unroll")                                                 \
      for (int i_ = 0; i_ < 4; ++i_) gld16(sa + i_ * 4096, da + i_ * 1024); \
    }
  #define STGY_Q(buf, k0)                                               \
    {                                                                   \
      const char* sb = (const char*)WaT + b_off + (size_t)(k0) * 2;     \
      char* db = (char*)&BL[buf][0] + wave * 4096;                      \
      _Pragma("unroll")                                                 \
      for (int i_ = 0; i_ < 4; ++i_) gld16(sb + i_ * 4096, db + i_ * 1024); \
    }
  GEMM_LOOP3(256, STGX_Q, STGY_Q, GEMM_COMPUTE(&AL[cx][0], &BL[cy][0]));
  #pragma unroll
  for (int mi = 0; mi < 4; ++mi)
    #pragma unroll
    for (int ni = 0; ni < 4; ++ni) {
      int gcol = n0 + wc + ni * 16 + m16;
      float bias = ba[gcol];
      #pragma unroll
      for (int r = 0; r < 4; ++r) {
        int grow = m0 + wr + mi * 16 + 4 * g + r;
        q[(size_t)grow * 256 + gcol] = (f16)(acc[mi][ni][r] + bias);
      }
    }
}

// ---------------------------------------------------------------------------
// hmT[b][d][n] = f16( (h[b] @ Wm + bm)^T ). 1024 blocks; o: tile = o&7, b = o>>3
// (swizzle puts all 8 tiles of a batch on one XCD).
// X = B (h16 stream, 3-buf), Y = A (WmT image, 2-buf).
// ---------------------------------------------------------------------------
__global__ __launch_bounds__(256) void k_gemm_hmT(
    const f16* __restrict__ h16, const f16* __restrict__ WmT,
    const float* __restrict__ bm, f16* __restrict__ hmT) {
  __shared__ __align__(16) f16 AL[2][128 * 64], BL[3][128 * 64];
  GEMM_PRE();
  const int o = XCD_O(7);                       // C = 128
  const int b = o >> 3;
  const int m0 = ((o & 7) >> 2) * 128, n0 = (o & 3) * 128;
  const size_t a_off = SRC_IMG(m0, 512);
  const size_t b_off = SRC_SWZ(b * 512 + n0);
  #define STGX_HM(buf, k0)                                              \
    {                                                                   \
      const char* sb = (const char*)h16 + b_off + (size_t)(k0) * 2;     \
      char* db = (char*)&BL[buf][0] + wave * 4096;                      \
      _Pragma("unroll")                                                 \
      for (int i_ = 0; i_ < 4; ++i_) gld16(sb + i_ * 4096, db + i_ * 1024); \
    }
  #define STGY_HM(buf, k0)                                              \
    {                                                                   \
      const char* sa = (const char*)WmT + a_off + (size_t)(k0) * 2;     \
      char* da = (char*)&AL[buf][0] + wave * 4096;                      \
      _Pragma("unroll")                                                 \
      for (int i_ = 0; i_ < 4; ++i_) gld16(sa + i_ * 4096, da + i_ * 1024); \
    }
  GEMM_LOOP3(256, STGX_HM, STGY_HM, GEMM_COMPUTE(&AL[cy][0], &BL[cx][0]));
  #pragma unroll
  for (int mi = 0; mi < 4; ++mi)
    #pragma unroll
    for (int r = 0; r < 4; ++r) {
      int d = m0 + wr + mi * 16 + 4 * g + r;
      float bias = bm[d];
      #pragma unroll
      for (int ni = 0; ni < 4; ++ni) {
        int n = n0 + wc + ni * 16 + m16;
        hmT[(size_t)b * H_ * N_ + (size_t)d * N_ + n] = (f16)(acc[mi][ni][r] + bias);
      }
    }
}

// ---------------------------------------------------------------------------
// Flash attention + DTNN message, v7 (R9 body; grid XCD-swizzled: 512 blocks,
// o: b = o&127, i-tile = o>>7 — 4 i-tiles of a batch share one XCD's L2).
// ---------------------------------------------------------------------------
__global__ __launch_bounds__(256, 2) void k_attn7(
    const f16* __restrict__ q, const float* __restrict__ mask,
    const f16* __restrict__ hmT, const f16* __restrict__ h16,
    f16* __restrict__ msg) {
  __shared__ __align__(16) f16 Kt[2][32 * 256];   // 2 x 16KB
  __shared__ __align__(16) f16 Vt[2][256 * 32];   // 2 x 16KB
  __shared__ float mask_lds[N_];
  const int tid = threadIdx.x, lane = tid & 63, wave = tid >> 6;
  const int l31 = lane & 31, hi = lane >> 5;
  const int o = XCD_O(6);                        // C = 64
  const int b = o & 127, i0 = (o >> 7) * 128 + wave * 32;

  mask_lds[tid]       = mask[b * N_ + tid];
  mask_lds[tid + 256] = mask[b * N_ + tid + 256];

  const f16* qrow = q + (size_t)(b * N_ + i0 + l31) * H_ + hi * 8;
  f16x8 qb[16];
  #pragma unroll
  for (int s5 = 0; s5 < 16; ++s5) qb[s5] = *(const f16x8*)(qrow + s5 * 16);

  f32x16 ot[8] = {};          // O^T: 8 d-tiles x 16 f32
  float mrun = -3.0e38f, lrun = 0.f;

  const char* hvbs = (const char*)(hmT + (size_t)b * H_ * N_);
  const char* h16b = (const char*)(h16 + (size_t)b * N_ * H_);

  auto stageK = [&](int buf, int jt) {
    const int rl = lane >> 5, s5 = lane & 31;
    char* dst = (char*)&Kt[buf][0] + wave * 4096;
    #pragma unroll
    for (int i = 0; i < 4; ++i) {
      int row = wave * 8 + i * 2 + rl;
      const char* src = h16b + (size_t)(jt * 32 + row) * 512
                      + (size_t)((s5 ^ (row & 7)) << 4);
      gld16(src, dst + i * 1024);
    }
  };
  auto stageV = [&](int buf, int jt) {
    const int swz = ((lane & 3) ^ ((lane >> 3) & 3)) << 4;
    char* dst = (char*)&Vt[buf][0] + wave * 4096;
    #pragma unroll
    for (int i = 0; i < 4; ++i) {
      int d = wave * 64 + i * 16 + (lane >> 2);
      gld16(hvbs + (size_t)d * 1024 + jt * 64 + swz, dst + i * 1024);
    }
  };

  __syncthreads();            // mask_lds visible before first use
  stageK(0, 0); stageV(0, 0); // 8 gld16
  __builtin_amdgcn_sched_barrier(0);

  const int x7 = lane & 7, x3 = (l31 >> 1) & 3;

  for (int jt = 0; jt < 16; ++jt) {
    const int cur = jt & 1, j0 = jt * 32;
    if (jt < 15) {
      stageK(cur ^ 1, jt + 1); stageV(cur ^ 1, jt + 1);
      asm volatile("s_waitcnt vmcnt(8)" ::: "memory");
    } else {
      asm volatile("s_waitcnt vmcnt(0)" ::: "memory");
    }
    __builtin_amdgcn_sched_barrier(0);
    __builtin_amdgcn_s_barrier();      // cur K/V visible; prev-buf reads done
    __builtin_amdgcn_sched_barrier(0);

    // ---- S^T = K · Q^T  (16 slabs of K=16)
    const char* kb = (const char*)&Kt[cur][0] + l31 * 512;
    f32x16 st = {};
    __builtin_amdgcn_s_setprio(1);
    #pragma unroll
    for (int s5 = 0; s5 < 16; ++s5) {
      f16x8 kf = *(const f16x8*)(kb + (((s5 * 2 + hi) ^ x7) << 4));
      st = MFMA32(kf, qb[s5], st);
    }
    __builtin_amdgcn_s_setprio(0);

    // ---- in-register online softmax
    float pm = st[0];
    #pragma unroll
    for (int r = 1; r < 16; ++r) pm = fmaxf(pm, st[r]);
    pm = fmaxf(pm, __shfl_xor(pm, 32, 64));
    if (!__all(pm <= mrun + 8.f)) {      // defer-max (T13)
      float mn = fmaxf(mrun, pm);
      float al = __expf(mrun - mn);
      lrun *= al;
      #pragma unroll
      for (int dt = 0; dt < 8; ++dt)
        #pragma unroll
        for (int e = 0; e < 16; ++e) ot[dt][e] *= al;
      mrun = mn;
    }
    float p[16], ts = 0.f;
    #pragma unroll
    for (int r = 0; r < 16; ++r) {
      float mk = mask_lds[j0 + (r & 3) + 8 * (r >> 2) + 4 * hi];
      p[r] = __expf(st[r] - mrun) * mk;
      ts += p[r];
    }
    ts += __shfl_xor(ts, 32, 64);
    lrun += ts;

    // ---- pack P -> f16 B-frags via shfl_xor(32) redistribution
    f16x8 pf[2];
    #pragma unroll
    for (int kk = 0; kk < 2; ++kk) {
      uint32_t pk01 = pkrtz(p[kk * 8 + 0], p[kk * 8 + 1]);
      uint32_t pk23 = pkrtz(p[kk * 8 + 2], p[kk * 8 + 3]);
      uint32_t pk45 = pkrtz(p[kk * 8 + 4], p[kk * 8 + 5]);
      uint32_t pk67 = pkrtz(p[kk * 8 + 6], p[kk * 8 + 7]);
      uint32_t s01 = __shfl_xor(pk01, 32, 64);
      uint32_t s23 = __shfl_xor(pk23, 32, 64);
      uint32_t s45 = __shfl_xor(pk45, 32, 64);
      uint32_t s67 = __shfl_xor(pk67, 32, 64);
      union { uint32_t u[4]; f16x8 v; } w;
      w.u[0] = hi ? s45 : pk01;
      w.u[1] = hi ? s67 : pk23;
      w.u[2] = hi ? pk45 : s01;
      w.u[3] = hi ? pk67 : s23;
      pf[kk] = w.v;
    }

    // ---- O^T += V^T · P^T
    const char* vb = (const char*)&Vt[cur][0] + l31 * 64;
    __builtin_amdgcn_s_setprio(1);
    #pragma unroll
    for (int kk = 0; kk < 2; ++kk)
      #pragma unroll
      for (int dt = 0; dt < 8; ++dt) {
        f16x8 vf = *(const f16x8*)(vb + dt * 2048 + (((kk * 2 + hi) ^ x3) << 4));
        ot[dt] = MFMA32(vf, pf[kk], ot[dt]);
      }
    __builtin_amdgcn_s_setprio(0);

    __builtin_amdgcn_s_barrier();      // all reads of cur done before overwrite
    __builtin_amdgcn_sched_barrier(0);
  }

  // ---- epilogue: msg[i][d] = tanh(rm * O^T[d][i] / l), packed 8B stores
  float rm  = mask_lds[i0 + l31];
  float inv = rm / lrun;
  f16* msgp = msg + (size_t)(b * N_ + i0 + l31) * H_;
  #pragma unroll
  for (int dt = 0; dt < 8; ++dt)
    #pragma unroll
    for (int rg = 0; rg < 4; ++rg) {
      float t0 = tanhfast(ot[dt][rg * 4 + 0] * inv);
      float t1 = tanhfast(ot[dt][rg * 4 + 1] * inv);
      float t2 = tanhfast(ot[dt][rg * 4 + 2] * inv);
      float t3 = tanhfast(ot[dt][rg * 4 + 3] * inv);
      union { uint32_t u[2]; uint64_t q; } w;
      w.u[0] = pkrtz(t0, t1); w.u[1] = pkrtz(t2, t3);
      *(uint64_t*)(msgp + dt * 32 + rg * 8 + 4 * hi) = w.q;
    }
}

// ---------------------------------------------------------------------------
// Gate GEMM 1: pre = [msg|h] @ Wzr + c. 2048 blocks; o: n = o&3, m = o>>2
// (4 n-tiles sharing the A panel co-located on one XCD by the swizzle).
// X = A (msg/h16 stream, 3-buf), Y = B (WzrT image, 2-buf).
// ---------------------------------------------------------------------------
__global__ __launch_bounds__(256) void k_gemm_zr(
    const f16* __restrict__ msg, const f16* __restrict__ h16,
    const f16* __restrict__ WzrT, const float* __restrict__ cz,
    const float* __restrict__ cr, f16* __restrict__ z, f16* __restrict__ rh) {
  __shared__ __align__(16) f16 AL[3][128 * 64], BL[2][128 * 64];
  GEMM_PRE();
  const int o = XCD_O(8);                       // C = 256
  const int m0 = (o >> 2) * 128;
  const int nx = o & 3;
  const int n0 = nx * 128;
  const size_t a_off = SRC_SWZ(m0);
  const size_t b_off = SRC_IMG(n0, 1024);
  #define STGX_ZR(buf, k0)                                              \
    {                                                                   \
      const char* ab = (const char*)((k0) < 256 ? msg : h16);           \
      const char* sa = ab + a_off + (size_t)(((k0) & 255)) * 2;         \
      char* da = (char*)&AL[buf][0] + wave * 4096;                      \
      _Pragma("unroll")                                                 \
      for (int i_ = 0; i_ < 4; ++i_) gld16(sa + i_ * 4096, da + i_ * 1024); \
    }
  #define STGY_ZR(buf, k0)                                              \
    {                                                                   \
      const char* sb = (const char*)WzrT + b_off + (size_t)(k0) * 2;    \
      char* db = (char*)&BL[buf][0] + wave * 4096;                      \
      _Pragma("unroll")                                                 \
      for (int i_ = 0; i_ < 4; ++i_) gld16(sb + i_ * 8192, db + i_ * 1024); \
    }
  GEMM_LOOP3(512, STGX_ZR, STGY_ZR, GEMM_COMPUTE(&AL[cx][0], &BL[cy][0]));
  const int is_r = nx >> 1;
  #pragma unroll
  for (int mi = 0; mi < 4; ++mi)
    #pragma unroll
    for (int ni = 0; ni < 4; ++ni) {
      int ncol = (nx & 1) * 128 + wc + ni * 16 + m16;
      #pragma unroll
      for (int r = 0; r < 4; ++r) {
        int grow = m0 + wr + mi * 16 + 4 * g + r;
        int bb = grow >> 9;
        float a = acc[mi][ni][r];
        size_t oidx = (size_t)grow * 256 + ncol;
        if (!is_r) {
          float v = a + cz[bb * 256 + ncol];
          z[oidx] = (f16)(1.f / (1.f + __expf(-v)));
        } else {
          float v  = a + cr[bb * 256 + ncol];
          float rr = 1.f / (1.f + __expf(-v));
          rh[oidx] = (f16)(rr * (float)h16[oidx]);
        }
      }
    }
}

// ---------------------------------------------------------------------------
// Gate GEMM 2: h_tilde = tanh([msg|rh] @ Whc + c_h); out = (1-z)*h + z*h_tilde
// 1024 blocks; o: n = o&1, m = o>>1. X = A (msg/rh), Y = B (WhcT).
// ---------------------------------------------------------------------------
__global__ __launch_bounds__(256) void k_gemm_ht(
    const f16* __restrict__ msg, const f16* __restrict__ rh,
    const f16* __restrict__ WhcT, const float* __restrict__ ch,
    const f16* __restrict__ z, const f16* __restrict__ h16,
    float* __restrict__ out) {
  __shared__ __align__(16) f16 AL[3][128 * 64], BL[2][128 * 64];
  GEMM_PRE();
  const int o = XCD_O(7);                       // C = 128
  const int m0 = (o >> 1) * 128;
  const int n0 = (o & 1) * 128;
  const size_t a_off = SRC_SWZ(m0);
  const size_t b_off = SRC_IMG(n0, 1024);
  #define STGX_HT(buf, k0)                                              \
    {                                                                   \
      const char* ab = (const char*)((k0) < 256 ? msg : rh);            \
      const char* sa = ab + a_off + (size_t)(((k0) & 255)) * 2;         \
      char* da = (char*)&AL[buf][0] + wave * 4096;                      \
      _Pragma("unroll")                                                 \
      for (int i_ = 0; i_ < 4; ++i_) gld16(sa + i_ * 4096, da + i_ * 1024); \
    }
  #define STGY_HT(buf, k0)                                              \
    {                                                                   \
      const char* sb = (const char*)WhcT + b_off + (size_t)(k0) * 2;    \
      char* db = (char*)&BL[buf][0] + wave * 4096;                      \
      _Pragma("unroll")                                                 \
      for (int i_ = 0; i_ < 4; ++i_) gld16(sb + i_ * 8192, db + i_ * 1024); \
    }
  GEMM_LOOP3(512, STGX_HT, STGY_HT, GEMM_COMPUTE(&AL[cx][0], &BL[cy][0]));
  #pragma unroll
  for (int mi = 0; mi < 4; ++mi)
    #pragma unroll
    for (int ni = 0; ni < 4; ++ni) {
      int gcol = n0 + wc + ni * 16 + m16;
      #pragma unroll
      for (int r = 0; r < 4; ++r) {
        int grow = m0 + wr + mi * 16 + 4 * g + r;
        int bb = grow >> 9;
        size_t oidx = (size_t)grow * 256 + gcol;
        float pre = acc[mi][ni][r] + ch[bb * 256 + gcol];
        float htl = tanhf(pre);
        float zv  = (float)z[oidx];
        float hv  = (float)h16[oidx];
        out[oidx] = (1.f - zv) * hv + zv * htl;
      }
    }
}

// ---------------------------------------------------------------------------
extern "C" void kernel_launch(void* const* d_in, const int* in_sizes, int n_in,
                              void* d_out, int out_size, void* d_ws, size_t ws_size,
                              hipStream_t stream) {
  const float* h    = (const float*)d_in[0];
  const float* jets = (const float*)d_in[1];
  const float* mask = (const float*)d_in[2];
  const float* Wa   = (const float*)d_in[3];
  const float* ba   = (const float*)d_in[4];
  const float* Wm   = (const float*)d_in[5];
  const float* bm   = (const float*)d_in[6];
  const float* Wz   = (const float*)d_in[7];
  const float* bz   = (const float*)d_in[8];
  const float* Wr   = (const float*)d_in[9];
  const float* br   = (const float*)d_in[10];
  const float* Wh   = (const float*)d_in[11];
  const float* bh   = (const float*)d_in[12];
  float* out = (float*)d_out;

  char* ws = (char*)d_ws;
  size_t off = 0;
  auto alloc = [&](size_t bytes) -> void* {
    void* p = ws + off;
    off += (bytes + 255) & ~(size_t)255;
    return p;
  };
  // big: q (f16, 32MB) during attention; z (f16) + rh (f16) afterwards.
  char*   big   = (char*) alloc((size_t)ROWS * H_ * 4);
  f16*    hmT   = (f16*)  alloc((size_t)B_ * H_ * N_ * 2);
  f16*    msg   = (f16*)  alloc((size_t)ROWS * H_ * 2);
  f16*    h16   = (f16*)  alloc((size_t)ROWS * H_ * 2);
  float*  hmean4= (float*)alloc((size_t)B_ * 4 * H_ * 4);
  float*  cz    = (float*)alloc((size_t)B_ * H_ * 4);
  float*  cr    = (float*)alloc((size_t)B_ * H_ * 4);
  float*  chv   = (float*)alloc((size_t)B_ * H_ * 4);
  f16*    WaT   = (f16*)  alloc(65536 * 2);
  f16*    WmT   = (f16*)  alloc(65536 * 2);
  f16*    WzrT  = (f16*)  alloc(262144 * 2);
  f16*    WhcT  = (f16*)  alloc(131072 * 2);
  f16* q  = (f16*)big;
  f16* z  = (f16*)big;                                     // q dead after attn
  f16* rh = (f16*)(big + (size_t)ROWS * H_ * 2);
  if (off > ws_size) return;  // workspace insufficient

  k_prep    <<<2048, 256, 0, stream>>>(Wa, Wm, Wz, Wr, Wh, WaT, WmT, WzrT, WhcT);
  k_hmean   <<<dim3(B_, 4), H_, 0, stream>>>(h, hmean4);
  k_cvec    <<<B_, H_, 0, stream>>>(hmean4, jets, Wz, Wr, Wh, bz, br, bh, cz, cr, chv);
  k_h16     <<<8192, 256, 0, stream>>>(h, h16);
  k_gemm_q  <<<1024, 256, 0, stream>>>(h16, WaT, ba, q);
  k_gemm_hmT<<<1024, 256, 0, stream>>>(h16, WmT, bm, hmT);
  k_attn7   <<<512, 256, 0, stream>>>(q, mask, hmT, h16, msg);
  k_gemm_zr <<<2048, 256, 0, stream>>>(msg, h16, WzrT, cz, cr, z, rh);
  k_gemm_ht <<<1024, 256, 0, stream>>>(msg, rh, WhcT, chv, z, h16, out);
}

// Round 13
// 369.337 us; speedup vs baseline: 1.8636x; 1.1721x over previous
//
#include <hip/hip_runtime.h>

// Problem constants (from reference): B=128, N=512, H=256, F_JET=8, gin=776.
#define B_   128
#define N_   512
#define H_   256
#define FJ   8
#define ROWS (B_ * N_)          // 65536 flattened vertex rows
#define NEGV (-1e9f)

typedef _Float16 f16;
typedef __attribute__((ext_vector_type(8)))  f16   f16x8;    // MFMA A/B fragment (4 VGPRs)
typedef __attribute__((ext_vector_type(4)))  float f32x4;    // 16x16 C/D fragment
typedef __attribute__((ext_vector_type(16))) float f32x16;   // 32x32 C/D fragment

static __device__ inline f32x4 MFMA16(f16x8 a, f16x8 b, f32x4 c) {
  return __builtin_amdgcn_mfma_f32_16x16x32_f16(a, b, c, 0, 0, 0);
}
static __device__ inline f32x16 MFMA32(f16x8 a, f16x8 b, f32x16 c) {
  return __builtin_amdgcn_mfma_f32_32x32x16_f16(a, b, c, 0, 0, 0);
}

// global -> LDS direct copy, 16B per lane. LDS ptr must be wave-uniform; HW adds lane*16.
static __device__ inline void gld16(const void* g, void* l) {
  __builtin_amdgcn_global_load_lds(
      (const __attribute__((address_space(1))) void*)g,
      (__attribute__((address_space(3))) void*)(uintptr_t)l,
      16, 0, 0);
}

// pack two f32 -> 2 f16 in one u32 (v_cvt_pkrtz_f16_f32)
static __device__ inline uint32_t pkrtz(float a, float b) {
  auto v = __builtin_amdgcn_cvt_pkrtz(a, b);
  return __builtin_bit_cast(uint32_t, v);
}
static __device__ inline float tanhfast(float x) {
  float e = __expf(2.f * x);
  return 1.f - 2.f / (e + 1.f);
}

// XCD-aware bijective block remap (T1): launch slot s -> original block o.
// Forward map (o -> slot) is s = (o&7)*C + (o>>3), C = nwg/8 (power of 2).
// 8 consecutive original blocks (sharing operand panels) land on ONE XCD.
#define XCD_O(LG_C) ((int)(((blockIdx.x & ((1u << (LG_C)) - 1)) << 3) | (blockIdx.x >> (LG_C))))

// ---------------------------------------------------------------------------
// Prep: transpose/convert weights to fp16 with the LDS bank-swizzle BAKED IN:
// within each row, 16B-chunk c is stored at slot c^(row&7)  (8-chunk window).
// ---------------------------------------------------------------------------
__global__ void k_prep(const float* __restrict__ Wa, const float* __restrict__ Wm,
                       const float* __restrict__ Wz, const float* __restrict__ Wr,
                       const float* __restrict__ Wh,
                       f16* __restrict__ WaT, f16* __restrict__ WmT,
                       f16* __restrict__ WzrT, f16* __restrict__ WhcT) {
  int idx = blockIdx.x * 256 + threadIdx.x;
  if (idx < 65536) {
    int d = idx >> 8, k = idx & 255;
    int kk = ((((k >> 3) ^ (d & 7)) << 3) | (k & 7));
    WaT[d * 256 + kk] = (f16)Wa[k * 256 + d];
  } else if (idx < 131072) {
    int t = idx - 65536;
    int d = t >> 8, k = t & 255;
    int kk = ((((k >> 3) ^ (d & 7)) << 3) | (k & 7));
    WmT[d * 256 + kk] = (f16)Wm[k * 256 + d];
  } else if (idx < 131072 + 262144) {
    int t = idx - 131072;
    int n = t >> 9, k = t & 511;
    const float* src = (n < 256) ? Wz : Wr;
    int np  = n & 255;
    int row = (k < 256) ? k : (264 + k);   // 520 + (k - 256)
    int kk = ((((k >> 3) ^ (n & 7)) << 3) | (k & 7));
    WzrT[n * 512 + kk] = (f16)src[row * 256 + np];
  } else {
    int t = idx - (131072 + 262144);       // < 131072
    int n = t >> 9, k = t & 511;
    int row = (k < 256) ? k : (264 + k);
    int kk = ((((k >> 3) ^ (n & 7)) << 3) | (k & 7));
    WhcT[n * 512 + kk] = (f16)Wh[row * 256 + n];
  }
}

// FUSED: partial column sums AND f16 image of h in one pass over h.
// hmean4[b][part][d] = sum_{n in part} h[b][n][d];  h16 = f16(h).
__global__ void k_hmean(const float* __restrict__ h, float* __restrict__ hmean4,
                        f16* __restrict__ h16) {
  int b = blockIdx.x, part = blockIdx.y, d = threadIdx.x;
  size_t base = ((size_t)b * N_ + part * 128) * H_ + d;
  const float* p = h + base;
  f16* p16 = h16 + base;
  float s = 0.f;
  #pragma unroll 8
  for (int n = 0; n < 128; ++n) {
    float v = p[n * H_];
    s += v;
    p16[n * H_] = (f16)v;
  }
  hmean4[(b * 4 + part) * H_ + d] = s;
}

// Per-batch GRU constants: c_*[b][d] = bias[d] + h_mean[b]·W*[256:512,d] + jets[b]·W*[512:520,d]
__global__ void k_cvec(const float* __restrict__ hmean4, const float* __restrict__ jets,
                       const float* __restrict__ Wz, const float* __restrict__ Wr,
                       const float* __restrict__ Wh,
                       const float* __restrict__ bz, const float* __restrict__ br,
                       const float* __restrict__ bh,
                       float* __restrict__ cz, float* __restrict__ cr, float* __restrict__ ch) {
  __shared__ float hm[H_];
  __shared__ float jt[FJ];
  int b = blockIdx.x, d = threadIdx.x;
  hm[d] = (hmean4[(b * 4 + 0) * H_ + d] + hmean4[(b * 4 + 1) * H_ + d] +
           hmean4[(b * 4 + 2) * H_ + d] + hmean4[(b * 4 + 3) * H_ + d]) * (1.f / N_);
  if (d < FJ) jt[d] = jets[b * FJ + d];
  __syncthreads();
  float az = bz[d], ar = br[d], ah = bh[d];
  #pragma unroll 4
  for (int k = 0; k < H_; ++k) {
    float m = hm[k];
    az += m * Wz[(256 + k) * 256 + d];
    ar += m * Wr[(256 + k) * 256 + d];
    ah += m * Wh[(256 + k) * 256 + d];
  }
  #pragma unroll
  for (int f = 0; f < FJ; ++f) {
    float j = jt[f];
    az += j * Wz[(512 + f) * 256 + d];
    ar += j * Wr[(512 + f) * 256 + d];
    ah += j * Wh[(512 + f) * 256 + d];
  }
  cz[b * H_ + d] = az;
  cr[b * H_ + d] = ar;
  ch[b * H_ + d] = ah;
}

// ===========================================================================
// Shared GEMM geometry: 128x128 tile, 4 waves 2x2 (wave 64x64, acc[4][4]),
// BK=64, SINGLE-buffered LDS (A 16KB + B 16KB = 32KB -> 4-5 blocks/CU).
// m97-style loop (latency hidden by TLP, not in-wave prefetch — m114):
//   [stage A(kt), B(kt)]            (LDS free: after barrier #2 of kt-1)
//   vmcnt(0)   -> own loads landed
//   s_barrier  -> all waves' loads landed
//   compute
//   s_barrier  -> all reads done before kt+1's stage overwrites.  Race-free.
// ===========================================================================
#define GEMM_PRE()                                                      \
  const int tid = threadIdx.x, lane = tid & 63, wave = tid >> 6;        \
  const int g = lane >> 4, m16 = lane & 15;                             \
  const int wr = (wave >> 1) * 64, wc = (wave & 1) * 64;                \
  f32x4 acc[4][4] = {};

#define GEMM_COMPUTE(Ab, Bb)                                            \
  _Pragma("unroll")                                                     \
  for (int ks = 0; ks < 2; ++ks) {                                      \
    f16x8 af[4], bf[4];                                                 \
    _Pragma("unroll")                                                   \
    for (int mi = 0; mi < 4; ++mi)                                      \
      af[mi] = *(const f16x8*)((const char*)(Ab) + (wr + mi * 16 + m16) * 128 \
                               + (((ks * 4 + g) ^ (m16 & 7)) << 4));    \
    _Pragma("unroll")                                                   \
    for (int ni = 0; ni < 4; ++ni)                                      \
      bf[ni] = *(const f16x8*)((const char*)(Bb) + (wc + ni * 16 + m16) * 128 \
                               + (((ks * 4 + g) ^ (m16 & 7)) << 4));    \
    _Pragma("unroll")                                                   \
    for (int mi = 0; mi < 4; ++mi)                                      \
      _Pragma("unroll")                                                 \
      for (int ni = 0; ni < 4; ++ni)                                    \
        acc[mi][ni] = MFMA16(af[mi], bf[ni], acc[mi][ni]);              \
  }

// STGX/STGY each issue exactly 4 gld16 for K-cols k0..k0+63 (buf arg kept for
// macro-compat; always 0 = single buffer).
#define GEMM_LOOP1(KMAX, STGX, STGY)                                    \
  for (int kt = 0; kt < (KMAX) / 64; ++kt) {                            \
    STGX(0, kt * 64);                                                   \
    STGY(0, kt * 64);                                                   \
    asm volatile("s_waitcnt vmcnt(0)" ::: "memory");                    \
    __builtin_amdgcn_sched_barrier(0);                                  \
    __builtin_amdgcn_s_barrier();                                       \
    __builtin_amdgcn_sched_barrier(0);                                  \
    GEMM_COMPUTE(&AL[0], &BL[0]);                                       \
    __builtin_amdgcn_s_barrier();                                       \
    __builtin_amdgcn_sched_barrier(0);                                  \
  }

// per-lane source offsets
#define SRC_SWZ(row0) ((size_t)(row0 + wave * 32 + (lane >> 3)) * 512 \
                       + (size_t)(((lane & 7) ^ ((lane >> 3) & 7)) << 4))
#define SRC_IMG(row0, RS) ((size_t)(row0 + wave * 32 + (lane >> 3)) * (RS) \
                           + (size_t)((lane & 7) << 4))

// ---------------------------------------------------------------------------
// q = f16(h @ Wa + ba). 1024 blocks XCD-swizzled; o: n = o&1, m = o>>1.
// ---------------------------------------------------------------------------
__global__ __launch_bounds__(256) void k_gemm_q(
    const f16* __restrict__ h16, const f16* __restrict__ WaT,
    const float* __restrict__ ba, f16* __restrict__ q) {
  __shared__ __align__(16) f16 AL[128 * 64], BL[128 * 64];
  GEMM_PRE();
  const int o = XCD_O(7);                       // C = 128
  const int m0 = (o >> 1) * 128, n0 = (o & 1) * 128;
  const size_t a_off = SRC_SWZ(m0);
  const size_t b_off = SRC_IMG(n0, 512);
  #define STGX_Q(buf, k0)                                               \
    {                                                                   \
      const char* sa = (const char*)h16 + a_off + (size_t)(k0) * 2;     \
      char* da = (char*)&AL[0] + wave * 4096;                           \
      _Pragma("unroll")                                                 \
      for (int i_ = 0; i_ < 4; ++i_) gld16(sa + i_ * 4096, da + i_ * 1024); \
    }
  #define STGY_Q(buf, k0)                                               \
    {                                                                   \
      const char* sb = (const char*)WaT + b_off + (size_t)(k0) * 2;     \
      char* db = (char*)&BL[0] + wave * 4096;                           \
      _Pragma("unroll")                                                 \
      for (int i_ = 0; i_ < 4; ++i_) gld16(sb + i_ * 4096, db + i_ * 1024); \
    }
  GEMM_LOOP1(256, STGX_Q, STGY_Q);
  #pragma unroll
  for (int mi = 0; mi < 4; ++mi)
    #pragma unroll
    for (int ni = 0; ni < 4; ++ni) {
      int gcol = n0 + wc + ni * 16 + m16;
      float bias = ba[gcol];
      #pragma unroll
      for (int r = 0; r < 4; ++r) {
        int grow = m0 + wr + mi * 16 + 4 * g + r;
        q[(size_t)grow * 256 + gcol] = (f16)(acc[mi][ni][r] + bias);
      }
    }
}

// ---------------------------------------------------------------------------
// hmT[b][d][n] = f16( (h[b] @ Wm + bm)^T ). 1024 blocks; o: tile = o&7, b = o>>3.
// ---------------------------------------------------------------------------
__global__ __launch_bounds__(256) void k_gemm_hmT(
    const f16* __restrict__ h16, const f16* __restrict__ WmT,
    const float* __restrict__ bm, f16* __restrict__ hmT) {
  __shared__ __align__(16) f16 AL[128 * 64], BL[128 * 64];
  GEMM_PRE();
  const int o = XCD_O(7);                       // C = 128
  const int b = o >> 3;
  const int m0 = ((o & 7) >> 2) * 128, n0 = (o & 3) * 128;
  const size_t a_off = SRC_IMG(m0, 512);
  const size_t b_off = SRC_SWZ(b * 512 + n0);
  #define STGX_HM(buf, k0)                                              \
    {                                                                   \
      const char* sb = (const char*)h16 + b_off + (size_t)(k0) * 2;     \
      char* db = (char*)&BL[0] + wave * 4096;                           \
      _Pragma("unroll")                                                 \
      for (int i_ = 0; i_ < 4; ++i_) gld16(sb + i_ * 4096, db + i_ * 1024); \
    }
  #define STGY_HM(buf, k0)                                              \
    {                                                                   \
      const char* sa = (const char*)WmT + a_off + (size_t)(k0) * 2;     \
      char* da = (char*)&AL[0] + wave * 4096;                           \
      _Pragma("unroll")                                                 \
      for (int i_ = 0; i_ < 4; ++i_) gld16(sa + i_ * 4096, da + i_ * 1024); \
    }
  GEMM_LOOP1(256, STGX_HM, STGY_HM);
  #pragma unroll
  for (int mi = 0; mi < 4; ++mi)
    #pragma unroll
    for (int r = 0; r < 4; ++r) {
      int d = m0 + wr + mi * 16 + 4 * g + r;
      float bias = bm[d];
      #pragma unroll
      for (int ni = 0; ni < 4; ++ni) {
        int n = n0 + wc + ni * 16 + m16;
        hmT[(size_t)b * H_ * N_ + (size_t)d * N_ + n] = (f16)(acc[mi][ni][r] + bias);
      }
    }
}

// ---------------------------------------------------------------------------
// Flash attention + DTNN message, v7 (UNCHANGED from R12 — passing).
// ---------------------------------------------------------------------------
__global__ __launch_bounds__(256, 2) void k_attn7(
    const f16* __restrict__ q, const float* __restrict__ mask,
    const f16* __restrict__ hmT, const f16* __restrict__ h16,
    f16* __restrict__ msg) {
  __shared__ __align__(16) f16 Kt[2][32 * 256];   // 2 x 16KB
  __shared__ __align__(16) f16 Vt[2][256 * 32];   // 2 x 16KB
  __shared__ float mask_lds[N_];
  const int tid = threadIdx.x, lane = tid & 63, wave = tid >> 6;
  const int l31 = lane & 31, hi = lane >> 5;
  const int o = XCD_O(6);                        // C = 64
  const int b = o & 127, i0 = (o >> 7) * 128 + wave * 32;

  mask_lds[tid]       = mask[b * N_ + tid];
  mask_lds[tid + 256] = mask[b * N_ + tid + 256];

  const f16* qrow = q + (size_t)(b * N_ + i0 + l31) * H_ + hi * 8;
  f16x8 qb[16];
  #pragma unroll
  for (int s5 = 0; s5 < 16; ++s5) qb[s5] = *(const f16x8*)(qrow + s5 * 16);

  f32x16 ot[8] = {};          // O^T: 8 d-tiles x 16 f32
  float mrun = -3.0e38f, lrun = 0.f;

  const char* hvbs = (const char*)(hmT + (size_t)b * H_ * N_);
  const char* h16b = (const char*)(h16 + (size_t)b * N_ * H_);

  auto stageK = [&](int buf, int jt) {
    const int rl = lane >> 5, s5 = lane & 31;
    char* dst = (char*)&Kt[buf][0] + wave * 4096;
    #pragma unroll
    for (int i = 0; i < 4; ++i) {
      int row = wave * 8 + i * 2 + rl;
      const char* src = h16b + (size_t)(jt * 32 + row) * 512
                      + (size_t)((s5 ^ (row & 7)) << 4);
      gld16(src, dst + i * 1024);
    }
  };
  auto stageV = [&](int buf, int jt) {
    const int swz = ((lane & 3) ^ ((lane >> 3) & 3)) << 4;
    char* dst = (char*)&Vt[buf][0] + wave * 4096;
    #pragma unroll
    for (int i = 0; i < 4; ++i) {
      int d = wave * 64 + i * 16 + (lane >> 2);
      gld16(hvbs + (size_t)d * 1024 + jt * 64 + swz, dst + i * 1024);
    }
  };

  __syncthreads();            // mask_lds visible before first use
  stageK(0, 0); stageV(0, 0); // 8 gld16
  __builtin_amdgcn_sched_barrier(0);

  const int x7 = lane & 7, x3 = (l31 >> 1) & 3;

  for (int jt = 0; jt < 16; ++jt) {
    const int cur = jt & 1, j0 = jt * 32;
    if (jt < 15) {
      stageK(cur ^ 1, jt + 1); stageV(cur ^ 1, jt + 1);
      asm volatile("s_waitcnt vmcnt(8)" ::: "memory");
    } else {
      asm volatile("s_waitcnt vmcnt(0)" ::: "memory");
    }
    __builtin_amdgcn_sched_barrier(0);
    __builtin_amdgcn_s_barrier();      // cur K/V visible; prev-buf reads done
    __builtin_amdgcn_sched_barrier(0);

    // ---- S^T = K · Q^T  (16 slabs of K=16)
    const char* kb = (const char*)&Kt[cur][0] + l31 * 512;
    f32x16 st = {};
    __builtin_amdgcn_s_setprio(1);
    #pragma unroll
    for (int s5 = 0; s5 < 16; ++s5) {
      f16x8 kf = *(const f16x8*)(kb + (((s5 * 2 + hi) ^ x7) << 4));
      st = MFMA32(kf, qb[s5], st);
    }
    __builtin_amdgcn_s_setprio(0);

    // ---- in-register online softmax
    float pm = st[0];
    #pragma unroll
    for (int r = 1; r < 16; ++r) pm = fmaxf(pm, st[r]);
    pm = fmaxf(pm, __shfl_xor(pm, 32, 64));
    if (!__all(pm <= mrun + 8.f)) {      // defer-max (T13)
      float mn = fmaxf(mrun, pm);
      float al = __expf(mrun - mn);
      lrun *= al;
      #pragma unroll
      for (int dt = 0; dt < 8; ++dt)
        #pragma unroll
        for (int e = 0; e < 16; ++e) ot[dt][e] *= al;
      mrun = mn;
    }
    float p[16], ts = 0.f;
    #pragma unroll
    for (int r = 0; r < 16; ++r) {
      float mk = mask_lds[j0 + (r & 3) + 8 * (r >> 2) + 4 * hi];
      p[r] = __expf(st[r] - mrun) * mk;
      ts += p[r];
    }
    ts += __shfl_xor(ts, 32, 64);
    lrun += ts;

    // ---- pack P -> f16 B-frags via shfl_xor(32) redistribution
    f16x8 pf[2];
    #pragma unroll
    for (int kk = 0; kk < 2; ++kk) {
      uint32_t pk01 = pkrtz(p[kk * 8 + 0], p[kk * 8 + 1]);
      uint32_t pk23 = pkrtz(p[kk * 8 + 2], p[kk * 8 + 3]);
      uint32_t pk45 = pkrtz(p[kk * 8 + 4], p[kk * 8 + 5]);
      uint32_t pk67 = pkrtz(p[kk * 8 + 6], p[kk * 8 + 7]);
      uint32_t s01 = __shfl_xor(pk01, 32, 64);
      uint32_t s23 = __shfl_xor(pk23, 32, 64);
      uint32_t s45 = __shfl_xor(pk45, 32, 64);
      uint32_t s67 = __shfl_xor(pk67, 32, 64);
      union { uint32_t u[4]; f16x8 v; } w;
      w.u[0] = hi ? s45 : pk01;
      w.u[1] = hi ? s67 : pk23;
      w.u[2] = hi ? pk45 : s01;
      w.u[3] = hi ? pk67 : s23;
      pf[kk] = w.v;
    }

    // ---- O^T += V^T · P^T
    const char* vb = (const char*)&Vt[cur][0] + l31 * 64;
    __builtin_amdgcn_s_setprio(1);
    #pragma unroll
    for (int kk = 0; kk < 2; ++kk)
      #pragma unroll
      for (int dt = 0; dt < 8; ++dt) {
        f16x8 vf = *(const f16x8*)(vb + dt * 2048 + (((kk * 2 + hi) ^ x3) << 4));
        ot[dt] = MFMA32(vf, pf[kk], ot[dt]);
      }
    __builtin_amdgcn_s_setprio(0);

    __builtin_amdgcn_s_barrier();      // all reads of cur done before overwrite
    __builtin_amdgcn_sched_barrier(0);
  }

  // ---- epilogue: msg[i][d] = tanh(rm * O^T[d][i] / l), packed 8B stores
  float rm  = mask_lds[i0 + l31];
  float inv = rm / lrun;
  f16* msgp = msg + (size_t)(b * N_ + i0 + l31) * H_;
  #pragma unroll
  for (int dt = 0; dt < 8; ++dt)
    #pragma unroll
    for (int rg = 0; rg < 4; ++rg) {
      float t0 = tanhfast(ot[dt][rg * 4 + 0] * inv);
      float t1 = tanhfast(ot[dt][rg * 4 + 1] * inv);
      float t2 = tanhfast(ot[dt][rg * 4 + 2] * inv);
      float t3 = tanhfast(ot[dt][rg * 4 + 3] * inv);
      union { uint32_t u[2]; uint64_t q; } w;
      w.u[0] = pkrtz(t0, t1); w.u[1] = pkrtz(t2, t3);
      *(uint64_t*)(msgp + dt * 32 + rg * 8 + 4 * hi) = w.q;
    }
}

// ---------------------------------------------------------------------------
// Gate GEMM 1: pre = [msg|h] @ Wzr + c. 2048 blocks; o: n = o&3, m = o>>2.
// ---------------------------------------------------------------------------
__global__ __launch_bounds__(256) void k_gemm_zr(
    const f16* __restrict__ msg, const f16* __restrict__ h16,
    const f16* __restrict__ WzrT, const float* __restrict__ cz,
    const float* __restrict__ cr, f16* __restrict__ z, f16* __restrict__ rh) {
  __shared__ __align__(16) f16 AL[128 * 64], BL[128 * 64];
  GEMM_PRE();
  const int o = XCD_O(8);                       // C = 256
  const int m0 = (o >> 2) * 128;
  const int nx = o & 3;
  const int n0 = nx * 128;
  const size_t a_off = SRC_SWZ(m0);
  const size_t b_off = SRC_IMG(n0, 1024);
  #define STGX_ZR(buf, k0)                                              \
    {                                                                   \
      const char* ab = (const char*)((k0) < 256 ? msg : h16);           \
      const char* sa = ab + a_off + (size_t)(((k0) & 255)) * 2;         \
      char* da = (char*)&AL[0] + wave * 4096;                           \
      _Pragma("unroll")                                                 \
      for (int i_ = 0; i_ < 4; ++i_) gld16(sa + i_ * 4096, da + i_ * 1024); \
    }
  #define STGY_ZR(buf, k0)                                              \
    {                                                                   \
      const char* sb = (const char*)WzrT + b_off + (size_t)(k0) * 2;    \
      char* db = (char*)&BL[0] + wave * 4096;                           \
      _Pragma("unroll")                                                 \
      for (int i_ = 0; i_ < 4; ++i_) gld16(sb + i_ * 8192, db + i_ * 1024); \
    }
  GEMM_LOOP1(512, STGX_ZR, STGY_ZR);
  const int is_r = nx >> 1;
  #pragma unroll
  for (int mi = 0; mi < 4; ++mi)
    #pragma unroll
    for (int ni = 0; ni < 4; ++ni) {
      int ncol = (nx & 1) * 128 + wc + ni * 16 + m16;
      #pragma unroll
      for (int r = 0; r < 4; ++r) {
        int grow = m0 + wr + mi * 16 + 4 * g + r;
        int bb = grow >> 9;
        float a = acc[mi][ni][r];
        size_t oidx = (size_t)grow * 256 + ncol;
        if (!is_r) {
          float v = a + cz[bb * 256 + ncol];
          z[oidx] = (f16)(1.f / (1.f + __expf(-v)));
        } else {
          float v  = a + cr[bb * 256 + ncol];
          float rr = 1.f / (1.f + __expf(-v));
          rh[oidx] = (f16)(rr * (float)h16[oidx]);
        }
      }
    }
}

// ---------------------------------------------------------------------------
// Gate GEMM 2: h_tilde = tanh([msg|rh] @ Whc + c_h); out = (1-z)*h + z*h_tilde
// 1024 blocks; o: n = o&1, m = o>>1.
// ---------------------------------------------------------------------------
__global__ __launch_bounds__(256) void k_gemm_ht(
    const f16* __restrict__ msg, const f16* __restrict__ rh,
    const f16* __restrict__ WhcT, const float* __restrict__ ch,
    const f16* __restrict__ z, const f16* __restrict__ h16,
    float* __restrict__ out) {
  __shared__ __align__(16) f16 AL[128 * 64], BL[128 * 64];
  GEMM_PRE();
  const int o = XCD_O(7);                       // C = 128
  const int m0 = (o >> 1) * 128;
  const int n0 = (o & 1) * 128;
  const size_t a_off = SRC_SWZ(m0);
  const size_t b_off = SRC_IMG(n0, 1024);
  #define STGX_HT(buf, k0)                                              \
    {                                                                   \
      const char* ab = (const char*)((k0) < 256 ? msg : rh);            \
      const char* sa = ab + a_off + (size_t)(((k0) & 255)) * 2;         \
      char* da = (char*)&AL[0] + wave * 4096;                           \
      _Pragma("unroll")                                                 \
      for (int i_ = 0; i_ < 4; ++i_) gld16(sa + i_ * 4096, da + i_ * 1024); \
    }
  #define STGY_HT(buf, k0)                                              \
    {                                                                   \
      const char* sb = (const char*)WhcT + b_off + (size_t)(k0) * 2;    \
      char* db = (char*)&BL[0] + wave * 4096;                           \
      _Pragma("unroll")                                                 \
      for (int i_ = 0; i_ < 4; ++i_) gld16(sb + i_ * 8192, db + i_ * 1024); \
    }
  GEMM_LOOP1(512, STGX_HT, STGY_HT);
  #pragma unroll
  for (int mi = 0; mi < 4; ++mi)
    #pragma unroll
    for (int ni = 0; ni < 4; ++ni) {
      int gcol = n0 + wc + ni * 16 + m16;
      #pragma unroll
      for (int r = 0; r < 4; ++r) {
        int grow = m0 + wr + mi * 16 + 4 * g + r;
        int bb = grow >> 9;
        size_t oidx = (size_t)grow * 256 + gcol;
        float pre = acc[mi][ni][r] + ch[bb * 256 + gcol];
        float htl = tanhf(pre);
        float zv  = (float)z[oidx];
        float hv  = (float)h16[oidx];
        out[oidx] = (1.f - zv) * hv + zv * htl;
      }
    }
}

// ---------------------------------------------------------------------------
extern "C" void kernel_launch(void* const* d_in, const int* in_sizes, int n_in,
                              void* d_out, int out_size, void* d_ws, size_t ws_size,
                              hipStream_t stream) {
  const float* h    = (const float*)d_in[0];
  const float* jets = (const float*)d_in[1];
  const float* mask = (const float*)d_in[2];
  const float* Wa   = (const float*)d_in[3];
  const float* ba   = (const float*)d_in[4];
  const float* Wm   = (const float*)d_in[5];
  const float* bm   = (const float*)d_in[6];
  const float* Wz   = (const float*)d_in[7];
  const float* bz   = (const float*)d_in[8];
  const float* Wr   = (const float*)d_in[9];
  const float* br   = (const float*)d_in[10];
  const float* Wh   = (const float*)d_in[11];
  const float* bh   = (const float*)d_in[12];
  float* out = (float*)d_out;

  char* ws = (char*)d_ws;
  size_t off = 0;
  auto alloc = [&](size_t bytes) -> void* {
    void* p = ws + off;
    off += (bytes + 255) & ~(size_t)255;
    return p;
  };
  // big: q (f16, 32MB) during attention; z (f16) + rh (f16) afterwards.
  char*   big   = (char*) alloc((size_t)ROWS * H_ * 4);
  f16*    hmT   = (f16*)  alloc((size_t)B_ * H_ * N_ * 2);
  f16*    msg   = (f16*)  alloc((size_t)ROWS * H_ * 2);
  f16*    h16   = (f16*)  alloc((size_t)ROWS * H_ * 2);
  float*  hmean4= (float*)alloc((size_t)B_ * 4 * H_ * 4);
  float*  cz    = (float*)alloc((size_t)B_ * H_ * 4);
  float*  cr    = (float*)alloc((size_t)B_ * H_ * 4);
  float*  chv   = (float*)alloc((size_t)B_ * H_ * 4);
  f16*    WaT   = (f16*)  alloc(65536 * 2);
  f16*    WmT   = (f16*)  alloc(65536 * 2);
  f16*    WzrT  = (f16*)  alloc(262144 * 2);
  f16*    WhcT  = (f16*)  alloc(131072 * 2);
  f16* q  = (f16*)big;
  f16* z  = (f16*)big;                                     // q dead after attn
  f16* rh = (f16*)(big + (size_t)ROWS * H_ * 2);
  if (off > ws_size) return;  // workspace insufficient

  k_prep    <<<2048, 256, 0, stream>>>(Wa, Wm, Wz, Wr, Wh, WaT, WmT, WzrT, WhcT);
  k_hmean   <<<dim3(B_, 4), H_, 0, stream>>>(h, hmean4, h16);
  k_cvec    <<<B_, H_, 0, stream>>>(hmean4, jets, Wz, Wr, Wh, bz, br, bh, cz, cr, chv);
  k_gemm_q  <<<1024, 256, 0, stream>>>(h16, WaT, ba, q);
  k_gemm_hmT<<<1024, 256, 0, stream>>>(h16, WmT, bm, hmT);
  k_attn7   <<<512, 256, 0, stream>>>(q, mask, hmT, h16, msg);
  k_gemm_zr <<<2048, 256, 0, stream>>>(msg, h16, WzrT, cz, cr, z, rh);
  k_gemm_ht <<<1024, 256, 0, stream>>>(msg, rh, WhcT, chv, z, h16, out);
}